// Round 12
// baseline (1131.730 us; speedup 1.0000x reference)
//
#include <hip/hip_runtime.h>
#include <hip/hip_bf16.h>
#include <math.h>

typedef __attribute__((ext_vector_type(8))) short short8;
typedef __attribute__((ext_vector_type(4))) float f32x4;
typedef unsigned short u16;
typedef unsigned int u32;
typedef unsigned long long u64;

#define DEV __device__ __forceinline__

DEV float bf2f(u16 u){ u32 x = ((u32)u)<<16; return __builtin_bit_cast(float, x); }
DEV u16 f2bf(float f){ u32 x = __builtin_bit_cast(u32, f); return (u16)((x + 0x7FFFu + ((x>>16)&1u))>>16); }
DEV f32x4 mfma16(short8 a, short8 b, f32x4 c){ return __builtin_amdgcn_mfma_f32_16x16x32_bf16(a,b,c,0,0,0); }
DEV void gload16(const void* g, void* l){
  __builtin_amdgcn_global_load_lds((const __attribute__((address_space(1))) void*)g,
                                   (__attribute__((address_space(3))) void*)l, 16, 0, 0);
}
DEV u32 fkey(float f){ u32 b = __builtin_bit_cast(u32, f); return (b & 0x80000000u) ? ~b : (b ^ 0x80000000u); }
DEV float funkey(u32 k){ u32 b = (k & 0x80000000u) ? (k ^ 0x80000000u) : ~k; return __builtin_bit_cast(float, b); }
DEV u32 cvtpk(float lo, float hi){ u32 d; asm("v_cvt_pk_bf16_f32 %0, %1, %2" : "=v"(d) : "v"(lo), "v"(hi)); return d; }

// ---------------- workspace layout (bytes) ----------------
static constexpr size_t O_PROJW = 0;                         // 512*512*2
static constexpr size_t O_QKVW  = O_PROJW + 524288;          // 6*1536*512*2
static constexpr size_t O_WOW   = O_QKVW + 9437184;          // 6*512*512*2
static constexpr size_t O_W1W   = O_WOW + 3145728;
static constexpr size_t O_W2W   = O_W1W + 3145728;
static constexpr size_t O_C1W   = O_W2W + 3145728;           // 128*2880*2
static constexpr size_t O_C2W   = O_C1W + 737280;            // 320*1152*2
static constexpr size_t O_RA    = O_C2W + 737280;            // pcl1 22.3MB / tmp f32 / vt 8.4MB / pcl2
static constexpr size_t O_RB    = O_RA + 22302720;           // patches f32 16.8MB then qkv bf16 25.2MB
static constexpr size_t O_X     = O_RB + 25165824;           // x f32 16.8MB
static constexpr size_t O_D     = O_X + 16777216;            // xn bf16 8.4MB
static constexpr size_t O_F     = O_D + 8388608;             // o/g bf16 8.4MB
static constexpr size_t O_RM    = O_F + 8388608;             // 48*1024 u8
static constexpr size_t O_MIN   = O_RM + 49152;              // min keys [0..5], max keys [8..13]
static constexpr size_t O_RMB   = O_MIN + 256;               // 48*16 u64 bit-packed masks
static constexpr size_t WS_NEED = O_RMB + 8192;

// ---------------- weight conversion ----------------
// src [z][K][N] f32 -> dst [z][N][K] bf16
__global__ __launch_bounds__(256) void k_transpose_bf(const float* __restrict__ src, u16* __restrict__ dst, int K, int N){
  __shared__ float tile[32][33];
  const int k0 = blockIdx.x*32, n0 = blockIdx.y*32;
  src += (size_t)blockIdx.z*K*N; dst += (size_t)blockIdx.z*K*N;
  const int c = threadIdx.x & 31, r4 = threadIdx.x >> 5;
  for(int r=r4; r<32; r+=8) tile[r][c] = src[(size_t)(k0+r)*N + n0+c];
  __syncthreads();
  for(int r=r4; r<32; r+=8) dst[(size_t)(n0+r)*K + k0+c] = f2bf(tile[c][r]);
}

// conv weights [OC][IC][3][3] f32 -> Wt [OC][tap*IC+ic] bf16
__global__ __launch_bounds__(256) void k_convw(const float* __restrict__ src, u16* __restrict__ dst, int OC, int IC){
  int idx = blockIdx.x*256 + threadIdx.x;
  int total = OC*IC*9;
  if(idx >= total) return;
  int oc = idx/(IC*9); int rem = idx - oc*IC*9; int tap = rem/IC; int ic = rem - tap*IC;
  dst[idx] = f2bf(src[(size_t)(oc*IC+ic)*9 + tap]);
}

// img [8][320][64][64] f32 -> pcl1 [8][66][66][320] bf16 (interior; borders pre-zeroed)
__global__ __launch_bounds__(256) void k_pad_img(const float* __restrict__ img, u16* __restrict__ pcl){
  const int by = blockIdx.x; const int b = by>>6, y = by&63; const int c0 = blockIdx.y*64;
  __shared__ float t[64][65];
  const int tx = threadIdx.x & 63, tz = threadIdx.x >> 6;
  for(int ci=tz; ci<64; ci+=4) t[ci][tx] = img[(((size_t)b*320 + c0+ci)*64 + y)*64 + tx];
  __syncthreads();
  for(int x=tz; x<64; x+=4) pcl[(((size_t)b*66 + y+1)*66 + (x+1))*320 + c0 + tx] = f2bf(t[tx][x]);
}

// x tokens f32 -> pcl2 [8][66][66][128] bf16 (interior)
__global__ __launch_bounds__(256) void k_pad_tok(const float* __restrict__ x, u16* __restrict__ pcl){
  int idx = blockIdx.x*256 + threadIdx.x;           // 8*64*64*128
  const int c = idx & 127; int r = idx >> 7; const int xx = r & 63; r >>= 6; const int yy = r & 63; const int b = r >> 6;
  const int n = (yy>>1)*32 + (xx>>1); const int f = (yy&1)*256 + (xx&1)*128 + c;
  pcl[(((size_t)b*66 + yy+1)*66 + xx+1)*128 + c] = f2bf(x[((size_t)b*1024 + n)*512 + f]);
}

// mask [48][64][64] int -> rmbits [48][16] u64 (2x2 any)
__global__ __launch_bounds__(256) void k_rmask(const int* __restrict__ mask, u64* __restrict__ rmbits){
  int idx = blockIdx.x*256 + threadIdx.x;
  const int m = idx >> 10, n = idx & 1023; const int h = n>>5, w = n&31;
  const int* mp = mask + ((size_t)m*64 + h*2)*64 + w*2;
  const int v = (mp[0]==1) | (mp[1]==1) | (mp[64]==1) | (mp[65]==1);
  const u64 bm = __ballot(v);
  if((threadIdx.x & 63) == 0) rmbits[idx>>6] = bm;
}

// ---------------- layernorm (wave per token) ----------------
__global__ __launch_bounds__(256) void k_ln_bf(const float* __restrict__ in, const float* __restrict__ gw,
                                               const float* __restrict__ bw, u16* __restrict__ out){
  const int tok = blockIdx.x*4 + (threadIdx.x>>6);
  const int lane = threadIdx.x & 63;
  const float* rp = in + (size_t)tok*512 + lane*8;
  const float4 a = *(const float4*)rp;
  const float4 b = *(const float4*)(rp+4);
  float s  = a.x+a.y+a.z+a.w + b.x+b.y+b.z+b.w;
  float sq = a.x*a.x+a.y*a.y+a.z*a.z+a.w*a.w + b.x*b.x+b.y*b.y+b.z*b.z+b.w*b.w;
  #pragma unroll
  for(int off=1; off<64; off<<=1){ s += __shfl_xor(s,off); sq += __shfl_xor(sq,off); }
  const float mu = s*(1.f/512.f);
  const float rs = rsqrtf(fmaxf(sq*(1.f/512.f) - mu*mu, 0.f) + 1e-5f);
  const float4 g0 = *(const float4*)(gw + lane*8);
  const float4 g1 = *(const float4*)(gw + lane*8 + 4);
  const float4 b0 = *(const float4*)(bw + lane*8);
  const float4 b1 = *(const float4*)(bw + lane*8 + 4);
  short8 o8;
  o8[0]=f2bf((a.x-mu)*rs*g0.x+b0.x); o8[1]=f2bf((a.y-mu)*rs*g0.y+b0.y);
  o8[2]=f2bf((a.z-mu)*rs*g0.z+b0.z); o8[3]=f2bf((a.w-mu)*rs*g0.w+b0.w);
  o8[4]=f2bf((b.x-mu)*rs*g1.x+b1.x); o8[5]=f2bf((b.y-mu)*rs*g1.y+b1.y);
  o8[6]=f2bf((b.z-mu)*rs*g1.z+b1.z); o8[7]=f2bf((b.w-mu)*rs*g1.w+b1.w);
  *(short8*)(out + (size_t)tok*512 + lane*8) = o8;
}

// LN + sincos 2d posemb -> f32 x (wave per token)
__global__ __launch_bounds__(256) void k_lnq_pos(const float* __restrict__ in, const float* __restrict__ gw,
                                                 const float* __restrict__ bw, float* __restrict__ out){
  const int tok = blockIdx.x*4 + (threadIdx.x>>6);
  const int lane = threadIdx.x & 63;
  const float* rp = in + (size_t)tok*512 + lane*8;
  const float4 a = *(const float4*)rp;
  const float4 b = *(const float4*)(rp+4);
  float s  = a.x+a.y+a.z+a.w + b.x+b.y+b.z+b.w;
  float sq = a.x*a.x+a.y*a.y+a.z*a.z+a.w*a.w + b.x*b.x+b.y*b.y+b.z*b.z+b.w*b.w;
  #pragma unroll
  for(int off=1; off<64; off<<=1){ s += __shfl_xor(s,off); sq += __shfl_xor(sq,off); }
  const float mu = s*(1.f/512.f);
  const float rs = rsqrtf(fmaxf(sq*(1.f/512.f) - mu*mu, 0.f) + 1e-5f);
  const int n = tok & 1023; const int yy = n>>5, xx = n&31;
  const int f0 = lane*8; const int sec = f0>>7;
  const float coord = (sec<2) ? (float)xx : (float)yy;
  const float vv[8] = {a.x,a.y,a.z,a.w,b.x,b.y,b.z,b.w};
  float ov[8];
  #pragma unroll
  for(int j=0;j<8;j++){
    const int f = f0+j; const int qq = f & 127;
    const float om = __expf(-(float)qq * (9.2103403719761836f/127.f));
    const float arg = coord * om;
    const float pe = (sec&1) ? __cosf(arg) : __sinf(arg);
    ov[j] = (vv[j]-mu)*rs*gw[f] + bw[f] + pe;
  }
  float* op = out + (size_t)tok*512 + f0;
  *(float4*)op = (float4){ov[0],ov[1],ov[2],ov[3]};
  *(float4*)(op+4) = (float4){ov[4],ov[5],ov[6],ov[7]};
}

// ---------------- GEMM 64x64 tile (4 blocks/CU) for N=512 layers ----------------
// EPI: 0 proj(f32+bias) 2 resid(f32) 3 gelu(bf16+bias) 4 resid+bias
template<int EPI>
__global__ __launch_bounds__(256, 4)
void k_gemm64(const u16* __restrict__ A, const u16* __restrict__ Wt,
              const float* __restrict__ bias, void* __restrict__ outp,
              const float* __restrict__ resid, int Kd)
{
  __shared__ u16 Ald[2][4096];
  __shared__ u16 Bld[2][4096];
  const int tid = threadIdx.x, lane = tid & 63, wv = tid >> 6;
  const int lr = lane & 15, g = lane >> 4;
  const int m0 = blockIdx.x * 64, n0 = blockIdx.y * 64;
  const int wm = (wv >> 1) * 32, wn = (wv & 1) * 32;
  const int srow = tid >> 3;
  const int sc  = (tid & 7) ^ (srow & 7);
  const u16* arow0p = A + (size_t)(m0+srow)*Kd + sc*8;
  const u16* arow1p = A + (size_t)(m0+srow+32)*Kd + sc*8;
  const u16* brow0p = Wt + (size_t)(n0+srow)*Kd + sc*8;
  const u16* brow1p = Wt + (size_t)(n0+srow+32)*Kd + sc*8;

  f32x4 acc[2][2];
  #pragma unroll
  for(int i=0;i<2;i++)
    #pragma unroll
    for(int j=0;j<2;j++) acc[i][j] = (f32x4){0.f,0.f,0.f,0.f};

  const int nIter = Kd >> 6;
  int cur = 0;
  auto stage = [&](int kt, int buf){
    const int k0 = kt << 6;
    gload16(arow0p + k0, &Ald[buf][tid*8]);
    gload16(arow1p + k0, &Ald[buf][2048 + tid*8]);
    gload16(brow0p + k0, &Bld[buf][tid*8]);
    gload16(brow1p + k0, &Bld[buf][2048 + tid*8]);
  };

  stage(0, 0);
  for(int kt=0; kt<nIter; ++kt){
    __syncthreads();
    if(kt+1 < nIter) stage(kt+1, cur^1);
    short8 af[2][2], bg[2][2];
    #pragma unroll
    for(int mi=0;mi<2;mi++)
      #pragma unroll
      for(int kk=0;kk<2;kk++){
        const int R = wm + mi*16 + lr;
        const int Rn = wn + mi*16 + lr;
        const int c = kk*4 + g;
        af[mi][kk] = *(const short8*)&Ald[cur][R*64 + ((c ^ (R&7))<<3)];
        bg[mi][kk] = *(const short8*)&Bld[cur][Rn*64 + ((c ^ (Rn&7))<<3)];
      }
    #pragma unroll
    for(int mi=0;mi<2;mi++)
      #pragma unroll
      for(int nj=0;nj<2;nj++)
        #pragma unroll
        for(int kk=0;kk<2;kk++)
          acc[mi][nj] = mfma16(af[mi][kk], bg[nj][kk], acc[mi][nj]);
    cur ^= 1;
  }

  #pragma unroll
  for(int mi=0;mi<2;mi++){
    #pragma unroll
    for(int nj=0;nj<2;nj++){
      #pragma unroll
      for(int r=0;r<4;r++){
        const int mrow = m0 + wm + mi*16 + g*4 + r;
        const int ncol = n0 + wn + nj*16 + lr;
        float val = acc[mi][nj][r];
        if constexpr (EPI==0 || EPI==3 || EPI==4)
          val += bias[ncol];
        if constexpr (EPI==0){
          ((float*)outp)[(size_t)mrow*512 + ncol] = val;
        } else if constexpr (EPI==2 || EPI==4){
          const size_t idx = (size_t)mrow*512 + ncol;
          ((float*)outp)[idx] = resid[idx] + val;
        } else if constexpr (EPI==3){
          const float gl = 0.5f * val * (1.f + erff(val * 0.70710678118654752f));
          ((u16*)outp)[(size_t)mrow*512 + ncol] = f2bf(gl);
        }
      }
    }
  }
}

// ---------------- wide GEMM (128x64 tile) for convs ----------------
// EPI: 5 conv1->patches 6 conv2->out
template<int EPI, int CONVC>
__global__ __launch_bounds__(256, 3)
void k_gemm(const u16* __restrict__ A, const u16* __restrict__ Wt,
            const float* __restrict__ bias, void* __restrict__ outp,
            const float* __restrict__ resid, int M, int N, int Kd)
{
  __shared__ u16 Ald[2][8192];                        // [128][64] (4 chunks of 32 rows)
  __shared__ u16 Bld[2][4096];                        // [64][64]
  const int tid = threadIdx.x, lane = tid & 63, wv = tid >> 6;
  const int lr = lane & 15, g = lane >> 4;
  const int m0 = blockIdx.x * 128, n0 = blockIdx.y * 64;
  const int wm = wv * 32;
  const int srow = tid >> 3;
  const int sc  = (tid & 7) ^ (srow & 7);
  int b0=0, y0=0;
  if constexpr (CONVC != 0){ b0 = m0>>12; y0 = (m0>>6)&63; }
  const u16* ar[4];
  if constexpr (CONVC == 0){
    #pragma unroll
    for(int j=0;j<4;j++) ar[j] = A + (size_t)(m0+srow+32*j)*Kd + sc*8;
  }
  const u16* br0 = Wt + (size_t)(n0+srow)*Kd + sc*8;
  const u16* br1 = Wt + (size_t)(n0+srow+32)*Kd + sc*8;

  f32x4 acc[2][4];
  #pragma unroll
  for(int i=0;i<2;i++)
    #pragma unroll
    for(int j=0;j<4;j++) acc[i][j] = (f32x4){0.f,0.f,0.f,0.f};

  const int nIter = Kd >> 6;
  int cur = 0;

  auto stage = [&](int kt, int buf){
    const int k0 = kt << 6;
    if constexpr (CONVC != 0){
      const int tap = k0 / CONVC;
      const int ic0 = k0 - tap*CONVC;
      const int ky = tap/3, kx = tap - 3*(tap/3);
      #pragma unroll
      for(int j=0;j<4;j++){
        const int xr = srow + 32*(j&1);
        const int yr = y0 + (j>>1) + ky;
        const u16* ga = A + ((size_t)((b0*66 + yr)*66 + xr + kx))*CONVC + ic0 + sc*8;
        gload16(ga, &Ald[buf][j*2048 + tid*8]);
      }
    } else {
      #pragma unroll
      for(int j=0;j<4;j++) gload16(ar[j] + k0, &Ald[buf][j*2048 + tid*8]);
    }
    gload16(br0 + k0, &Bld[buf][tid*8]);
    gload16(br1 + k0, &Bld[buf][2048 + tid*8]);
  };

  stage(0, 0);
  for(int kt=0; kt<nIter; ++kt){
    __syncthreads();
    if(kt+1 < nIter) stage(kt+1, cur^1);
    short8 af[2][2], bg[4][2];
    #pragma unroll
    for(int mi=0;mi<2;mi++)
      #pragma unroll
      for(int kk=0;kk<2;kk++){
        const int R = wm + mi*16 + lr;
        const int c = kk*4 + g;
        af[mi][kk] = *(const short8*)&Ald[cur][R*64 + ((c ^ (R&7))<<3)];
      }
    #pragma unroll
    for(int nj=0;nj<4;nj++)
      #pragma unroll
      for(int kk=0;kk<2;kk++){
        const int Rn = nj*16 + lr;
        const int c = kk*4 + g;
        bg[nj][kk] = *(const short8*)&Bld[cur][Rn*64 + ((c ^ (Rn&7))<<3)];
      }
    #pragma unroll
    for(int mi=0;mi<2;mi++)
      #pragma unroll
      for(int nj=0;nj<4;nj++)
        #pragma unroll
        for(int kk=0;kk<2;kk++)
          acc[mi][nj] = mfma16(af[mi][kk], bg[nj][kk], acc[mi][nj]);
    cur ^= 1;
  }

  #pragma unroll
  for(int mi=0;mi<2;mi++){
    #pragma unroll
    for(int nj=0;nj<4;nj++){
      #pragma unroll
      for(int r=0;r<4;r++){
        const int mrow = m0 + wm + mi*16 + g*4 + r;
        const int ncol = n0 + nj*16 + lr;
        float val = acc[mi][nj][r] + bias[ncol];
        if constexpr (EPI==5){
          const int b = mrow>>12; const int rr = mrow&4095; const int y = rr>>6; const int xx = rr&63;
          const size_t pidx = ((size_t)(b*1024 + (y>>1)*32 + (xx>>1)))*512 + (y&1)*256 + (xx&1)*128 + ncol;
          ((float*)outp)[pidx] = val;
        } else if constexpr (EPI==6){
          const int b = mrow>>12; const int rr = mrow&4095; const int y = rr>>6; const int xx = rr&63;
          ((float*)outp)[(((size_t)(b*320 + ncol))*64 + y)*64 + xx] = val;
        }
      }
    }
  }
}

// ---------------- wide GEMM for qkv: 128x64 tile, BK=64; q/k scatter; v -> vt directly ----------------
__global__ __launch_bounds__(256, 3)
void k_gemmW(const u16* __restrict__ A, const u16* __restrict__ Wt,
             void* __restrict__ outp, u16* __restrict__ vt, int Kd)
{
  __shared__ u16 Ald[2][8192];                       // [128][64]; reused as Vt bounce tile
  __shared__ u16 Bld[2][4096];                       // [64][64]
  const int tid = threadIdx.x, lane = tid & 63, wv = tid >> 6;
  const int lr = lane & 15, g = lane >> 4;
  const int m0 = blockIdx.x * 128, n0 = blockIdx.y * 64;
  const int wm = wv * 32;
  const int srow = tid >> 3;
  const int sc  = (tid & 7) ^ (srow & 7);
  const u16* ar[4];
  #pragma unroll
  for(int j=0;j<4;j++) ar[j] = A + (size_t)(m0+srow+32*j)*Kd + sc*8;
  const u16* br0 = Wt + (size_t)(n0+srow)*Kd + sc*8;
  const u16* br1 = Wt + (size_t)(n0+srow+32)*Kd + sc*8;

  f32x4 acc[2][4];
  #pragma unroll
  for(int i=0;i<2;i++)
    #pragma unroll
    for(int j=0;j<4;j++) acc[i][j] = (f32x4){0.f,0.f,0.f,0.f};

  const int nIter = Kd >> 6;
  int cur = 0;
  auto stage = [&](int kt, int buf){
    const int k0 = kt << 6;
    #pragma unroll
    for(int j=0;j<4;j++) gload16(ar[j] + k0, &Ald[buf][j*2048 + tid*8]);
    gload16(br0 + k0, &Bld[buf][tid*8]);
    gload16(br1 + k0, &Bld[buf][2048 + tid*8]);
  };

  stage(0, 0);
  for(int kt=0; kt<nIter; ++kt){
    __syncthreads();
    if(kt+1 < nIter) stage(kt+1, cur^1);
    short8 af[2][2], bg[4][2];
    #pragma unroll
    for(int mi=0;mi<2;mi++)
      #pragma unroll
      for(int kk=0;kk<2;kk++){
        const int R = wm + mi*16 + lr;
        const int c = kk*4 + g;
        af[mi][kk] = *(const short8*)&Ald[cur][R*64 + ((c ^ (R&7))<<3)];
      }
    #pragma unroll
    for(int nj=0;nj<4;nj++)
      #pragma unroll
      for(int kk=0;kk<2;kk++){
        const int Rn = nj*16 + lr;
        const int c = kk*4 + g;
        bg[nj][kk] = *(const short8*)&Bld[cur][Rn*64 + ((c ^ (Rn&7))<<3)];
      }
    #pragma unroll
    for(int mi=0;mi<2;mi++)
      #pragma unroll
      for(int nj=0;nj<4;nj++)
        #pragma unroll
        for(int kk=0;kk<2;kk++)
          acc[mi][nj] = mfma16(af[mi][kk], bg[nj][kk], acc[mi][nj]);
    cur ^= 1;
  }

  if(n0 < 1024){
    // q/k scatter epilogue
    #pragma unroll
    for(int mi=0;mi<2;mi++){
      #pragma unroll
      for(int nj=0;nj<4;nj++){
        #pragma unroll
        for(int r=0;r<4;r++){
          const int mrow = m0 + wm + mi*16 + g*4 + r;
          const int ncol = n0 + nj*16 + lr;
          const int sec = ncol >> 9, rem = ncol & 511;
          const int head = rem >> 6, d = rem & 63;
          const int b = mrow >> 10, t = mrow & 1023;
          ((u16*)outp)[(size_t)sec*4194304 + ((size_t)((b*8+head)*1024 + t))*64 + d] = f2bf(acc[mi][nj][r]);
        }
      }
    }
  } else {
    // v block: write vt[bh][d][t] directly via LDS bounce (raw v never materialized)
    const int head = (n0 - 1024) >> 6;
    const int b = m0 >> 10;
    const int t0 = m0 & 1023;
    const int bh = b*8 + head;
    __syncthreads();                                  // all waves done reading Ald
    u16* Vt = (u16*)Ald;                              // [64 d][136] (stride 272B, 16B-aligned)
    #pragma unroll
    for(int mi=0;mi<2;mi++)
      #pragma unroll
      for(int nj=0;nj<4;nj++)
        #pragma unroll
        for(int r=0;r<4;r++){
          const int lt = wm + mi*16 + g*4 + r;
          const int d  = nj*16 + lr;
          Vt[d*136 + lt] = f2bf(acc[mi][nj][r]);
        }
    __syncthreads();
    const int d = tid >> 2, qd = tid & 3;             // 64 d-rows x 4 chunks of 32 t
    u16* dst = vt + (size_t)bh*65536 + (size_t)d*1024 + t0 + qd*32;
    const u16* srcl = &Vt[d*136 + qd*32];
    #pragma unroll
    for(int e4=0;e4<4;e4++)
      *(short8*)(dst + e4*8) = *(const short8*)(srcl + e4*8);
  }
}

// ---------------- attention pass A: global min AND max, 128-q tile, 4-way j-split ----------------
__global__ __launch_bounds__(256, 4)
void k_attn_minmax(const u16* __restrict__ q, const u16* __restrict__ k, u32* __restrict__ keys, int layer){
  const int id = blockIdx.x;                   // 2048 blocks: bhLo(3) | qt(3) | js(2) | bhHi(3)
  const int t = id >> 3;
  const int qt = t & 7;
  const int js = (t >> 3) & 3;
  const int bh = ((id & 7) << 3) | (t >> 5);
  __shared__ u16 Kld[2][4096];
  __shared__ float redn[4], redx[4];
  const int tid = threadIdx.x, lane = tid & 63, wv = tid >> 6;
  const int lr = lane & 15, g = lane >> 4;
  const u16* qp0 = q + ((size_t)bh*1024 + qt*128 + wv*16 + lr)*64;
  const u16* qp1 = qp0 + 64*64;
  const short8 qa00 = *(const short8*)(qp0 + g*8);
  const short8 qa01 = *(const short8*)(qp0 + 32 + g*8);
  const short8 qa10 = *(const short8*)(qp1 + g*8);
  const short8 qa11 = *(const short8*)(qp1 + 32 + g*8);
  const u16* kbase = k + (size_t)bh*65536;
  const int srow = tid>>3, scs = lane&7;
  const int scg = scs ^ (srow&7);
  const int srow2 = srow + 32;
  const int scg2 = scs ^ (srow2&7);
  float mn = 3.0e38f, mx = -3.0e38f;
  auto stageK = [&](int jt, int buf){
    const int j0 = jt*64;
    gload16(kbase + (size_t)(j0+srow)*64 + scg*8, &Kld[buf][wv*512]);
    gload16(kbase + (size_t)(j0+srow2)*64 + scg2*8, &Kld[buf][2048 + wv*512]);
  };
  const int jt0 = js*4;
  stageK(jt0, 0);
  int cur = 0;
  for(int i=0; i<4; ++i){
    __syncthreads();
    if(i < 3) stageK(jt0+i+1, cur^1);
    #pragma unroll
    for(int c=0;c<4;c++){
      const int rr = c*16 + lr;
      const short8 kb0 = *(const short8*)&Kld[cur][rr*64 + ((g ^ (rr&7))<<3)];
      const short8 kb1 = *(const short8*)&Kld[cur][rr*64 + (((g+4) ^ (rr&7))<<3)];
      f32x4 sa = (f32x4){0.f,0.f,0.f,0.f};
      f32x4 sb = (f32x4){0.f,0.f,0.f,0.f};
      __builtin_amdgcn_s_setprio(1);
      sa = mfma16(qa00, kb0, sa);
      sa = mfma16(qa01, kb1, sa);
      sb = mfma16(qa10, kb0, sb);
      sb = mfma16(qa11, kb1, sb);
      __builtin_amdgcn_s_setprio(0);
      mn = fminf(mn, fminf(fminf(sa[0],sa[1]), fminf(sa[2],sa[3])));
      mx = fmaxf(mx, fmaxf(fmaxf(sa[0],sa[1]), fmaxf(sa[2],sa[3])));
      mn = fminf(mn, fminf(fminf(sb[0],sb[1]), fminf(sb[2],sb[3])));
      mx = fmaxf(mx, fmaxf(fmaxf(sb[0],sb[1]), fmaxf(sb[2],sb[3])));
    }
    cur ^= 1;
  }
  mn *= 0.125f; mx *= 0.125f;
  #pragma unroll
  for(int off=32; off; off>>=1){
    mn = fminf(mn, __shfl_down(mn, off));
    mx = fmaxf(mx, __shfl_down(mx, off));
  }
  if(lane==0){ redn[wv] = mn; redx[wv] = mx; }
  __syncthreads();
  if(tid==0){
    atomicMin(keys + layer,     fkey(fminf(fminf(redn[0],redn[1]), fminf(redn[2],redn[3]))));
    atomicMax(keys + 8 + layer, fkey(fmaxf(fmaxf(redx[0],redx[1]), fmaxf(redx[2],redx[3]))));
  }
}

// ---------------- attention pass B: 128-q tile, swapped QK^T, global-shift softmax, packed P ----------------
__global__ __launch_bounds__(256, 3)
void k_attn(const u16* __restrict__ q, const u16* __restrict__ k, const u16* __restrict__ vt,
            const u64* __restrict__ rmbits, const u32* __restrict__ keys,
            u16* __restrict__ o, int layer){
  const int id = blockIdx.x;                   // 512 blocks
  const int qt = (id>>3)&7;
  const int bh = ((id&7)<<3) | (id>>6);
  const int b = bh>>3, h = bh&7;
  __shared__ u16 Kld[2][4096];
  __shared__ u16 Vtld[2][4096];
  __shared__ u32 Pld[4][1024];                 // per-wave [32 qrow][32 u32]
  const int tid = threadIdx.x, lane = tid & 63, wv = tid >> 6;
  const int lr = lane & 15, g = lane >> 4;
  const int L7 = lr & 7;
  const int LH = (lr >> 3) << 2;               // extra swizzle bit: lr/lr+8 split banks
  const u16* qp0 = q + ((size_t)bh*1024 + qt*128 + wv*16 + lr)*64;
  const u16* qp1 = qp0 + 64*64;
  const short8 qa00 = *(const short8*)(qp0 + g*8);
  const short8 qa01 = *(const short8*)(qp0 + 32 + g*8);
  const short8 qa10 = *(const short8*)(qp1 + g*8);
  const short8 qa11 = *(const short8*)(qp1 + 32 + g*8);
  const float L2E = 1.44269504088896f;
  const float SC = 0.125f * L2E;
  float mnv = funkey(keys[layer]);
  float mxv = funkey(keys[8+layer]);
  if(!(mnv >= -1e38f && mnv <= 1e38f)) mnv = 0.f;
  if(!(mxv >= -1e38f && mxv <= 1e38f)) mxv = 0.f;
  const float ME   = mxv * L2E;
  const float minM = fmaxf(mnv*L2E - ME, -120.f);
  const u32* cbp = (const u32*)(rmbits + (size_t)(layer*8 + b)*16);
  const int rowi0 = qt*128 + wv*16 + lr;
  const int rowi1 = rowi0 + 64;
  const u32 rf0 = ((cbp[rowi0>>5] >> (rowi0&31)) & 1u) ? 0xFu : 0u;
  const u32 rf1 = ((cbp[rowi1>>5] >> (rowi1&31)) & 1u) ? 0xFu : 0u;
  u32* Pw = &Pld[wv][0];
  u32 wslot[4][2];
  #pragma unroll
  for(int c=0;c<4;c++){
    const int blk = (c*2 + (g>>1)) ^ L7 ^ LH;
    wslot[c][0] = lr*32 + (blk<<2) + (g&1)*2;
    wslot[c][1] = wslot[c][0] + 1;
  }
  const u32 ra0 = lr*32 + ((g ^ L7 ^ LH)<<2);
  const u32 ra1 = lr*32 + (((4+g) ^ L7 ^ LH)<<2);

  float ls0 = 0.f, ls1 = 0.f;
  f32x4 acc0[4], acc1[4];
  #pragma unroll
  for(int d=0;d<4;d++){ acc0[d] = (f32x4){0.f,0.f,0.f,0.f}; acc1[d] = (f32x4){0.f,0.f,0.f,0.f}; }
  const u16* kbase = k + (size_t)bh*65536;
  const u16* vtbase = vt + (size_t)bh*65536;
  const int srow = tid>>3, scs = lane&7;
  const int scg = scs ^ (srow&7);
  const int srow2 = srow + 32;
  const int scg2 = scs ^ (srow2&7);
  gload16(kbase + (size_t)srow*64 + scg*8, &Kld[0][wv*512]);
  gload16(kbase + (size_t)srow2*64 + scg2*8, &Kld[0][2048 + wv*512]);
  gload16(vtbase + (size_t)srow*1024 + scg*8, &Vtld[0][wv*512]);
  gload16(vtbase + (size_t)srow2*1024 + scg2*8, &Vtld[0][2048 + wv*512]);
  int cur = 0;
  for(int jt=0; jt<16; ++jt){
    __syncthreads();
    if(jt < 15){
      const int j1 = (jt+1)*64;
      gload16(kbase + (size_t)(j1+srow)*64 + scg*8, &Kld[cur^1][wv*512]);
      gload16(kbase + (size_t)(j1+srow2)*64 + scg2*8, &Kld[cur^1][2048 + wv*512]);
      gload16(vtbase + (size_t)srow*1024 + j1 + scg*8, &Vtld[cur^1][wv*512]);
      gload16(vtbase + (size_t)srow2*1024 + j1 + scg2*8, &Vtld[cur^1][2048 + wv*512]);
    }
    const u32 cb_lo = cbp[jt*2], cb_hi = cbp[jt*2+1];
    #pragma unroll
    for(int c=0;c<4;c++){
      const int rr = c*16 + lr;
      const short8 kb0 = *(const short8*)&Kld[cur][rr*64 + ((g ^ (rr&7))<<3)];
      const short8 kb1 = *(const short8*)&Kld[cur][rr*64 + (((g+4) ^ (rr&7))<<3)];
      f32x4 sa = (f32x4){0.f,0.f,0.f,0.f};
      f32x4 sb = (f32x4){0.f,0.f,0.f,0.f};
      __builtin_amdgcn_s_setprio(1);
      sa = mfma16(kb0, qa00, sa);
      sa = mfma16(kb1, qa01, sa);
      sb = mfma16(kb0, qa10, sb);
      sb = mfma16(kb1, qa11, sb);
      __builtin_amdgcn_s_setprio(0);
      const u32 base = (((c<2) ? cb_lo : cb_hi) >> ((c&1)*16 + g*4));
      const u32 cw0 = base | rf0;
      const u32 cw1 = base | rf1;
      float e0[4], e1[4];
      #pragma unroll
      for(int r=0;r<4;r++){
        float sv0 = fmaxf(fmaf(sa[r], SC, -ME), -120.f);
        float sv1 = fmaxf(fmaf(sb[r], SC, -ME), -120.f);
        e0[r] = exp2f(((cw0 >> r) & 1u) ? sv0 : minM);
        e1[r] = exp2f(((cw1 >> r) & 1u) ? sv1 : minM);
        ls0 += e0[r]; ls1 += e1[r];
      }
      Pw[wslot[c][0]]       = cvtpk(e0[0], e0[1]);
      Pw[wslot[c][1]]       = cvtpk(e0[2], e0[3]);
      Pw[512 + wslot[c][0]] = cvtpk(e1[0], e1[1]);
      Pw[512 + wslot[c][1]] = cvtpk(e1[2], e1[3]);
    }
    asm volatile("s_waitcnt lgkmcnt(0)" ::: "memory");
    __builtin_amdgcn_sched_barrier(0);
    const short8 pa00 = *(const short8*)&Pw[ra0];
    const short8 pa01 = *(const short8*)&Pw[ra1];
    const short8 pa10 = *(const short8*)&Pw[512 + ra0];
    const short8 pa11 = *(const short8*)&Pw[512 + ra1];
    #pragma unroll
    for(int d=0;d<4;d++){
      const int rr = d*16 + lr;
      const short8 vb0 = *(const short8*)&Vtld[cur][rr*64 + ((g ^ (rr&7))<<3)];
      const short8 vb1 = *(const short8*)&Vtld[cur][rr*64 + (((g+4) ^ (rr&7))<<3)];
      __builtin_amdgcn_s_setprio(1);
      acc0[d] = mfma16(pa00, vb0, acc0[d]);
      acc0[d] = mfma16(pa01, vb1, acc0[d]);
      acc1[d] = mfma16(pa10, vb0, acc1[d]);
      acc1[d] = mfma16(pa11, vb1, acc1[d]);
      __builtin_amdgcn_s_setprio(0);
    }
    cur ^= 1;
  }
  ls0 += __shfl_xor(ls0, 16); ls0 += __shfl_xor(ls0, 32);
  ls1 += __shfl_xor(ls1, 16); ls1 += __shfl_xor(ls1, 32);
  float inv0[4], inv1[4];
  #pragma unroll
  for(int r=0;r<4;r++){ inv0[r] = 1.f / __shfl(ls0, g*4 + r); inv1[r] = 1.f / __shfl(ls1, g*4 + r); }
  #pragma unroll
  for(int d=0;d<4;d++)
    #pragma unroll
    for(int r=0;r<4;r++){
      const int qr0 = qt*128 + wv*16 + g*4 + r;
      o[((size_t)b*1024 + qr0)*512 + h*64 + d*16 + lr]        = f2bf(acc0[d][r] * inv0[r]);
      o[((size_t)b*1024 + qr0 + 64)*512 + h*64 + d*16 + lr]   = f2bf(acc1[d][r] * inv1[r]);
    }
}

// ---------------- host ----------------
extern "C" void kernel_launch(void* const* d_in, const int* in_sizes, int n_in,
                              void* d_out, int out_size, void* d_ws, size_t ws_size,
                              hipStream_t stream)
{
  const float* img     = (const float*)d_in[0];
  const int*   mask    = (const int*)d_in[1];
  const float* conv1_w = (const float*)d_in[2];
  const float* conv1_b = (const float*)d_in[3];
  const float* ln_p_g  = (const float*)d_in[4];
  const float* ln_p_b  = (const float*)d_in[5];
  const float* proj_w  = (const float*)d_in[6];
  const float* proj_b  = (const float*)d_in[7];
  const float* ln_q_g  = (const float*)d_in[8];
  const float* ln_q_b  = (const float*)d_in[9];
  const float* attn_ln_g = (const float*)d_in[10];
  const float* attn_ln_b = (const float*)d_in[11];
  const float* wqkv    = (const float*)d_in[12];
  const float* wo      = (const float*)d_in[13];
  const float* ff_ln_g = (const float*)d_in[14];
  const float* ff_ln_b = (const float*)d_in[15];
  const float* w1      = (const float*)d_in[16];
  const float* b1      = (const float*)d_in[17];
  const float* w2      = (const float*)d_in[18];
  const float* b2      = (const float*)d_in[19];
  const float* conv2_w = (const float*)d_in[20];
  const float* conv2_b = (const float*)d_in[21];

  if(ws_size < WS_NEED) return;
  char* ws = (char*)d_ws;
  u16* projWt = (u16*)(ws + O_PROJW);
  u16* qkvWt  = (u16*)(ws + O_QKVW);
  u16* woWt   = (u16*)(ws + O_WOW);
  u16* w1Wt   = (u16*)(ws + O_W1W);
  u16* w2Wt   = (u16*)(ws + O_W2W);
  u16* c1Wt   = (u16*)(ws + O_C1W);
  u16* c2Wt   = (u16*)(ws + O_C2W);
  u16* pcl    = (u16*)(ws + O_RA);      // pcl1 / vt / pcl2
  float* tmpf = (float*)(ws + O_RA);
  u16* vtb    = (u16*)(ws + O_RA);      // v^T during layer loop
  float* patches = (float*)(ws + O_RB);
  u16* qkvb   = (u16*)(ws + O_RB);      // q|k (v folded into vt), each 8*8*1024*64
  float* xbuf = (float*)(ws + O_X);
  u16* xnbf   = (u16*)(ws + O_D);
  u16* obf    = (u16*)(ws + O_F);
  u32* minbuf = (u32*)(ws + O_MIN);
  u64* rmbits = (u64*)(ws + O_RMB);

  hipMemsetAsync(ws + O_MIN, 0xFF, 32, stream);       // min keys -> UINT_MAX
  hipMemsetAsync(ws + O_MIN + 32, 0, 32, stream);     // max keys -> 0
  hipMemsetAsync(ws + O_RA, 0, 22302720, stream);     // pcl1 zero borders

  // weight conversion
  k_transpose_bf<<<dim3(16,16,1),256,0,stream>>>(proj_w, projWt, 512, 512);
  k_transpose_bf<<<dim3(16,48,6),256,0,stream>>>(wqkv,   qkvWt,  512, 1536);
  k_transpose_bf<<<dim3(16,16,6),256,0,stream>>>(wo,     woWt,   512, 512);
  k_transpose_bf<<<dim3(16,16,6),256,0,stream>>>(w1,     w1Wt,   512, 512);
  k_transpose_bf<<<dim3(16,16,6),256,0,stream>>>(w2,     w2Wt,   512, 512);
  k_convw<<<1440,256,0,stream>>>(conv1_w, c1Wt, 128, 320);
  k_convw<<<1440,256,0,stream>>>(conv2_w, c2Wt, 320, 128);
  k_rmask<<<192,256,0,stream>>>(mask, rmbits);

  // patch embed
  k_pad_img<<<dim3(512,5),256,0,stream>>>(img, pcl);
  k_gemm<5,320><<<dim3(256,2),256,0,stream>>>(pcl, c1Wt, conv1_b, patches, nullptr, 32768, 128, 2880);
  k_ln_bf<<<2048,256,0,stream>>>(patches, ln_p_g, ln_p_b, xnbf);
  k_gemm64<0><<<dim3(128,8),256,0,stream>>>(xnbf, projWt, proj_b, tmpf, nullptr, 512);
  k_lnq_pos<<<2048,256,0,stream>>>(tmpf, ln_q_g, ln_q_b, xbuf);

  const u16* qb = qkvb;
  const u16* kb = qkvb + 4194304;
  for(int i=0;i<6;i++){
    k_ln_bf<<<2048,256,0,stream>>>(xbuf, attn_ln_g + i*512, attn_ln_b + i*512, xnbf);
    k_gemmW<<<dim3(64,24),256,0,stream>>>(xnbf, qkvWt + (size_t)i*1536*512, qkvb, vtb, 512);
    k_attn_minmax<<<2048,256,0,stream>>>(qb, kb, minbuf, i);
    k_attn<<<512,256,0,stream>>>(qb, kb, vtb, rmbits, minbuf, obf, i);
    k_gemm64<2><<<dim3(128,8),256,0,stream>>>(obf, woWt + (size_t)i*512*512, nullptr, xbuf, xbuf, 512);
    k_ln_bf<<<2048,256,0,stream>>>(xbuf, ff_ln_g + i*512, ff_ln_b + i*512, xnbf);
    k_gemm64<3><<<dim3(128,8),256,0,stream>>>(xnbf, w1Wt + (size_t)i*512*512, b1 + i*512, obf, nullptr, 512);
    k_gemm64<4><<<dim3(128,8),256,0,stream>>>(obf, w2Wt + (size_t)i*512*512, b2 + i*512, xbuf, xbuf, 512);
  }

  // final conv
  hipMemsetAsync(ws + O_RA, 0, 8921088, stream);    // pcl2 zero borders
  k_pad_tok<<<16384,256,0,stream>>>(xbuf, pcl);
  k_gemm<6,128><<<dim3(256,5),256,0,stream>>>(pcl, c2Wt, conv2_b, d_out, nullptr, 32768, 320, 1152);
}

// Round 13
// 961.276 us; speedup vs baseline: 1.1773x; 1.1773x over previous
//
#include <hip/hip_runtime.h>
#include <hip/hip_bf16.h>
#include <math.h>

typedef __attribute__((ext_vector_type(8))) short short8;
typedef __attribute__((ext_vector_type(4))) float f32x4;
typedef unsigned short u16;
typedef unsigned int u32;
typedef unsigned long long u64;

#define DEV __device__ __forceinline__

DEV float bf2f(u16 u){ u32 x = ((u32)u)<<16; return __builtin_bit_cast(float, x); }
DEV u16 f2bf(float f){ u32 x = __builtin_bit_cast(u32, f); return (u16)((x + 0x7FFFu + ((x>>16)&1u))>>16); }
DEV f32x4 mfma16(short8 a, short8 b, f32x4 c){ return __builtin_amdgcn_mfma_f32_16x16x32_bf16(a,b,c,0,0,0); }
DEV void gload16(const void* g, void* l){
  __builtin_amdgcn_global_load_lds((const __attribute__((address_space(1))) void*)g,
                                   (__attribute__((address_space(3))) void*)l, 16, 0, 0);
}
DEV u32 fkey(float f){ u32 b = __builtin_bit_cast(u32, f); return (b & 0x80000000u) ? ~b : (b ^ 0x80000000u); }
DEV float funkey(u32 k){ u32 b = (k & 0x80000000u) ? (k ^ 0x80000000u) : ~k; return __builtin_bit_cast(float, b); }
DEV u32 cvtpk(float lo, float hi){ u32 d; asm("v_cvt_pk_bf16_f32 %0, %1, %2" : "=v"(d) : "v"(lo), "v"(hi)); return d; }

// ---------------- workspace layout (bytes) ----------------
static constexpr size_t O_PROJW = 0;                         // 512*512*2
static constexpr size_t O_QKVW  = O_PROJW + 524288;          // 6*1536*512*2
static constexpr size_t O_WOW   = O_QKVW + 9437184;          // 6*512*512*2
static constexpr size_t O_W1W   = O_WOW + 3145728;
static constexpr size_t O_W2W   = O_W1W + 3145728;
static constexpr size_t O_C1W   = O_W2W + 3145728;           // 128*2880*2
static constexpr size_t O_C2W   = O_C1W + 737280;            // 320*1152*2
static constexpr size_t O_RA    = O_C2W + 737280;            // pcl1 22.3MB / tmp f32 / vt 8.4MB / pcl2
static constexpr size_t O_RB    = O_RA + 22302720;           // patches f32 16.8MB then qkv bf16 25.2MB
static constexpr size_t O_X     = O_RB + 25165824;           // x f32 16.8MB
static constexpr size_t O_D     = O_X + 16777216;            // xn bf16 8.4MB
static constexpr size_t O_F     = O_D + 8388608;             // o/g bf16 8.4MB
static constexpr size_t O_RM    = O_F + 8388608;             // 48*1024 u8
static constexpr size_t O_MIN   = O_RM + 49152;              // min keys [0..5], max keys [8..13]
static constexpr size_t O_RMB   = O_MIN + 256;               // 48*16 u64 bit-packed masks
static constexpr size_t WS_NEED = O_RMB + 8192;

// ---------------- weight conversion ----------------
// src [z][K][N] f32 -> dst [z][N][K] bf16
__global__ __launch_bounds__(256) void k_transpose_bf(const float* __restrict__ src, u16* __restrict__ dst, int K, int N){
  __shared__ float tile[32][33];
  const int k0 = blockIdx.x*32, n0 = blockIdx.y*32;
  src += (size_t)blockIdx.z*K*N; dst += (size_t)blockIdx.z*K*N;
  const int c = threadIdx.x & 31, r4 = threadIdx.x >> 5;
  for(int r=r4; r<32; r+=8) tile[r][c] = src[(size_t)(k0+r)*N + n0+c];
  __syncthreads();
  for(int r=r4; r<32; r+=8) dst[(size_t)(n0+r)*K + k0+c] = f2bf(tile[c][r]);
}

// conv weights [OC][IC][3][3] f32 -> Wt [OC][tap*IC+ic] bf16
__global__ __launch_bounds__(256) void k_convw(const float* __restrict__ src, u16* __restrict__ dst, int OC, int IC){
  int idx = blockIdx.x*256 + threadIdx.x;
  int total = OC*IC*9;
  if(idx >= total) return;
  int oc = idx/(IC*9); int rem = idx - oc*IC*9; int tap = rem/IC; int ic = rem - tap*IC;
  dst[idx] = f2bf(src[(size_t)(oc*IC+ic)*9 + tap]);
}

// img [8][320][64][64] f32 -> pcl1 [8][66][66][320] bf16 (interior; borders pre-zeroed)
__global__ __launch_bounds__(256) void k_pad_img(const float* __restrict__ img, u16* __restrict__ pcl){
  const int by = blockIdx.x; const int b = by>>6, y = by&63; const int c0 = blockIdx.y*64;
  __shared__ float t[64][65];
  const int tx = threadIdx.x & 63, tz = threadIdx.x >> 6;
  for(int ci=tz; ci<64; ci+=4) t[ci][tx] = img[(((size_t)b*320 + c0+ci)*64 + y)*64 + tx];
  __syncthreads();
  for(int x=tz; x<64; x+=4) pcl[(((size_t)b*66 + y+1)*66 + (x+1))*320 + c0 + tx] = f2bf(t[tx][x]);
}

// x tokens f32 -> pcl2 [8][66][66][128] bf16 (interior)
__global__ __launch_bounds__(256) void k_pad_tok(const float* __restrict__ x, u16* __restrict__ pcl){
  int idx = blockIdx.x*256 + threadIdx.x;           // 8*64*64*128
  const int c = idx & 127; int r = idx >> 7; const int xx = r & 63; r >>= 6; const int yy = r & 63; const int b = r >> 6;
  const int n = (yy>>1)*32 + (xx>>1); const int f = (yy&1)*256 + (xx&1)*128 + c;
  pcl[(((size_t)b*66 + yy+1)*66 + xx+1)*128 + c] = f2bf(x[((size_t)b*1024 + n)*512 + f]);
}

// mask [48][64][64] int -> rmbits [48][16] u64 (2x2 any)
__global__ __launch_bounds__(256) void k_rmask(const int* __restrict__ mask, u64* __restrict__ rmbits){
  int idx = blockIdx.x*256 + threadIdx.x;
  const int m = idx >> 10, n = idx & 1023; const int h = n>>5, w = n&31;
  const int* mp = mask + ((size_t)m*64 + h*2)*64 + w*2;
  const int v = (mp[0]==1) | (mp[1]==1) | (mp[64]==1) | (mp[65]==1);
  const u64 bm = __ballot(v);
  if((threadIdx.x & 63) == 0) rmbits[idx>>6] = bm;
}

// ---------------- layernorm (wave per token) ----------------
__global__ __launch_bounds__(256) void k_ln_bf(const float* __restrict__ in, const float* __restrict__ gw,
                                               const float* __restrict__ bw, u16* __restrict__ out){
  const int tok = blockIdx.x*4 + (threadIdx.x>>6);
  const int lane = threadIdx.x & 63;
  const float* rp = in + (size_t)tok*512 + lane*8;
  const float4 a = *(const float4*)rp;
  const float4 b = *(const float4*)(rp+4);
  float s  = a.x+a.y+a.z+a.w + b.x+b.y+b.z+b.w;
  float sq = a.x*a.x+a.y*a.y+a.z*a.z+a.w*a.w + b.x*b.x+b.y*b.y+b.z*b.z+b.w*b.w;
  #pragma unroll
  for(int off=1; off<64; off<<=1){ s += __shfl_xor(s,off); sq += __shfl_xor(sq,off); }
  const float mu = s*(1.f/512.f);
  const float rs = rsqrtf(fmaxf(sq*(1.f/512.f) - mu*mu, 0.f) + 1e-5f);
  const float4 g0 = *(const float4*)(gw + lane*8);
  const float4 g1 = *(const float4*)(gw + lane*8 + 4);
  const float4 b0 = *(const float4*)(bw + lane*8);
  const float4 b1 = *(const float4*)(bw + lane*8 + 4);
  short8 o8;
  o8[0]=f2bf((a.x-mu)*rs*g0.x+b0.x); o8[1]=f2bf((a.y-mu)*rs*g0.y+b0.y);
  o8[2]=f2bf((a.z-mu)*rs*g0.z+b0.z); o8[3]=f2bf((a.w-mu)*rs*g0.w+b0.w);
  o8[4]=f2bf((b.x-mu)*rs*g1.x+b1.x); o8[5]=f2bf((b.y-mu)*rs*g1.y+b1.y);
  o8[6]=f2bf((b.z-mu)*rs*g1.z+b1.z); o8[7]=f2bf((b.w-mu)*rs*g1.w+b1.w);
  *(short8*)(out + (size_t)tok*512 + lane*8) = o8;
}

// LN + sincos 2d posemb -> f32 x (wave per token)
__global__ __launch_bounds__(256) void k_lnq_pos(const float* __restrict__ in, const float* __restrict__ gw,
                                                 const float* __restrict__ bw, float* __restrict__ out){
  const int tok = blockIdx.x*4 + (threadIdx.x>>6);
  const int lane = threadIdx.x & 63;
  const float* rp = in + (size_t)tok*512 + lane*8;
  const float4 a = *(const float4*)rp;
  const float4 b = *(const float4*)(rp+4);
  float s  = a.x+a.y+a.z+a.w + b.x+b.y+b.z+b.w;
  float sq = a.x*a.x+a.y*a.y+a.z*a.z+a.w*a.w + b.x*b.x+b.y*b.y+b.z*b.z+b.w*b.w;
  #pragma unroll
  for(int off=1; off<64; off<<=1){ s += __shfl_xor(s,off); sq += __shfl_xor(sq,off); }
  const float mu = s*(1.f/512.f);
  const float rs = rsqrtf(fmaxf(sq*(1.f/512.f) - mu*mu, 0.f) + 1e-5f);
  const int n = tok & 1023; const int yy = n>>5, xx = n&31;
  const int f0 = lane*8; const int sec = f0>>7;
  const float coord = (sec<2) ? (float)xx : (float)yy;
  const float vv[8] = {a.x,a.y,a.z,a.w,b.x,b.y,b.z,b.w};
  float ov[8];
  #pragma unroll
  for(int j=0;j<8;j++){
    const int f = f0+j; const int qq = f & 127;
    const float om = __expf(-(float)qq * (9.2103403719761836f/127.f));
    const float arg = coord * om;
    const float pe = (sec&1) ? __cosf(arg) : __sinf(arg);
    ov[j] = (vv[j]-mu)*rs*gw[f] + bw[f] + pe;
  }
  float* op = out + (size_t)tok*512 + f0;
  *(float4*)op = (float4){ov[0],ov[1],ov[2],ov[3]};
  *(float4*)(op+4) = (float4){ov[4],ov[5],ov[6],ov[7]};
}

// ---------------- GEMM 64x64 tile (4 blocks/CU) for N=512 layers ----------------
// EPI: 0 proj(f32+bias) 2 resid(f32) 3 gelu(bf16+bias) 4 resid+bias
template<int EPI>
__global__ __launch_bounds__(256, 4)
void k_gemm64(const u16* __restrict__ A, const u16* __restrict__ Wt,
              const float* __restrict__ bias, void* __restrict__ outp,
              const float* __restrict__ resid, int Kd)
{
  __shared__ u16 Ald[2][4096];
  __shared__ u16 Bld[2][4096];
  const int tid = threadIdx.x, lane = tid & 63, wv = tid >> 6;
  const int lr = lane & 15, g = lane >> 4;
  const int m0 = blockIdx.x * 64, n0 = blockIdx.y * 64;
  const int wm = (wv >> 1) * 32, wn = (wv & 1) * 32;
  const int srow = tid >> 3;
  const int sc  = (tid & 7) ^ (srow & 7);
  const u16* arow0p = A + (size_t)(m0+srow)*Kd + sc*8;
  const u16* arow1p = A + (size_t)(m0+srow+32)*Kd + sc*8;
  const u16* brow0p = Wt + (size_t)(n0+srow)*Kd + sc*8;
  const u16* brow1p = Wt + (size_t)(n0+srow+32)*Kd + sc*8;

  f32x4 acc[2][2];
  #pragma unroll
  for(int i=0;i<2;i++)
    #pragma unroll
    for(int j=0;j<2;j++) acc[i][j] = (f32x4){0.f,0.f,0.f,0.f};

  const int nIter = Kd >> 6;
  int cur = 0;
  auto stage = [&](int kt, int buf){
    const int k0 = kt << 6;
    gload16(arow0p + k0, &Ald[buf][tid*8]);
    gload16(arow1p + k0, &Ald[buf][2048 + tid*8]);
    gload16(brow0p + k0, &Bld[buf][tid*8]);
    gload16(brow1p + k0, &Bld[buf][2048 + tid*8]);
  };

  stage(0, 0);
  for(int kt=0; kt<nIter; ++kt){
    __syncthreads();
    if(kt+1 < nIter) stage(kt+1, cur^1);
    short8 af[2][2], bg[2][2];
    #pragma unroll
    for(int mi=0;mi<2;mi++)
      #pragma unroll
      for(int kk=0;kk<2;kk++){
        const int R = wm + mi*16 + lr;
        const int Rn = wn + mi*16 + lr;
        const int c = kk*4 + g;
        af[mi][kk] = *(const short8*)&Ald[cur][R*64 + ((c ^ (R&7))<<3)];
        bg[mi][kk] = *(const short8*)&Bld[cur][Rn*64 + ((c ^ (Rn&7))<<3)];
      }
    #pragma unroll
    for(int mi=0;mi<2;mi++)
      #pragma unroll
      for(int nj=0;nj<2;nj++)
        #pragma unroll
        for(int kk=0;kk<2;kk++)
          acc[mi][nj] = mfma16(af[mi][kk], bg[nj][kk], acc[mi][nj]);
    cur ^= 1;
  }

  #pragma unroll
  for(int mi=0;mi<2;mi++){
    #pragma unroll
    for(int nj=0;nj<2;nj++){
      #pragma unroll
      for(int r=0;r<4;r++){
        const int mrow = m0 + wm + mi*16 + g*4 + r;
        const int ncol = n0 + wn + nj*16 + lr;
        float val = acc[mi][nj][r];
        if constexpr (EPI==0 || EPI==3 || EPI==4)
          val += bias[ncol];
        if constexpr (EPI==0){
          ((float*)outp)[(size_t)mrow*512 + ncol] = val;
        } else if constexpr (EPI==2 || EPI==4){
          const size_t idx = (size_t)mrow*512 + ncol;
          ((float*)outp)[idx] = resid[idx] + val;
        } else if constexpr (EPI==3){
          const float gl = 0.5f * val * (1.f + erff(val * 0.70710678118654752f));
          ((u16*)outp)[(size_t)mrow*512 + ncol] = f2bf(gl);
        }
      }
    }
  }
}

// ---------------- wide GEMM (128x64 tile) for convs ----------------
// EPI: 5 conv1->patches 6 conv2->out
template<int EPI, int CONVC>
__global__ __launch_bounds__(256, 3)
void k_gemm(const u16* __restrict__ A, const u16* __restrict__ Wt,
            const float* __restrict__ bias, void* __restrict__ outp,
            const float* __restrict__ resid, int M, int N, int Kd)
{
  __shared__ u16 Ald[2][8192];                        // [128][64] (4 chunks of 32 rows)
  __shared__ u16 Bld[2][4096];                        // [64][64]
  const int tid = threadIdx.x, lane = tid & 63, wv = tid >> 6;
  const int lr = lane & 15, g = lane >> 4;
  const int m0 = blockIdx.x * 128, n0 = blockIdx.y * 64;
  const int wm = wv * 32;
  const int srow = tid >> 3;
  const int sc  = (tid & 7) ^ (srow & 7);
  int b0=0, y0=0;
  if constexpr (CONVC != 0){ b0 = m0>>12; y0 = (m0>>6)&63; }
  const u16* ar[4];
  if constexpr (CONVC == 0){
    #pragma unroll
    for(int j=0;j<4;j++) ar[j] = A + (size_t)(m0+srow+32*j)*Kd + sc*8;
  }
  const u16* br0 = Wt + (size_t)(n0+srow)*Kd + sc*8;
  const u16* br1 = Wt + (size_t)(n0+srow+32)*Kd + sc*8;

  f32x4 acc[2][4];
  #pragma unroll
  for(int i=0;i<2;i++)
    #pragma unroll
    for(int j=0;j<4;j++) acc[i][j] = (f32x4){0.f,0.f,0.f,0.f};

  const int nIter = Kd >> 6;
  int cur = 0;

  auto stage = [&](int kt, int buf){
    const int k0 = kt << 6;
    if constexpr (CONVC != 0){
      const int tap = k0 / CONVC;
      const int ic0 = k0 - tap*CONVC;
      const int ky = tap/3, kx = tap - 3*(tap/3);
      #pragma unroll
      for(int j=0;j<4;j++){
        const int xr = srow + 32*(j&1);
        const int yr = y0 + (j>>1) + ky;
        const u16* ga = A + ((size_t)((b0*66 + yr)*66 + xr + kx))*CONVC + ic0 + sc*8;
        gload16(ga, &Ald[buf][j*2048 + tid*8]);
      }
    } else {
      #pragma unroll
      for(int j=0;j<4;j++) gload16(ar[j] + k0, &Ald[buf][j*2048 + tid*8]);
    }
    gload16(br0 + k0, &Bld[buf][tid*8]);
    gload16(br1 + k0, &Bld[buf][2048 + tid*8]);
  };

  stage(0, 0);
  for(int kt=0; kt<nIter; ++kt){
    __syncthreads();
    if(kt+1 < nIter) stage(kt+1, cur^1);
    short8 af[2][2], bg[4][2];
    #pragma unroll
    for(int mi=0;mi<2;mi++)
      #pragma unroll
      for(int kk=0;kk<2;kk++){
        const int R = wm + mi*16 + lr;
        const int c = kk*4 + g;
        af[mi][kk] = *(const short8*)&Ald[cur][R*64 + ((c ^ (R&7))<<3)];
      }
    #pragma unroll
    for(int nj=0;nj<4;nj++)
      #pragma unroll
      for(int kk=0;kk<2;kk++){
        const int Rn = nj*16 + lr;
        const int c = kk*4 + g;
        bg[nj][kk] = *(const short8*)&Bld[cur][Rn*64 + ((c ^ (Rn&7))<<3)];
      }
    #pragma unroll
    for(int mi=0;mi<2;mi++)
      #pragma unroll
      for(int nj=0;nj<4;nj++)
        #pragma unroll
        for(int kk=0;kk<2;kk++)
          acc[mi][nj] = mfma16(af[mi][kk], bg[nj][kk], acc[mi][nj]);
    cur ^= 1;
  }

  #pragma unroll
  for(int mi=0;mi<2;mi++){
    #pragma unroll
    for(int nj=0;nj<4;nj++){
      #pragma unroll
      for(int r=0;r<4;r++){
        const int mrow = m0 + wm + mi*16 + g*4 + r;
        const int ncol = n0 + nj*16 + lr;
        float val = acc[mi][nj][r] + bias[ncol];
        if constexpr (EPI==5){
          const int b = mrow>>12; const int rr = mrow&4095; const int y = rr>>6; const int xx = rr&63;
          const size_t pidx = ((size_t)(b*1024 + (y>>1)*32 + (xx>>1)))*512 + (y&1)*256 + (xx&1)*128 + ncol;
          ((float*)outp)[pidx] = val;
        } else if constexpr (EPI==6){
          const int b = mrow>>12; const int rr = mrow&4095; const int y = rr>>6; const int xx = rr&63;
          ((float*)outp)[(((size_t)(b*320 + ncol))*64 + y)*64 + xx] = val;
        }
      }
    }
  }
}

// ---------------- wide GEMM for qkv: 128x64 tile, BK=64; q/k scatter; v -> vt directly ----------------
__global__ __launch_bounds__(256, 3)
void k_gemmW(const u16* __restrict__ A, const u16* __restrict__ Wt,
             void* __restrict__ outp, u16* __restrict__ vt, int Kd)
{
  __shared__ u16 Ald[2][8192];                       // [128][64]; reused as Vt bounce tile
  __shared__ u16 Bld[2][4096];                       // [64][64]
  const int tid = threadIdx.x, lane = tid & 63, wv = tid >> 6;
  const int lr = lane & 15, g = lane >> 4;
  const int m0 = blockIdx.x * 128, n0 = blockIdx.y * 64;
  const int wm = wv * 32;
  const int srow = tid >> 3;
  const int sc  = (tid & 7) ^ (srow & 7);
  const u16* ar[4];
  #pragma unroll
  for(int j=0;j<4;j++) ar[j] = A + (size_t)(m0+srow+32*j)*Kd + sc*8;
  const u16* br0 = Wt + (size_t)(n0+srow)*Kd + sc*8;
  const u16* br1 = Wt + (size_t)(n0+srow+32)*Kd + sc*8;

  f32x4 acc[2][4];
  #pragma unroll
  for(int i=0;i<2;i++)
    #pragma unroll
    for(int j=0;j<4;j++) acc[i][j] = (f32x4){0.f,0.f,0.f,0.f};

  const int nIter = Kd >> 6;
  int cur = 0;
  auto stage = [&](int kt, int buf){
    const int k0 = kt << 6;
    #pragma unroll
    for(int j=0;j<4;j++) gload16(ar[j] + k0, &Ald[buf][j*2048 + tid*8]);
    gload16(br0 + k0, &Bld[buf][tid*8]);
    gload16(br1 + k0, &Bld[buf][2048 + tid*8]);
  };

  stage(0, 0);
  for(int kt=0; kt<nIter; ++kt){
    __syncthreads();
    if(kt+1 < nIter) stage(kt+1, cur^1);
    short8 af[2][2], bg[4][2];
    #pragma unroll
    for(int mi=0;mi<2;mi++)
      #pragma unroll
      for(int kk=0;kk<2;kk++){
        const int R = wm + mi*16 + lr;
        const int c = kk*4 + g;
        af[mi][kk] = *(const short8*)&Ald[cur][R*64 + ((c ^ (R&7))<<3)];
      }
    #pragma unroll
    for(int nj=0;nj<4;nj++)
      #pragma unroll
      for(int kk=0;kk<2;kk++){
        const int Rn = nj*16 + lr;
        const int c = kk*4 + g;
        bg[nj][kk] = *(const short8*)&Bld[cur][Rn*64 + ((c ^ (Rn&7))<<3)];
      }
    #pragma unroll
    for(int mi=0;mi<2;mi++)
      #pragma unroll
      for(int nj=0;nj<4;nj++)
        #pragma unroll
        for(int kk=0;kk<2;kk++)
          acc[mi][nj] = mfma16(af[mi][kk], bg[nj][kk], acc[mi][nj]);
    cur ^= 1;
  }

  if(n0 < 1024){
    // q/k scatter epilogue
    #pragma unroll
    for(int mi=0;mi<2;mi++){
      #pragma unroll
      for(int nj=0;nj<4;nj++){
        #pragma unroll
        for(int r=0;r<4;r++){
          const int mrow = m0 + wm + mi*16 + g*4 + r;
          const int ncol = n0 + nj*16 + lr;
          const int sec = ncol >> 9, rem = ncol & 511;
          const int head = rem >> 6, d = rem & 63;
          const int b = mrow >> 10, t = mrow & 1023;
          ((u16*)outp)[(size_t)sec*4194304 + ((size_t)((b*8+head)*1024 + t))*64 + d] = f2bf(acc[mi][nj][r]);
        }
      }
    }
  } else {
    // v block: write vt[bh][d][t] directly via LDS bounce (raw v never materialized)
    const int head = (n0 - 1024) >> 6;
    const int b = m0 >> 10;
    const int t0 = m0 & 1023;
    const int bh = b*8 + head;
    __syncthreads();                                  // all waves done reading Ald
    u16* Vt = (u16*)Ald;                              // [64 d][136] (stride 272B, 16B-aligned)
    #pragma unroll
    for(int mi=0;mi<2;mi++)
      #pragma unroll
      for(int nj=0;nj<4;nj++)
        #pragma unroll
        for(int r=0;r<4;r++){
          const int lt = wm + mi*16 + g*4 + r;
          const int d  = nj*16 + lr;
          Vt[d*136 + lt] = f2bf(acc[mi][nj][r]);
        }
    __syncthreads();
    const int d = tid >> 2, qd = tid & 3;             // 64 d-rows x 4 chunks of 32 t
    u16* dst = vt + (size_t)bh*65536 + (size_t)d*1024 + t0 + qd*32;
    const u16* srcl = &Vt[d*136 + qd*32];
    #pragma unroll
    for(int e4=0;e4<4;e4++)
      *(short8*)(dst + e4*8) = *(const short8*)(srcl + e4*8);
  }
}

// ---------------- attention pass A: global min AND max, 128-q tile, full 16-iter pipeline ----------------
__global__ __launch_bounds__(256, 4)
void k_attn_minmax(const u16* __restrict__ q, const u16* __restrict__ k, u32* __restrict__ keys, int layer){
  const int id = blockIdx.x;                   // 512 blocks
  const int qt = (id>>3)&7;
  const int bh = ((id&7)<<3) | (id>>6);
  __shared__ u16 Kld[2][4096];
  __shared__ float redn[4], redx[4];
  const int tid = threadIdx.x, lane = tid & 63, wv = tid >> 6;
  const int lr = lane & 15, g = lane >> 4;
  const u16* qp0 = q + ((size_t)bh*1024 + qt*128 + wv*16 + lr)*64;
  const u16* qp1 = qp0 + 64*64;
  const short8 qa00 = *(const short8*)(qp0 + g*8);
  const short8 qa01 = *(const short8*)(qp0 + 32 + g*8);
  const short8 qa10 = *(const short8*)(qp1 + g*8);
  const short8 qa11 = *(const short8*)(qp1 + 32 + g*8);
  const u16* kbase = k + (size_t)bh*65536;
  const int srow = tid>>3, scs = lane&7;
  const int scg = scs ^ (srow&7);
  const int srow2 = srow + 32;
  const int scg2 = scs ^ (srow2&7);
  float mn = 3.0e38f, mx = -3.0e38f;
  gload16(kbase + (size_t)srow*64 + scg*8, &Kld[0][wv*512]);
  gload16(kbase + (size_t)srow2*64 + scg2*8, &Kld[0][2048 + wv*512]);
  int cur = 0;
  for(int jt=0; jt<16; ++jt){
    __syncthreads();
    if(jt < 15){
      const int j1 = (jt+1)*64;
      gload16(kbase + (size_t)(j1+srow)*64 + scg*8, &Kld[cur^1][wv*512]);
      gload16(kbase + (size_t)(j1+srow2)*64 + scg2*8, &Kld[cur^1][2048 + wv*512]);
    }
    #pragma unroll
    for(int c=0;c<4;c++){
      const int rr = c*16 + lr;
      const short8 kb0 = *(const short8*)&Kld[cur][rr*64 + ((g ^ (rr&7))<<3)];
      const short8 kb1 = *(const short8*)&Kld[cur][rr*64 + (((g+4) ^ (rr&7))<<3)];
      f32x4 sa = (f32x4){0.f,0.f,0.f,0.f};
      f32x4 sb = (f32x4){0.f,0.f,0.f,0.f};
      __builtin_amdgcn_s_setprio(1);
      sa = mfma16(qa00, kb0, sa);
      sa = mfma16(qa01, kb1, sa);
      sb = mfma16(qa10, kb0, sb);
      sb = mfma16(qa11, kb1, sb);
      __builtin_amdgcn_s_setprio(0);
      mn = fminf(mn, fminf(fminf(sa[0],sa[1]), fminf(sa[2],sa[3])));
      mx = fmaxf(mx, fmaxf(fmaxf(sa[0],sa[1]), fmaxf(sa[2],sa[3])));
      mn = fminf(mn, fminf(fminf(sb[0],sb[1]), fminf(sb[2],sb[3])));
      mx = fmaxf(mx, fmaxf(fmaxf(sb[0],sb[1]), fmaxf(sb[2],sb[3])));
    }
    cur ^= 1;
  }
  mn *= 0.125f; mx *= 0.125f;
  #pragma unroll
  for(int off=32; off; off>>=1){
    mn = fminf(mn, __shfl_down(mn, off));
    mx = fmaxf(mx, __shfl_down(mx, off));
  }
  if(lane==0){ redn[wv] = mn; redx[wv] = mx; }
  __syncthreads();
  if(tid==0){
    atomicMin(keys + layer,     fkey(fminf(fminf(redn[0],redn[1]), fminf(redn[2],redn[3]))));
    atomicMax(keys + 8 + layer, fkey(fmaxf(fmaxf(redx[0],redx[1]), fmaxf(redx[2],redx[3]))));
  }
}

// ---------------- attention pass B: 128-q tile, swapped QK^T, global-shift softmax, packed P ----------------
__global__ __launch_bounds__(256, 3)
void k_attn(const u16* __restrict__ q, const u16* __restrict__ k, const u16* __restrict__ vt,
            const u64* __restrict__ rmbits, const u32* __restrict__ keys,
            u16* __restrict__ o, int layer){
  const int id = blockIdx.x;                   // 512 blocks
  const int qt = (id>>3)&7;
  const int bh = ((id&7)<<3) | (id>>6);
  const int b = bh>>3, h = bh&7;
  __shared__ u16 Kld[2][4096];
  __shared__ u16 Vtld[2][4096];
  __shared__ u32 Pld[4][1024];                 // per-wave [32 qrow][32 u32]
  const int tid = threadIdx.x, lane = tid & 63, wv = tid >> 6;
  const int lr = lane & 15, g = lane >> 4;
  const int L7 = lr & 7;
  const int LH = (lr >> 3) << 2;               // extra swizzle bit: lr/lr+8 split banks
  const u16* qp0 = q + ((size_t)bh*1024 + qt*128 + wv*16 + lr)*64;
  const u16* qp1 = qp0 + 64*64;
  const short8 qa00 = *(const short8*)(qp0 + g*8);
  const short8 qa01 = *(const short8*)(qp0 + 32 + g*8);
  const short8 qa10 = *(const short8*)(qp1 + g*8);
  const short8 qa11 = *(const short8*)(qp1 + 32 + g*8);
  const float L2E = 1.44269504088896f;
  const float SC = 0.125f * L2E;
  float mnv = funkey(keys[layer]);
  float mxv = funkey(keys[8+layer]);
  if(!(mnv >= -1e38f && mnv <= 1e38f)) mnv = 0.f;
  if(!(mxv >= -1e38f && mxv <= 1e38f)) mxv = 0.f;
  const float ME   = mxv * L2E;
  const float minM = fmaxf(mnv*L2E - ME, -120.f);
  const u32* cbp = (const u32*)(rmbits + (size_t)(layer*8 + b)*16);
  const int rowi0 = qt*128 + wv*16 + lr;
  const int rowi1 = rowi0 + 64;
  const u32 rf0 = ((cbp[rowi0>>5] >> (rowi0&31)) & 1u) ? 0xFu : 0u;
  const u32 rf1 = ((cbp[rowi1>>5] >> (rowi1&31)) & 1u) ? 0xFu : 0u;
  u32* Pw = &Pld[wv][0];
  u32 wslot[4][2];
  #pragma unroll
  for(int c=0;c<4;c++){
    const int blk = (c*2 + (g>>1)) ^ L7 ^ LH;
    wslot[c][0] = lr*32 + (blk<<2) + (g&1)*2;
    wslot[c][1] = wslot[c][0] + 1;
  }
  const u32 ra0 = lr*32 + ((g ^ L7 ^ LH)<<2);
  const u32 ra1 = lr*32 + (((4+g) ^ L7 ^ LH)<<2);

  float ls0 = 0.f, ls1 = 0.f;
  f32x4 acc0[4], acc1[4];
  #pragma unroll
  for(int d=0;d<4;d++){ acc0[d] = (f32x4){0.f,0.f,0.f,0.f}; acc1[d] = (f32x4){0.f,0.f,0.f,0.f}; }
  const u16* kbase = k + (size_t)bh*65536;
  const u16* vtbase = vt + (size_t)bh*65536;
  const int srow = tid>>3, scs = lane&7;
  const int scg = scs ^ (srow&7);
  const int srow2 = srow + 32;
  const int scg2 = scs ^ (srow2&7);
  gload16(kbase + (size_t)srow*64 + scg*8, &Kld[0][wv*512]);
  gload16(kbase + (size_t)srow2*64 + scg2*8, &Kld[0][2048 + wv*512]);
  gload16(vtbase + (size_t)srow*1024 + scg*8, &Vtld[0][wv*512]);
  gload16(vtbase + (size_t)srow2*1024 + scg2*8, &Vtld[0][2048 + wv*512]);
  int cur = 0;
  for(int jt=0; jt<16; ++jt){
    __syncthreads();
    if(jt < 15){
      const int j1 = (jt+1)*64;
      gload16(kbase + (size_t)(j1+srow)*64 + scg*8, &Kld[cur^1][wv*512]);
      gload16(kbase + (size_t)(j1+srow2)*64 + scg2*8, &Kld[cur^1][2048 + wv*512]);
      gload16(vtbase + (size_t)srow*1024 + j1 + scg*8, &Vtld[cur^1][wv*512]);
      gload16(vtbase + (size_t)srow2*1024 + j1 + scg2*8, &Vtld[cur^1][2048 + wv*512]);
    }
    const u32 cb_lo = cbp[jt*2], cb_hi = cbp[jt*2+1];
    #pragma unroll
    for(int c=0;c<4;c++){
      const int rr = c*16 + lr;
      const short8 kb0 = *(const short8*)&Kld[cur][rr*64 + ((g ^ (rr&7))<<3)];
      const short8 kb1 = *(const short8*)&Kld[cur][rr*64 + (((g+4) ^ (rr&7))<<3)];
      f32x4 sa = (f32x4){0.f,0.f,0.f,0.f};
      f32x4 sb = (f32x4){0.f,0.f,0.f,0.f};
      __builtin_amdgcn_s_setprio(1);
      sa = mfma16(kb0, qa00, sa);
      sa = mfma16(kb1, qa01, sa);
      sb = mfma16(kb0, qa10, sb);
      sb = mfma16(kb1, qa11, sb);
      __builtin_amdgcn_s_setprio(0);
      const u32 base = (((c<2) ? cb_lo : cb_hi) >> ((c&1)*16 + g*4));
      const u32 cw0 = base | rf0;
      const u32 cw1 = base | rf1;
      float e0[4], e1[4];
      #pragma unroll
      for(int r=0;r<4;r++){
        float sv0 = fmaxf(fmaf(sa[r], SC, -ME), -120.f);
        float sv1 = fmaxf(fmaf(sb[r], SC, -ME), -120.f);
        e0[r] = exp2f(((cw0 >> r) & 1u) ? sv0 : minM);
        e1[r] = exp2f(((cw1 >> r) & 1u) ? sv1 : minM);
        ls0 += e0[r]; ls1 += e1[r];
      }
      Pw[wslot[c][0]]       = cvtpk(e0[0], e0[1]);
      Pw[wslot[c][1]]       = cvtpk(e0[2], e0[3]);
      Pw[512 + wslot[c][0]] = cvtpk(e1[0], e1[1]);
      Pw[512 + wslot[c][1]] = cvtpk(e1[2], e1[3]);
    }
    asm volatile("s_waitcnt lgkmcnt(0)" ::: "memory");
    __builtin_amdgcn_sched_barrier(0);
    const short8 pa00 = *(const short8*)&Pw[ra0];
    const short8 pa01 = *(const short8*)&Pw[ra1];
    const short8 pa10 = *(const short8*)&Pw[512 + ra0];
    const short8 pa11 = *(const short8*)&Pw[512 + ra1];
    #pragma unroll
    for(int d=0;d<4;d++){
      const int rr = d*16 + lr;
      const short8 vb0 = *(const short8*)&Vtld[cur][rr*64 + ((g ^ (rr&7))<<3)];
      const short8 vb1 = *(const short8*)&Vtld[cur][rr*64 + (((g+4) ^ (rr&7))<<3)];
      __builtin_amdgcn_s_setprio(1);
      acc0[d] = mfma16(pa00, vb0, acc0[d]);
      acc0[d] = mfma16(pa01, vb1, acc0[d]);
      acc1[d] = mfma16(pa10, vb0, acc1[d]);
      acc1[d] = mfma16(pa11, vb1, acc1[d]);
      __builtin_amdgcn_s_setprio(0);
    }
    cur ^= 1;
  }
  ls0 += __shfl_xor(ls0, 16); ls0 += __shfl_xor(ls0, 32);
  ls1 += __shfl_xor(ls1, 16); ls1 += __shfl_xor(ls1, 32);
  float inv0[4], inv1[4];
  #pragma unroll
  for(int r=0;r<4;r++){ inv0[r] = 1.f / __shfl(ls0, g*4 + r); inv1[r] = 1.f / __shfl(ls1, g*4 + r); }
  #pragma unroll
  for(int d=0;d<4;d++)
    #pragma unroll
    for(int r=0;r<4;r++){
      const int qr0 = qt*128 + wv*16 + g*4 + r;
      o[((size_t)b*1024 + qr0)*512 + h*64 + d*16 + lr]        = f2bf(acc0[d][r] * inv0[r]);
      o[((size_t)b*1024 + qr0 + 64)*512 + h*64 + d*16 + lr]   = f2bf(acc1[d][r] * inv1[r]);
    }
}

// ---------------- host ----------------
extern "C" void kernel_launch(void* const* d_in, const int* in_sizes, int n_in,
                              void* d_out, int out_size, void* d_ws, size_t ws_size,
                              hipStream_t stream)
{
  const float* img     = (const float*)d_in[0];
  const int*   mask    = (const int*)d_in[1];
  const float* conv1_w = (const float*)d_in[2];
  const float* conv1_b = (const float*)d_in[3];
  const float* ln_p_g  = (const float*)d_in[4];
  const float* ln_p_b  = (const float*)d_in[5];
  const float* proj_w  = (const float*)d_in[6];
  const float* proj_b  = (const float*)d_in[7];
  const float* ln_q_g  = (const float*)d_in[8];
  const float* ln_q_b  = (const float*)d_in[9];
  const float* attn_ln_g = (const float*)d_in[10];
  const float* attn_ln_b = (const float*)d_in[11];
  const float* wqkv    = (const float*)d_in[12];
  const float* wo      = (const float*)d_in[13];
  const float* ff_ln_g = (const float*)d_in[14];
  const float* ff_ln_b = (const float*)d_in[15];
  const float* w1      = (const float*)d_in[16];
  const float* b1      = (const float*)d_in[17];
  const float* w2      = (const float*)d_in[18];
  const float* b2      = (const float*)d_in[19];
  const float* conv2_w = (const float*)d_in[20];
  const float* conv2_b = (const float*)d_in[21];

  if(ws_size < WS_NEED) return;
  char* ws = (char*)d_ws;
  u16* projWt = (u16*)(ws + O_PROJW);
  u16* qkvWt  = (u16*)(ws + O_QKVW);
  u16* woWt   = (u16*)(ws + O_WOW);
  u16* w1Wt   = (u16*)(ws + O_W1W);
  u16* w2Wt   = (u16*)(ws + O_W2W);
  u16* c1Wt   = (u16*)(ws + O_C1W);
  u16* c2Wt   = (u16*)(ws + O_C2W);
  u16* pcl    = (u16*)(ws + O_RA);      // pcl1 / vt / pcl2
  float* tmpf = (float*)(ws + O_RA);
  u16* vtb    = (u16*)(ws + O_RA);      // v^T during layer loop
  float* patches = (float*)(ws + O_RB);
  u16* qkvb   = (u16*)(ws + O_RB);      // q|k (v folded into vt), each 8*8*1024*64
  float* xbuf = (float*)(ws + O_X);
  u16* xnbf   = (u16*)(ws + O_D);
  u16* obf    = (u16*)(ws + O_F);
  u32* minbuf = (u32*)(ws + O_MIN);
  u64* rmbits = (u64*)(ws + O_RMB);

  hipMemsetAsync(ws + O_MIN, 0xFF, 32, stream);       // min keys -> UINT_MAX
  hipMemsetAsync(ws + O_MIN + 32, 0, 32, stream);     // max keys -> 0
  hipMemsetAsync(ws + O_RA, 0, 22302720, stream);     // pcl1 zero borders

  // weight conversion
  k_transpose_bf<<<dim3(16,16,1),256,0,stream>>>(proj_w, projWt, 512, 512);
  k_transpose_bf<<<dim3(16,48,6),256,0,stream>>>(wqkv,   qkvWt,  512, 1536);
  k_transpose_bf<<<dim3(16,16,6),256,0,stream>>>(wo,     woWt,   512, 512);
  k_transpose_bf<<<dim3(16,16,6),256,0,stream>>>(w1,     w1Wt,   512, 512);
  k_transpose_bf<<<dim3(16,16,6),256,0,stream>>>(w2,     w2Wt,   512, 512);
  k_convw<<<1440,256,0,stream>>>(conv1_w, c1Wt, 128, 320);
  k_convw<<<1440,256,0,stream>>>(conv2_w, c2Wt, 320, 128);
  k_rmask<<<192,256,0,stream>>>(mask, rmbits);

  // patch embed
  k_pad_img<<<dim3(512,5),256,0,stream>>>(img, pcl);
  k_gemm<5,320><<<dim3(256,2),256,0,stream>>>(pcl, c1Wt, conv1_b, patches, nullptr, 32768, 128, 2880);
  k_ln_bf<<<2048,256,0,stream>>>(patches, ln_p_g, ln_p_b, xnbf);
  k_gemm64<0><<<dim3(128,8),256,0,stream>>>(xnbf, projWt, proj_b, tmpf, nullptr, 512);
  k_lnq_pos<<<2048,256,0,stream>>>(tmpf, ln_q_g, ln_q_b, xbuf);

  const u16* qb = qkvb;
  const u16* kb = qkvb + 4194304;
  for(int i=0;i<6;i++){
    k_ln_bf<<<2048,256,0,stream>>>(xbuf, attn_ln_g + i*512, attn_ln_b + i*512, xnbf);
    k_gemmW<<<dim3(64,24),256,0,stream>>>(xnbf, qkvWt + (size_t)i*1536*512, qkvb, vtb, 512);
    k_attn_minmax<<<512,256,0,stream>>>(qb, kb, minbuf, i);
    k_attn<<<512,256,0,stream>>>(qb, kb, vtb, rmbits, minbuf, obf, i);
    k_gemm64<2><<<dim3(128,8),256,0,stream>>>(obf, woWt + (size_t)i*512*512, nullptr, xbuf, xbuf, 512);
    k_ln_bf<<<2048,256,0,stream>>>(xbuf, ff_ln_g + i*512, ff_ln_b + i*512, xnbf);
    k_gemm64<3><<<dim3(128,8),256,0,stream>>>(xnbf, w1Wt + (size_t)i*512*512, b1 + i*512, obf, nullptr, 512);
    k_gemm64<4><<<dim3(128,8),256,0,stream>>>(obf, w2Wt + (size_t)i*512*512, b2 + i*512, xbuf, xbuf, 512);
  }

  // final conv
  hipMemsetAsync(ws + O_RA, 0, 8921088, stream);    // pcl2 zero borders
  k_pad_tok<<<16384,256,0,stream>>>(xbuf, pcl);
  k_gemm<6,128><<<dim3(256,5),256,0,stream>>>(pcl, c2Wt, conv2_b, d_out, nullptr, 32768, 320, 1152);
}

// Round 14
// 936.119 us; speedup vs baseline: 1.2090x; 1.0269x over previous
//
#include <hip/hip_runtime.h>
#include <hip/hip_bf16.h>
#include <math.h>

typedef __attribute__((ext_vector_type(8))) short short8;
typedef __attribute__((ext_vector_type(4))) float f32x4;
typedef unsigned short u16;
typedef unsigned int u32;
typedef unsigned long long u64;

#define DEV __device__ __forceinline__

DEV float bf2f(u16 u){ u32 x = ((u32)u)<<16; return __builtin_bit_cast(float, x); }
DEV u16 f2bf(float f){ u32 x = __builtin_bit_cast(u32, f); return (u16)((x + 0x7FFFu + ((x>>16)&1u))>>16); }
DEV f32x4 mfma16(short8 a, short8 b, f32x4 c){ return __builtin_amdgcn_mfma_f32_16x16x32_bf16(a,b,c,0,0,0); }
DEV void gload16(const void* g, void* l){
  __builtin_amdgcn_global_load_lds((const __attribute__((address_space(1))) void*)g,
                                   (__attribute__((address_space(3))) void*)l, 16, 0, 0);
}
DEV u32 fkey(float f){ u32 b = __builtin_bit_cast(u32, f); return (b & 0x80000000u) ? ~b : (b ^ 0x80000000u); }
DEV float funkey(u32 k){ u32 b = (k & 0x80000000u) ? (k ^ 0x80000000u) : ~k; return __builtin_bit_cast(float, b); }
DEV u32 cvtpk(float lo, float hi){ u32 d; asm("v_cvt_pk_bf16_f32 %0, %1, %2" : "=v"(d) : "v"(lo), "v"(hi)); return d; }

// ---------------- workspace layout (bytes) ----------------
static constexpr size_t O_PROJW = 0;                         // 512*512*2
static constexpr size_t O_QKVW  = O_PROJW + 524288;          // 6*1536*512*2
static constexpr size_t O_WOW   = O_QKVW + 9437184;          // 6*512*512*2
static constexpr size_t O_W1W   = O_WOW + 3145728;
static constexpr size_t O_W2W   = O_W1W + 3145728;
static constexpr size_t O_C1W   = O_W2W + 3145728;           // 128*2880*2
static constexpr size_t O_C2W   = O_C1W + 737280;            // 320*1152*2
static constexpr size_t O_RA    = O_C2W + 737280;            // pcl1 22.3MB / tmp f32 / vt 8.4MB / pcl2
static constexpr size_t O_RB    = O_RA + 22302720;           // patches f32 16.8MB then qkv bf16 25.2MB
static constexpr size_t O_X     = O_RB + 25165824;           // x f32 16.8MB
static constexpr size_t O_D     = O_X + 16777216;            // xn bf16 8.4MB
static constexpr size_t O_F     = O_D + 8388608;             // o/g bf16 8.4MB
static constexpr size_t O_RM    = O_F + 8388608;             // 48*1024 u8
static constexpr size_t O_MIN   = O_RM + 49152;              // min keys [0..5], max keys [8..13]
static constexpr size_t O_RMB   = O_MIN + 256;               // 48*16 u64 bit-packed masks
static constexpr size_t WS_NEED = O_RMB + 8192;

// ---------------- weight conversion ----------------
// src [z][K][N] f32 -> dst [z][N][K] bf16
__global__ __launch_bounds__(256) void k_transpose_bf(const float* __restrict__ src, u16* __restrict__ dst, int K, int N){
  __shared__ float tile[32][33];
  const int k0 = blockIdx.x*32, n0 = blockIdx.y*32;
  src += (size_t)blockIdx.z*K*N; dst += (size_t)blockIdx.z*K*N;
  const int c = threadIdx.x & 31, r4 = threadIdx.x >> 5;
  for(int r=r4; r<32; r+=8) tile[r][c] = src[(size_t)(k0+r)*N + n0+c];
  __syncthreads();
  for(int r=r4; r<32; r+=8) dst[(size_t)(n0+r)*K + k0+c] = f2bf(tile[c][r]);
}

// conv weights [OC][IC][3][3] f32 -> Wt [OC][tap*IC+ic] bf16
__global__ __launch_bounds__(256) void k_convw(const float* __restrict__ src, u16* __restrict__ dst, int OC, int IC){
  int idx = blockIdx.x*256 + threadIdx.x;
  int total = OC*IC*9;
  if(idx >= total) return;
  int oc = idx/(IC*9); int rem = idx - oc*IC*9; int tap = rem/IC; int ic = rem - tap*IC;
  dst[idx] = f2bf(src[(size_t)(oc*IC+ic)*9 + tap]);
}

// img [8][320][64][64] f32 -> pcl1 [8][66][66][320] bf16 (interior; borders pre-zeroed)
__global__ __launch_bounds__(256) void k_pad_img(const float* __restrict__ img, u16* __restrict__ pcl){
  const int by = blockIdx.x; const int b = by>>6, y = by&63; const int c0 = blockIdx.y*64;
  __shared__ float t[64][65];
  const int tx = threadIdx.x & 63, tz = threadIdx.x >> 6;
  for(int ci=tz; ci<64; ci+=4) t[ci][tx] = img[(((size_t)b*320 + c0+ci)*64 + y)*64 + tx];
  __syncthreads();
  for(int x=tz; x<64; x+=4) pcl[(((size_t)b*66 + y+1)*66 + (x+1))*320 + c0 + tx] = f2bf(t[tx][x]);
}

// x tokens f32 -> pcl2 [8][66][66][128] bf16 (interior)
__global__ __launch_bounds__(256) void k_pad_tok(const float* __restrict__ x, u16* __restrict__ pcl){
  int idx = blockIdx.x*256 + threadIdx.x;           // 8*64*64*128
  const int c = idx & 127; int r = idx >> 7; const int xx = r & 63; r >>= 6; const int yy = r & 63; const int b = r >> 6;
  const int n = (yy>>1)*32 + (xx>>1); const int f = (yy&1)*256 + (xx&1)*128 + c;
  pcl[(((size_t)b*66 + yy+1)*66 + xx+1)*128 + c] = f2bf(x[((size_t)b*1024 + n)*512 + f]);
}

// mask [48][64][64] int -> rmbits [48][16] u64 (2x2 any)
__global__ __launch_bounds__(256) void k_rmask(const int* __restrict__ mask, u64* __restrict__ rmbits){
  int idx = blockIdx.x*256 + threadIdx.x;
  const int m = idx >> 10, n = idx & 1023; const int h = n>>5, w = n&31;
  const int* mp = mask + ((size_t)m*64 + h*2)*64 + w*2;
  const int v = (mp[0]==1) | (mp[1]==1) | (mp[64]==1) | (mp[65]==1);
  const u64 bm = __ballot(v);
  if((threadIdx.x & 63) == 0) rmbits[idx>>6] = bm;
}

// ---------------- layernorm (wave per token) ----------------
__global__ __launch_bounds__(256) void k_ln_bf(const float* __restrict__ in, const float* __restrict__ gw,
                                               const float* __restrict__ bw, u16* __restrict__ out){
  const int tok = blockIdx.x*4 + (threadIdx.x>>6);
  const int lane = threadIdx.x & 63;
  const float* rp = in + (size_t)tok*512 + lane*8;
  const float4 a = *(const float4*)rp;
  const float4 b = *(const float4*)(rp+4);
  float s  = a.x+a.y+a.z+a.w + b.x+b.y+b.z+b.w;
  float sq = a.x*a.x+a.y*a.y+a.z*a.z+a.w*a.w + b.x*b.x+b.y*b.y+b.z*b.z+b.w*b.w;
  #pragma unroll
  for(int off=1; off<64; off<<=1){ s += __shfl_xor(s,off); sq += __shfl_xor(sq,off); }
  const float mu = s*(1.f/512.f);
  const float rs = rsqrtf(fmaxf(sq*(1.f/512.f) - mu*mu, 0.f) + 1e-5f);
  const float4 g0 = *(const float4*)(gw + lane*8);
  const float4 g1 = *(const float4*)(gw + lane*8 + 4);
  const float4 b0 = *(const float4*)(bw + lane*8);
  const float4 b1 = *(const float4*)(bw + lane*8 + 4);
  short8 o8;
  o8[0]=f2bf((a.x-mu)*rs*g0.x+b0.x); o8[1]=f2bf((a.y-mu)*rs*g0.y+b0.y);
  o8[2]=f2bf((a.z-mu)*rs*g0.z+b0.z); o8[3]=f2bf((a.w-mu)*rs*g0.w+b0.w);
  o8[4]=f2bf((b.x-mu)*rs*g1.x+b1.x); o8[5]=f2bf((b.y-mu)*rs*g1.y+b1.y);
  o8[6]=f2bf((b.z-mu)*rs*g1.z+b1.z); o8[7]=f2bf((b.w-mu)*rs*g1.w+b1.w);
  *(short8*)(out + (size_t)tok*512 + lane*8) = o8;
}

// LN + sincos 2d posemb -> f32 x (wave per token)
__global__ __launch_bounds__(256) void k_lnq_pos(const float* __restrict__ in, const float* __restrict__ gw,
                                                 const float* __restrict__ bw, float* __restrict__ out){
  const int tok = blockIdx.x*4 + (threadIdx.x>>6);
  const int lane = threadIdx.x & 63;
  const float* rp = in + (size_t)tok*512 + lane*8;
  const float4 a = *(const float4*)rp;
  const float4 b = *(const float4*)(rp+4);
  float s  = a.x+a.y+a.z+a.w + b.x+b.y+b.z+b.w;
  float sq = a.x*a.x+a.y*a.y+a.z*a.z+a.w*a.w + b.x*b.x+b.y*b.y+b.z*b.z+b.w*b.w;
  #pragma unroll
  for(int off=1; off<64; off<<=1){ s += __shfl_xor(s,off); sq += __shfl_xor(sq,off); }
  const float mu = s*(1.f/512.f);
  const float rs = rsqrtf(fmaxf(sq*(1.f/512.f) - mu*mu, 0.f) + 1e-5f);
  const int n = tok & 1023; const int yy = n>>5, xx = n&31;
  const int f0 = lane*8; const int sec = f0>>7;
  const float coord = (sec<2) ? (float)xx : (float)yy;
  const float vv[8] = {a.x,a.y,a.z,a.w,b.x,b.y,b.z,b.w};
  float ov[8];
  #pragma unroll
  for(int j=0;j<8;j++){
    const int f = f0+j; const int qq = f & 127;
    const float om = __expf(-(float)qq * (9.2103403719761836f/127.f));
    const float arg = coord * om;
    const float pe = (sec&1) ? __cosf(arg) : __sinf(arg);
    ov[j] = (vv[j]-mu)*rs*gw[f] + bw[f] + pe;
  }
  float* op = out + (size_t)tok*512 + f0;
  *(float4*)op = (float4){ov[0],ov[1],ov[2],ov[3]};
  *(float4*)(op+4) = (float4){ov[4],ov[5],ov[6],ov[7]};
}

// ---------------- GEMM 64x64 tile (4 blocks/CU) for N=512 layers ----------------
// EPI: 0 proj(f32+bias) 2 resid(f32) 3 gelu(bf16+bias) 4 resid+bias
template<int EPI>
__global__ __launch_bounds__(256, 4)
void k_gemm64(const u16* __restrict__ A, const u16* __restrict__ Wt,
              const float* __restrict__ bias, void* __restrict__ outp,
              const float* __restrict__ resid, int Kd)
{
  __shared__ u16 Ald[2][4096];
  __shared__ u16 Bld[2][4096];
  const int tid = threadIdx.x, lane = tid & 63, wv = tid >> 6;
  const int lr = lane & 15, g = lane >> 4;
  const int m0 = blockIdx.x * 64, n0 = blockIdx.y * 64;
  const int wm = (wv >> 1) * 32, wn = (wv & 1) * 32;
  const int srow = tid >> 3;
  const int sc  = (tid & 7) ^ (srow & 7);
  const u16* arow0p = A + (size_t)(m0+srow)*Kd + sc*8;
  const u16* arow1p = A + (size_t)(m0+srow+32)*Kd + sc*8;
  const u16* brow0p = Wt + (size_t)(n0+srow)*Kd + sc*8;
  const u16* brow1p = Wt + (size_t)(n0+srow+32)*Kd + sc*8;

  f32x4 acc[2][2];
  #pragma unroll
  for(int i=0;i<2;i++)
    #pragma unroll
    for(int j=0;j<2;j++) acc[i][j] = (f32x4){0.f,0.f,0.f,0.f};

  const int nIter = Kd >> 6;
  int cur = 0;
  auto stage = [&](int kt, int buf){
    const int k0 = kt << 6;
    gload16(arow0p + k0, &Ald[buf][tid*8]);
    gload16(arow1p + k0, &Ald[buf][2048 + tid*8]);
    gload16(brow0p + k0, &Bld[buf][tid*8]);
    gload16(brow1p + k0, &Bld[buf][2048 + tid*8]);
  };

  stage(0, 0);
  for(int kt=0; kt<nIter; ++kt){
    __syncthreads();
    if(kt+1 < nIter) stage(kt+1, cur^1);
    short8 af[2][2], bg[2][2];
    #pragma unroll
    for(int mi=0;mi<2;mi++)
      #pragma unroll
      for(int kk=0;kk<2;kk++){
        const int R = wm + mi*16 + lr;
        const int Rn = wn + mi*16 + lr;
        const int c = kk*4 + g;
        af[mi][kk] = *(const short8*)&Ald[cur][R*64 + ((c ^ (R&7))<<3)];
        bg[mi][kk] = *(const short8*)&Bld[cur][Rn*64 + ((c ^ (Rn&7))<<3)];
      }
    #pragma unroll
    for(int mi=0;mi<2;mi++)
      #pragma unroll
      for(int nj=0;nj<2;nj++)
        #pragma unroll
        for(int kk=0;kk<2;kk++)
          acc[mi][nj] = mfma16(af[mi][kk], bg[nj][kk], acc[mi][nj]);
    cur ^= 1;
  }

  #pragma unroll
  for(int mi=0;mi<2;mi++){
    #pragma unroll
    for(int nj=0;nj<2;nj++){
      #pragma unroll
      for(int r=0;r<4;r++){
        const int mrow = m0 + wm + mi*16 + g*4 + r;
        const int ncol = n0 + wn + nj*16 + lr;
        float val = acc[mi][nj][r];
        if constexpr (EPI==0 || EPI==3 || EPI==4)
          val += bias[ncol];
        if constexpr (EPI==0){
          ((float*)outp)[(size_t)mrow*512 + ncol] = val;
        } else if constexpr (EPI==2 || EPI==4){
          const size_t idx = (size_t)mrow*512 + ncol;
          ((float*)outp)[idx] = resid[idx] + val;
        } else if constexpr (EPI==3){
          const float gl = 0.5f * val * (1.f + erff(val * 0.70710678118654752f));
          ((u16*)outp)[(size_t)mrow*512 + ncol] = f2bf(gl);
        }
      }
    }
  }
}

// ---------------- wide GEMM (128x64 tile) for convs ----------------
// EPI: 5 conv1->patches 6 conv2->out
template<int EPI, int CONVC>
__global__ __launch_bounds__(256, 3)
void k_gemm(const u16* __restrict__ A, const u16* __restrict__ Wt,
            const float* __restrict__ bias, void* __restrict__ outp,
            const float* __restrict__ resid, int M, int N, int Kd)
{
  __shared__ u16 Ald[2][8192];                        // [128][64] (4 chunks of 32 rows)
  __shared__ u16 Bld[2][4096];                        // [64][64]
  const int tid = threadIdx.x, lane = tid & 63, wv = tid >> 6;
  const int lr = lane & 15, g = lane >> 4;
  const int m0 = blockIdx.x * 128, n0 = blockIdx.y * 64;
  const int wm = wv * 32;
  const int srow = tid >> 3;
  const int sc  = (tid & 7) ^ (srow & 7);
  int b0=0, y0=0;
  if constexpr (CONVC != 0){ b0 = m0>>12; y0 = (m0>>6)&63; }
  const u16* ar[4];
  if constexpr (CONVC == 0){
    #pragma unroll
    for(int j=0;j<4;j++) ar[j] = A + (size_t)(m0+srow+32*j)*Kd + sc*8;
  }
  const u16* br0 = Wt + (size_t)(n0+srow)*Kd + sc*8;
  const u16* br1 = Wt + (size_t)(n0+srow+32)*Kd + sc*8;

  f32x4 acc[2][4];
  #pragma unroll
  for(int i=0;i<2;i++)
    #pragma unroll
    for(int j=0;j<4;j++) acc[i][j] = (f32x4){0.f,0.f,0.f,0.f};

  const int nIter = Kd >> 6;
  int cur = 0;

  auto stage = [&](int kt, int buf){
    const int k0 = kt << 6;
    if constexpr (CONVC != 0){
      const int tap = k0 / CONVC;
      const int ic0 = k0 - tap*CONVC;
      const int ky = tap/3, kx = tap - 3*(tap/3);
      #pragma unroll
      for(int j=0;j<4;j++){
        const int xr = srow + 32*(j&1);
        const int yr = y0 + (j>>1) + ky;
        const u16* ga = A + ((size_t)((b0*66 + yr)*66 + xr + kx))*CONVC + ic0 + sc*8;
        gload16(ga, &Ald[buf][j*2048 + tid*8]);
      }
    } else {
      #pragma unroll
      for(int j=0;j<4;j++) gload16(ar[j] + k0, &Ald[buf][j*2048 + tid*8]);
    }
    gload16(br0 + k0, &Bld[buf][tid*8]);
    gload16(br1 + k0, &Bld[buf][2048 + tid*8]);
  };

  stage(0, 0);
  for(int kt=0; kt<nIter; ++kt){
    __syncthreads();
    if(kt+1 < nIter) stage(kt+1, cur^1);
    short8 af[2][2], bg[4][2];
    #pragma unroll
    for(int mi=0;mi<2;mi++)
      #pragma unroll
      for(int kk=0;kk<2;kk++){
        const int R = wm + mi*16 + lr;
        const int c = kk*4 + g;
        af[mi][kk] = *(const short8*)&Ald[cur][R*64 + ((c ^ (R&7))<<3)];
      }
    #pragma unroll
    for(int nj=0;nj<4;nj++)
      #pragma unroll
      for(int kk=0;kk<2;kk++){
        const int Rn = nj*16 + lr;
        const int c = kk*4 + g;
        bg[nj][kk] = *(const short8*)&Bld[cur][Rn*64 + ((c ^ (Rn&7))<<3)];
      }
    #pragma unroll
    for(int mi=0;mi<2;mi++)
      #pragma unroll
      for(int nj=0;nj<4;nj++)
        #pragma unroll
        for(int kk=0;kk<2;kk++)
          acc[mi][nj] = mfma16(af[mi][kk], bg[nj][kk], acc[mi][nj]);
    cur ^= 1;
  }

  #pragma unroll
  for(int mi=0;mi<2;mi++){
    #pragma unroll
    for(int nj=0;nj<4;nj++){
      #pragma unroll
      for(int r=0;r<4;r++){
        const int mrow = m0 + wm + mi*16 + g*4 + r;
        const int ncol = n0 + nj*16 + lr;
        float val = acc[mi][nj][r] + bias[ncol];
        if constexpr (EPI==5){
          const int b = mrow>>12; const int rr = mrow&4095; const int y = rr>>6; const int xx = rr&63;
          const size_t pidx = ((size_t)(b*1024 + (y>>1)*32 + (xx>>1)))*512 + (y&1)*256 + (xx&1)*128 + ncol;
          ((float*)outp)[pidx] = val;
        } else if constexpr (EPI==6){
          const int b = mrow>>12; const int rr = mrow&4095; const int y = rr>>6; const int xx = rr&63;
          ((float*)outp)[(((size_t)(b*320 + ncol))*64 + y)*64 + xx] = val;
        }
      }
    }
  }
}

// ---------------- wide GEMM for qkv: 128x64 tile, BK=64; q/k scatter; v -> vt directly ----------------
__global__ __launch_bounds__(256, 3)
void k_gemmW(const u16* __restrict__ A, const u16* __restrict__ Wt,
             void* __restrict__ outp, u16* __restrict__ vt, int Kd)
{
  __shared__ u16 Ald[2][8192];                       // [128][64]; reused as Vt bounce tile
  __shared__ u16 Bld[2][4096];                       // [64][64]
  const int tid = threadIdx.x, lane = tid & 63, wv = tid >> 6;
  const int lr = lane & 15, g = lane >> 4;
  const int m0 = blockIdx.x * 128, n0 = blockIdx.y * 64;
  const int wm = wv * 32;
  const int srow = tid >> 3;
  const int sc  = (tid & 7) ^ (srow & 7);
  const u16* ar[4];
  #pragma unroll
  for(int j=0;j<4;j++) ar[j] = A + (size_t)(m0+srow+32*j)*Kd + sc*8;
  const u16* br0 = Wt + (size_t)(n0+srow)*Kd + sc*8;
  const u16* br1 = Wt + (size_t)(n0+srow+32)*Kd + sc*8;

  f32x4 acc[2][4];
  #pragma unroll
  for(int i=0;i<2;i++)
    #pragma unroll
    for(int j=0;j<4;j++) acc[i][j] = (f32x4){0.f,0.f,0.f,0.f};

  const int nIter = Kd >> 6;
  int cur = 0;
  auto stage = [&](int kt, int buf){
    const int k0 = kt << 6;
    #pragma unroll
    for(int j=0;j<4;j++) gload16(ar[j] + k0, &Ald[buf][j*2048 + tid*8]);
    gload16(br0 + k0, &Bld[buf][tid*8]);
    gload16(br1 + k0, &Bld[buf][2048 + tid*8]);
  };

  stage(0, 0);
  for(int kt=0; kt<nIter; ++kt){
    __syncthreads();
    if(kt+1 < nIter) stage(kt+1, cur^1);
    short8 af[2][2], bg[4][2];
    #pragma unroll
    for(int mi=0;mi<2;mi++)
      #pragma unroll
      for(int kk=0;kk<2;kk++){
        const int R = wm + mi*16 + lr;
        const int c = kk*4 + g;
        af[mi][kk] = *(const short8*)&Ald[cur][R*64 + ((c ^ (R&7))<<3)];
      }
    #pragma unroll
    for(int nj=0;nj<4;nj++)
      #pragma unroll
      for(int kk=0;kk<2;kk++){
        const int Rn = nj*16 + lr;
        const int c = kk*4 + g;
        bg[nj][kk] = *(const short8*)&Bld[cur][Rn*64 + ((c ^ (Rn&7))<<3)];
      }
    #pragma unroll
    for(int mi=0;mi<2;mi++)
      #pragma unroll
      for(int nj=0;nj<4;nj++)
        #pragma unroll
        for(int kk=0;kk<2;kk++)
          acc[mi][nj] = mfma16(af[mi][kk], bg[nj][kk], acc[mi][nj]);
    cur ^= 1;
  }

  if(n0 < 1024){
    // q/k scatter epilogue
    #pragma unroll
    for(int mi=0;mi<2;mi++){
      #pragma unroll
      for(int nj=0;nj<4;nj++){
        #pragma unroll
        for(int r=0;r<4;r++){
          const int mrow = m0 + wm + mi*16 + g*4 + r;
          const int ncol = n0 + nj*16 + lr;
          const int sec = ncol >> 9, rem = ncol & 511;
          const int head = rem >> 6, d = rem & 63;
          const int b = mrow >> 10, t = mrow & 1023;
          ((u16*)outp)[(size_t)sec*4194304 + ((size_t)((b*8+head)*1024 + t))*64 + d] = f2bf(acc[mi][nj][r]);
        }
      }
    }
  } else {
    // v block: write vt[bh][d][t] directly via LDS bounce (raw v never materialized)
    const int head = (n0 - 1024) >> 6;
    const int b = m0 >> 10;
    const int t0 = m0 & 1023;
    const int bh = b*8 + head;
    __syncthreads();                                  // all waves done reading Ald
    u16* Vt = (u16*)Ald;                              // [64 d][136] (stride 272B, 16B-aligned)
    #pragma unroll
    for(int mi=0;mi<2;mi++)
      #pragma unroll
      for(int nj=0;nj<4;nj++)
        #pragma unroll
        for(int r=0;r<4;r++){
          const int lt = wm + mi*16 + g*4 + r;
          const int d  = nj*16 + lr;
          Vt[d*136 + lt] = f2bf(acc[mi][nj][r]);
        }
    __syncthreads();
    const int d = tid >> 2, qd = tid & 3;             // 64 d-rows x 4 chunks of 32 t
    u16* dst = vt + (size_t)bh*65536 + (size_t)d*1024 + t0 + qd*32;
    const u16* srcl = &Vt[d*136 + qd*32];
    #pragma unroll
    for(int e4=0;e4<4;e4++)
      *(short8*)(dst + e4*8) = *(const short8*)(srcl + e4*8);
  }
}

// ---------------- attention pass A: global min AND max, 128-q tile, 128-j staged (8 barriers) ----------------
__global__ __launch_bounds__(256, 4)
void k_attn_minmax(const u16* __restrict__ q, const u16* __restrict__ k, u32* __restrict__ keys, int layer){
  const int id = blockIdx.x;                   // 512 blocks
  const int qt = (id>>3)&7;
  const int bh = ((id&7)<<3) | (id>>6);
  __shared__ u16 Kld[2][8192];                 // [2 buf][2 sub][64 rows][64]
  __shared__ float redn[4], redx[4];
  const int tid = threadIdx.x, lane = tid & 63, wv = tid >> 6;
  const int lr = lane & 15, g = lane >> 4;
  const u16* qp0 = q + ((size_t)bh*1024 + qt*128 + wv*16 + lr)*64;
  const u16* qp1 = qp0 + 64*64;
  const short8 qa00 = *(const short8*)(qp0 + g*8);
  const short8 qa01 = *(const short8*)(qp0 + 32 + g*8);
  const short8 qa10 = *(const short8*)(qp1 + g*8);
  const short8 qa11 = *(const short8*)(qp1 + 32 + g*8);
  const u16* kbase = k + (size_t)bh*65536;
  const int srow = tid>>3, scs = lane&7;
  const int scg = scs ^ (srow&7);
  float mn = 3.0e38f, mx = -3.0e38f;
  auto stageK = [&](int jt, int buf){
    const int j0 = jt << 7;
    #pragma unroll
    for(int j=0;j<4;j++)
      gload16(kbase + (size_t)(j0 + srow + 32*j)*64 + scg*8, &Kld[buf][j*2048 + tid*8]);
  };
  stageK(0, 0);
  int cur = 0;
  for(int jt=0; jt<8; ++jt){
    __syncthreads();
    if(jt < 7) stageK(jt+1, cur^1);
    #pragma unroll
    for(int s=0;s<2;s++){
      const u16* Kp = &Kld[cur][s*4096];
      #pragma unroll
      for(int c=0;c<4;c++){
        const int rr = c*16 + lr;
        const short8 kb0 = *(const short8*)&Kp[rr*64 + ((g ^ (rr&7))<<3)];
        const short8 kb1 = *(const short8*)&Kp[rr*64 + (((g+4) ^ (rr&7))<<3)];
        f32x4 sa = (f32x4){0.f,0.f,0.f,0.f};
        f32x4 sb = (f32x4){0.f,0.f,0.f,0.f};
        __builtin_amdgcn_s_setprio(1);
        sa = mfma16(qa00, kb0, sa);
        sa = mfma16(qa01, kb1, sa);
        sb = mfma16(qa10, kb0, sb);
        sb = mfma16(qa11, kb1, sb);
        __builtin_amdgcn_s_setprio(0);
        mn = fminf(mn, fminf(fminf(sa[0],sa[1]), fminf(sa[2],sa[3])));
        mx = fmaxf(mx, fmaxf(fmaxf(sa[0],sa[1]), fmaxf(sa[2],sa[3])));
        mn = fminf(mn, fminf(fminf(sb[0],sb[1]), fminf(sb[2],sb[3])));
        mx = fmaxf(mx, fmaxf(fmaxf(sb[0],sb[1]), fmaxf(sb[2],sb[3])));
      }
    }
    cur ^= 1;
  }
  mn *= 0.125f; mx *= 0.125f;
  #pragma unroll
  for(int off=32; off; off>>=1){
    mn = fminf(mn, __shfl_down(mn, off));
    mx = fmaxf(mx, __shfl_down(mx, off));
  }
  if(lane==0){ redn[wv] = mn; redx[wv] = mx; }
  __syncthreads();
  if(tid==0){
    atomicMin(keys + layer,     fkey(fminf(fminf(redn[0],redn[1]), fminf(redn[2],redn[3]))));
    atomicMax(keys + 8 + layer, fkey(fmaxf(fmaxf(redx[0],redx[1]), fmaxf(redx[2],redx[3]))));
  }
}

// ---------------- attention pass B: 128-q tile, 128-j staged (8 barriers), swapped QK^T, packed P ----------------
__global__ __launch_bounds__(256, 2)
void k_attn(const u16* __restrict__ q, const u16* __restrict__ k, const u16* __restrict__ vt,
            const u64* __restrict__ rmbits, const u32* __restrict__ keys,
            u16* __restrict__ o, int layer){
  const int id = blockIdx.x;                   // 512 blocks
  const int qt = (id>>3)&7;
  const int bh = ((id&7)<<3) | (id>>6);
  const int b = bh>>3, h = bh&7;
  __shared__ u16 Kld[2][8192];                 // [buf][sub 2][64 rows][64]
  __shared__ u16 Vtld[2][8192];
  __shared__ u32 Pld[4][1024];                 // per-wave [32 qrow][32 u32]
  const int tid = threadIdx.x, lane = tid & 63, wv = tid >> 6;
  const int lr = lane & 15, g = lane >> 4;
  const int L7 = lr & 7;
  const u16* qp0 = q + ((size_t)bh*1024 + qt*128 + wv*16 + lr)*64;
  const u16* qp1 = qp0 + 64*64;
  const short8 qa00 = *(const short8*)(qp0 + g*8);
  const short8 qa01 = *(const short8*)(qp0 + 32 + g*8);
  const short8 qa10 = *(const short8*)(qp1 + g*8);
  const short8 qa11 = *(const short8*)(qp1 + 32 + g*8);
  const float L2E = 1.44269504088896f;
  const float SC = 0.125f * L2E;
  float mnv = funkey(keys[layer]);
  float mxv = funkey(keys[8+layer]);
  if(!(mnv >= -1e38f && mnv <= 1e38f)) mnv = 0.f;
  if(!(mxv >= -1e38f && mxv <= 1e38f)) mxv = 0.f;
  const float ME   = mxv * L2E;
  const float minM = fmaxf(mnv*L2E - ME, -120.f);
  const u32* cbp = (const u32*)(rmbits + (size_t)(layer*8 + b)*16);
  const int rowi0 = qt*128 + wv*16 + lr;
  const int rowi1 = rowi0 + 64;
  const u32 rf0 = ((cbp[rowi0>>5] >> (rowi0&31)) & 1u) ? 0xFu : 0u;
  const u32 rf1 = ((cbp[rowi1>>5] >> (rowi1&31)) & 1u) ? 0xFu : 0u;
  u32* Pw = &Pld[wv][0];
  u32 wslot[4][2];
  #pragma unroll
  for(int c=0;c<4;c++){
    const int blk = c*2 + (g>>1);
    wslot[c][0] = lr*32 + (((blk ^ L7))<<2) + (g&1)*2;
    wslot[c][1] = wslot[c][0] + 1;
  }
  const u32 ra0 = lr*32 + ((g ^ L7)<<2);
  const u32 ra1 = lr*32 + (((4+g) ^ L7)<<2);

  float ls0 = 0.f, ls1 = 0.f;
  f32x4 acc0[4], acc1[4];
  #pragma unroll
  for(int d=0;d<4;d++){ acc0[d] = (f32x4){0.f,0.f,0.f,0.f}; acc1[d] = (f32x4){0.f,0.f,0.f,0.f}; }
  const u16* kbase = k + (size_t)bh*65536;
  const u16* vtbase = vt + (size_t)bh*65536;
  const int srow = tid>>3, scs = lane&7;
  const int scg = scs ^ (srow&7);
  auto stageKV = [&](int jt, int buf){
    const int j0 = jt << 7;
    #pragma unroll
    for(int j=0;j<4;j++)
      gload16(kbase + (size_t)(j0 + srow + 32*j)*64 + scg*8, &Kld[buf][j*2048 + tid*8]);
    #pragma unroll
    for(int s=0;s<2;s++)
      #pragma unroll
      for(int jj=0;jj<2;jj++)
        gload16(vtbase + (size_t)(srow + 32*jj)*1024 + j0 + s*64 + scg*8,
                &Vtld[buf][s*4096 + jj*2048 + tid*8]);
  };
  stageKV(0, 0);
  int cur = 0;
  for(int jt=0; jt<8; ++jt){
    __syncthreads();
    if(jt < 7) stageKV(jt+1, cur^1);
    #pragma unroll
    for(int s=0;s<2;s++){
      const int jb = jt*2 + s;
      const u32 cb_lo = cbp[jb*2], cb_hi = cbp[jb*2+1];
      const u16* Kp = &Kld[cur][s*4096];
      const u16* Vp = &Vtld[cur][s*4096];
      #pragma unroll
      for(int c=0;c<4;c++){
        const int rr = c*16 + lr;
        const short8 kb0 = *(const short8*)&Kp[rr*64 + ((g ^ (rr&7))<<3)];
        const short8 kb1 = *(const short8*)&Kp[rr*64 + (((g+4) ^ (rr&7))<<3)];
        f32x4 sa = (f32x4){0.f,0.f,0.f,0.f};
        f32x4 sb = (f32x4){0.f,0.f,0.f,0.f};
        __builtin_amdgcn_s_setprio(1);
        sa = mfma16(kb0, qa00, sa);
        sa = mfma16(kb1, qa01, sa);
        sb = mfma16(kb0, qa10, sb);
        sb = mfma16(kb1, qa11, sb);
        __builtin_amdgcn_s_setprio(0);
        const u32 base = (((c<2) ? cb_lo : cb_hi) >> ((c&1)*16 + g*4));
        const u32 cw0 = base | rf0;
        const u32 cw1 = base | rf1;
        float e0[4], e1[4];
        #pragma unroll
        for(int r=0;r<4;r++){
          float sv0 = fmaxf(fmaf(sa[r], SC, -ME), -120.f);
          float sv1 = fmaxf(fmaf(sb[r], SC, -ME), -120.f);
          e0[r] = exp2f(((cw0 >> r) & 1u) ? sv0 : minM);
          e1[r] = exp2f(((cw1 >> r) & 1u) ? sv1 : minM);
          ls0 += e0[r]; ls1 += e1[r];
        }
        Pw[wslot[c][0]]       = cvtpk(e0[0], e0[1]);
        Pw[wslot[c][1]]       = cvtpk(e0[2], e0[3]);
        Pw[512 + wslot[c][0]] = cvtpk(e1[0], e1[1]);
        Pw[512 + wslot[c][1]] = cvtpk(e1[2], e1[3]);
      }
      asm volatile("s_waitcnt lgkmcnt(0)" ::: "memory");
      __builtin_amdgcn_sched_barrier(0);
      const short8 pa00 = *(const short8*)&Pw[ra0];
      const short8 pa01 = *(const short8*)&Pw[ra1];
      const short8 pa10 = *(const short8*)&Pw[512 + ra0];
      const short8 pa11 = *(const short8*)&Pw[512 + ra1];
      #pragma unroll
      for(int d=0;d<4;d++){
        const int rr = d*16 + lr;
        const short8 vb0 = *(const short8*)&Vp[rr*64 + ((g ^ (rr&7))<<3)];
        const short8 vb1 = *(const short8*)&Vp[rr*64 + (((g+4) ^ (rr&7))<<3)];
        __builtin_amdgcn_s_setprio(1);
        acc0[d] = mfma16(pa00, vb0, acc0[d]);
        acc0[d] = mfma16(pa01, vb1, acc0[d]);
        acc1[d] = mfma16(pa10, vb0, acc1[d]);
        acc1[d] = mfma16(pa11, vb1, acc1[d]);
        __builtin_amdgcn_s_setprio(0);
      }
    }
    cur ^= 1;
  }
  ls0 += __shfl_xor(ls0, 16); ls0 += __shfl_xor(ls0, 32);
  ls1 += __shfl_xor(ls1, 16); ls1 += __shfl_xor(ls1, 32);
  float inv0[4], inv1[4];
  #pragma unroll
  for(int r=0;r<4;r++){ inv0[r] = 1.f / __shfl(ls0, g*4 + r); inv1[r] = 1.f / __shfl(ls1, g*4 + r); }
  #pragma unroll
  for(int d=0;d<4;d++)
    #pragma unroll
    for(int r=0;r<4;r++){
      const int qr0 = qt*128 + wv*16 + g*4 + r;
      o[((size_t)b*1024 + qr0)*512 + h*64 + d*16 + lr]        = f2bf(acc0[d][r] * inv0[r]);
      o[((size_t)b*1024 + qr0 + 64)*512 + h*64 + d*16 + lr]   = f2bf(acc1[d][r] * inv1[r]);
    }
}

// ---------------- host ----------------
extern "C" void kernel_launch(void* const* d_in, const int* in_sizes, int n_in,
                              void* d_out, int out_size, void* d_ws, size_t ws_size,
                              hipStream_t stream)
{
  const float* img     = (const float*)d_in[0];
  const int*   mask    = (const int*)d_in[1];
  const float* conv1_w = (const float*)d_in[2];
  const float* conv1_b = (const float*)d_in[3];
  const float* ln_p_g  = (const float*)d_in[4];
  const float* ln_p_b  = (const float*)d_in[5];
  const float* proj_w  = (const float*)d_in[6];
  const float* proj_b  = (const float*)d_in[7];
  const float* ln_q_g  = (const float*)d_in[8];
  const float* ln_q_b  = (const float*)d_in[9];
  const float* attn_ln_g = (const float*)d_in[10];
  const float* attn_ln_b = (const float*)d_in[11];
  const float* wqkv    = (const float*)d_in[12];
  const float* wo      = (const float*)d_in[13];
  const float* ff_ln_g = (const float*)d_in[14];
  const float* ff_ln_b = (const float*)d_in[15];
  const float* w1      = (const float*)d_in[16];
  const float* b1      = (const float*)d_in[17];
  const float* w2      = (const float*)d_in[18];
  const float* b2      = (const float*)d_in[19];
  const float* conv2_w = (const float*)d_in[20];
  const float* conv2_b = (const float*)d_in[21];

  if(ws_size < WS_NEED) return;
  char* ws = (char*)d_ws;
  u16* projWt = (u16*)(ws + O_PROJW);
  u16* qkvWt  = (u16*)(ws + O_QKVW);
  u16* woWt   = (u16*)(ws + O_WOW);
  u16* w1Wt   = (u16*)(ws + O_W1W);
  u16* w2Wt   = (u16*)(ws + O_W2W);
  u16* c1Wt   = (u16*)(ws + O_C1W);
  u16* c2Wt   = (u16*)(ws + O_C2W);
  u16* pcl    = (u16*)(ws + O_RA);      // pcl1 / vt / pcl2
  float* tmpf = (float*)(ws + O_RA);
  u16* vtb    = (u16*)(ws + O_RA);      // v^T during layer loop
  float* patches = (float*)(ws + O_RB);
  u16* qkvb   = (u16*)(ws + O_RB);      // q|k (v folded into vt), each 8*8*1024*64
  float* xbuf = (float*)(ws + O_X);
  u16* xnbf   = (u16*)(ws + O_D);
  u16* obf    = (u16*)(ws + O_F);
  u32* minbuf = (u32*)(ws + O_MIN);
  u64* rmbits = (u64*)(ws + O_RMB);

  hipMemsetAsync(ws + O_MIN, 0xFF, 32, stream);       // min keys -> UINT_MAX
  hipMemsetAsync(ws + O_MIN + 32, 0, 32, stream);     // max keys -> 0
  hipMemsetAsync(ws + O_RA, 0, 22302720, stream);     // pcl1 zero borders

  // weight conversion
  k_transpose_bf<<<dim3(16,16,1),256,0,stream>>>(proj_w, projWt, 512, 512);
  k_transpose_bf<<<dim3(16,48,6),256,0,stream>>>(wqkv,   qkvWt,  512, 1536);
  k_transpose_bf<<<dim3(16,16,6),256,0,stream>>>(wo,     woWt,   512, 512);
  k_transpose_bf<<<dim3(16,16,6),256,0,stream>>>(w1,     w1Wt,   512, 512);
  k_transpose_bf<<<dim3(16,16,6),256,0,stream>>>(w2,     w2Wt,   512, 512);
  k_convw<<<1440,256,0,stream>>>(conv1_w, c1Wt, 128, 320);
  k_convw<<<1440,256,0,stream>>>(conv2_w, c2Wt, 320, 128);
  k_rmask<<<192,256,0,stream>>>(mask, rmbits);

  // patch embed
  k_pad_img<<<dim3(512,5),256,0,stream>>>(img, pcl);
  k_gemm<5,320><<<dim3(256,2),256,0,stream>>>(pcl, c1Wt, conv1_b, patches, nullptr, 32768, 128, 2880);
  k_ln_bf<<<2048,256,0,stream>>>(patches, ln_p_g, ln_p_b, xnbf);
  k_gemm64<0><<<dim3(128,8),256,0,stream>>>(xnbf, projWt, proj_b, tmpf, nullptr, 512);
  k_lnq_pos<<<2048,256,0,stream>>>(tmpf, ln_q_g, ln_q_b, xbuf);

  const u16* qb = qkvb;
  const u16* kb = qkvb + 4194304;
  for(int i=0;i<6;i++){
    k_ln_bf<<<2048,256,0,stream>>>(xbuf, attn_ln_g + i*512, attn_ln_b + i*512, xnbf);
    k_gemmW<<<dim3(64,24),256,0,stream>>>(xnbf, qkvWt + (size_t)i*1536*512, qkvb, vtb, 512);
    k_attn_minmax<<<512,256,0,stream>>>(qb, kb, minbuf, i);
    k_attn<<<512,256,0,stream>>>(qb, kb, vtb, rmbits, minbuf, obf, i);
    k_gemm64<2><<<dim3(128,8),256,0,stream>>>(obf, woWt + (size_t)i*512*512, nullptr, xbuf, xbuf, 512);
    k_ln_bf<<<2048,256,0,stream>>>(xbuf, ff_ln_g + i*512, ff_ln_b + i*512, xnbf);
    k_gemm64<3><<<dim3(128,8),256,0,stream>>>(xnbf, w1Wt + (size_t)i*512*512, b1 + i*512, obf, nullptr, 512);
    k_gemm64<4><<<dim3(128,8),256,0,stream>>>(obf, w2Wt + (size_t)i*512*512, b2 + i*512, xbuf, xbuf, 512);
  }

  // final conv
  hipMemsetAsync(ws + O_RA, 0, 8921088, stream);    // pcl2 zero borders
  k_pad_tok<<<16384,256,0,stream>>>(xbuf, pcl);
  k_gemm<6,128><<<dim3(256,5),256,0,stream>>>(pcl, c2Wt, conv2_b, d_out, nullptr, 32768, 320, 1152);
}

// Round 15
// 922.842 us; speedup vs baseline: 1.2264x; 1.0144x over previous
//
#include <hip/hip_runtime.h>
#include <hip/hip_bf16.h>
#include <math.h>

typedef __attribute__((ext_vector_type(8))) short short8;
typedef __attribute__((ext_vector_type(4))) float f32x4;
typedef unsigned short u16;
typedef unsigned int u32;
typedef unsigned long long u64;

#define DEV __device__ __forceinline__

DEV float bf2f(u16 u){ u32 x = ((u32)u)<<16; return __builtin_bit_cast(float, x); }
DEV u16 f2bf(float f){ u32 x = __builtin_bit_cast(u32, f); return (u16)((x + 0x7FFFu + ((x>>16)&1u))>>16); }
DEV f32x4 mfma16(short8 a, short8 b, f32x4 c){ return __builtin_amdgcn_mfma_f32_16x16x32_bf16(a,b,c,0,0,0); }
DEV void gload16(const void* g, void* l){
  __builtin_amdgcn_global_load_lds((const __attribute__((address_space(1))) void*)g,
                                   (__attribute__((address_space(3))) void*)l, 16, 0, 0);
}
DEV u32 fkey(float f){ u32 b = __builtin_bit_cast(u32, f); return (b & 0x80000000u) ? ~b : (b ^ 0x80000000u); }
DEV float funkey(u32 k){ u32 b = (k & 0x80000000u) ? (k ^ 0x80000000u) : ~k; return __builtin_bit_cast(float, b); }
DEV u32 cvtpk(float lo, float hi){ u32 d; asm("v_cvt_pk_bf16_f32 %0, %1, %2" : "=v"(d) : "v"(lo), "v"(hi)); return d; }

// ---------------- workspace layout (bytes) ----------------
static constexpr size_t O_PROJW = 0;                         // 512*512*2
static constexpr size_t O_QKVW  = O_PROJW + 524288;          // 6*1536*512*2
static constexpr size_t O_WOW   = O_QKVW + 9437184;          // 6*512*512*2
static constexpr size_t O_W1W   = O_WOW + 3145728;
static constexpr size_t O_W2W   = O_W1W + 3145728;
static constexpr size_t O_C1W   = O_W2W + 3145728;           // 128*2880*2
static constexpr size_t O_C2W   = O_C1W + 737280;            // 320*1152*2
static constexpr size_t O_RA    = O_C2W + 737280;            // pcl1 22.3MB / tmp f32 / vt 8.4MB / pcl2
static constexpr size_t O_RB    = O_RA + 22302720;           // patches f32 16.8MB then qkv bf16 25.2MB
static constexpr size_t O_X     = O_RB + 25165824;           // x f32 16.8MB
static constexpr size_t O_D     = O_X + 16777216;            // xn bf16 8.4MB
static constexpr size_t O_F     = O_D + 8388608;             // o/g bf16 8.4MB
static constexpr size_t O_RM    = O_F + 8388608;             // 48*1024 u8
static constexpr size_t O_MIN   = O_RM + 49152;              // min keys [0..5], max keys [8..13]
static constexpr size_t O_RMB   = O_MIN + 256;               // 48*16 u64 bit-packed masks
static constexpr size_t WS_NEED = O_RMB + 8192;

// ---------------- weight conversion ----------------
// src [z][K][N] f32 -> dst [z][N][K] bf16
__global__ __launch_bounds__(256) void k_transpose_bf(const float* __restrict__ src, u16* __restrict__ dst, int K, int N){
  __shared__ float tile[32][33];
  const int k0 = blockIdx.x*32, n0 = blockIdx.y*32;
  src += (size_t)blockIdx.z*K*N; dst += (size_t)blockIdx.z*K*N;
  const int c = threadIdx.x & 31, r4 = threadIdx.x >> 5;
  for(int r=r4; r<32; r+=8) tile[r][c] = src[(size_t)(k0+r)*N + n0+c];
  __syncthreads();
  for(int r=r4; r<32; r+=8) dst[(size_t)(n0+r)*K + k0+c] = f2bf(tile[c][r]);
}

// conv weights [OC][IC][3][3] f32 -> Wt [OC][tap*IC+ic] bf16
__global__ __launch_bounds__(256) void k_convw(const float* __restrict__ src, u16* __restrict__ dst, int OC, int IC){
  int idx = blockIdx.x*256 + threadIdx.x;
  int total = OC*IC*9;
  if(idx >= total) return;
  int oc = idx/(IC*9); int rem = idx - oc*IC*9; int tap = rem/IC; int ic = rem - tap*IC;
  dst[idx] = f2bf(src[(size_t)(oc*IC+ic)*9 + tap]);
}

// img [8][320][64][64] f32 -> pcl1 [8][66][66][320] bf16 (interior; borders pre-zeroed)
__global__ __launch_bounds__(256) void k_pad_img(const float* __restrict__ img, u16* __restrict__ pcl){
  const int by = blockIdx.x; const int b = by>>6, y = by&63; const int c0 = blockIdx.y*64;
  __shared__ float t[64][65];
  const int tx = threadIdx.x & 63, tz = threadIdx.x >> 6;
  for(int ci=tz; ci<64; ci+=4) t[ci][tx] = img[(((size_t)b*320 + c0+ci)*64 + y)*64 + tx];
  __syncthreads();
  for(int x=tz; x<64; x+=4) pcl[(((size_t)b*66 + y+1)*66 + (x+1))*320 + c0 + tx] = f2bf(t[tx][x]);
}

// x tokens f32 -> pcl2 [8][66][66][128] bf16 (interior)
__global__ __launch_bounds__(256) void k_pad_tok(const float* __restrict__ x, u16* __restrict__ pcl){
  int idx = blockIdx.x*256 + threadIdx.x;           // 8*64*64*128
  const int c = idx & 127; int r = idx >> 7; const int xx = r & 63; r >>= 6; const int yy = r & 63; const int b = r >> 6;
  const int n = (yy>>1)*32 + (xx>>1); const int f = (yy&1)*256 + (xx&1)*128 + c;
  pcl[(((size_t)b*66 + yy+1)*66 + xx+1)*128 + c] = f2bf(x[((size_t)b*1024 + n)*512 + f]);
}

// mask [48][64][64] int -> rmbits [48][16] u64 (2x2 any)
__global__ __launch_bounds__(256) void k_rmask(const int* __restrict__ mask, u64* __restrict__ rmbits){
  int idx = blockIdx.x*256 + threadIdx.x;
  const int m = idx >> 10, n = idx & 1023; const int h = n>>5, w = n&31;
  const int* mp = mask + ((size_t)m*64 + h*2)*64 + w*2;
  const int v = (mp[0]==1) | (mp[1]==1) | (mp[64]==1) | (mp[65]==1);
  const u64 bm = __ballot(v);
  if((threadIdx.x & 63) == 0) rmbits[idx>>6] = bm;
}

// ---------------- layernorm (wave per token) ----------------
__global__ __launch_bounds__(256) void k_ln_bf(const float* __restrict__ in, const float* __restrict__ gw,
                                               const float* __restrict__ bw, u16* __restrict__ out){
  const int tok = blockIdx.x*4 + (threadIdx.x>>6);
  const int lane = threadIdx.x & 63;
  const float* rp = in + (size_t)tok*512 + lane*8;
  const float4 a = *(const float4*)rp;
  const float4 b = *(const float4*)(rp+4);
  float s  = a.x+a.y+a.z+a.w + b.x+b.y+b.z+b.w;
  float sq = a.x*a.x+a.y*a.y+a.z*a.z+a.w*a.w + b.x*b.x+b.y*b.y+b.z*b.z+b.w*b.w;
  #pragma unroll
  for(int off=1; off<64; off<<=1){ s += __shfl_xor(s,off); sq += __shfl_xor(sq,off); }
  const float mu = s*(1.f/512.f);
  const float rs = rsqrtf(fmaxf(sq*(1.f/512.f) - mu*mu, 0.f) + 1e-5f);
  const float4 g0 = *(const float4*)(gw + lane*8);
  const float4 g1 = *(const float4*)(gw + lane*8 + 4);
  const float4 b0 = *(const float4*)(bw + lane*8);
  const float4 b1 = *(const float4*)(bw + lane*8 + 4);
  short8 o8;
  o8[0]=f2bf((a.x-mu)*rs*g0.x+b0.x); o8[1]=f2bf((a.y-mu)*rs*g0.y+b0.y);
  o8[2]=f2bf((a.z-mu)*rs*g0.z+b0.z); o8[3]=f2bf((a.w-mu)*rs*g0.w+b0.w);
  o8[4]=f2bf((b.x-mu)*rs*g1.x+b1.x); o8[5]=f2bf((b.y-mu)*rs*g1.y+b1.y);
  o8[6]=f2bf((b.z-mu)*rs*g1.z+b1.z); o8[7]=f2bf((b.w-mu)*rs*g1.w+b1.w);
  *(short8*)(out + (size_t)tok*512 + lane*8) = o8;
}

// LN + sincos 2d posemb -> f32 x (wave per token)
__global__ __launch_bounds__(256) void k_lnq_pos(const float* __restrict__ in, const float* __restrict__ gw,
                                                 const float* __restrict__ bw, float* __restrict__ out){
  const int tok = blockIdx.x*4 + (threadIdx.x>>6);
  const int lane = threadIdx.x & 63;
  const float* rp = in + (size_t)tok*512 + lane*8;
  const float4 a = *(const float4*)rp;
  const float4 b = *(const float4*)(rp+4);
  float s  = a.x+a.y+a.z+a.w + b.x+b.y+b.z+b.w;
  float sq = a.x*a.x+a.y*a.y+a.z*a.z+a.w*a.w + b.x*b.x+b.y*b.y+b.z*b.z+b.w*b.w;
  #pragma unroll
  for(int off=1; off<64; off<<=1){ s += __shfl_xor(s,off); sq += __shfl_xor(sq,off); }
  const float mu = s*(1.f/512.f);
  const float rs = rsqrtf(fmaxf(sq*(1.f/512.f) - mu*mu, 0.f) + 1e-5f);
  const int n = tok & 1023; const int yy = n>>5, xx = n&31;
  const int f0 = lane*8; const int sec = f0>>7;
  const float coord = (sec<2) ? (float)xx : (float)yy;
  const float vv[8] = {a.x,a.y,a.z,a.w,b.x,b.y,b.z,b.w};
  float ov[8];
  #pragma unroll
  for(int j=0;j<8;j++){
    const int f = f0+j; const int qq = f & 127;
    const float om = __expf(-(float)qq * (9.2103403719761836f/127.f));
    const float arg = coord * om;
    const float pe = (sec&1) ? __cosf(arg) : __sinf(arg);
    ov[j] = (vv[j]-mu)*rs*gw[f] + bw[f] + pe;
  }
  float* op = out + (size_t)tok*512 + f0;
  *(float4*)op = (float4){ov[0],ov[1],ov[2],ov[3]};
  *(float4*)(op+4) = (float4){ov[4],ov[5],ov[6],ov[7]};
}

// ---------------- GEMM 64x64 tile (4 blocks/CU) for N=512 layers ----------------
// EPI: 0 proj(f32+bias) 2 resid(f32) 3 gelu(bf16+bias) 4 resid+bias
template<int EPI>
__global__ __launch_bounds__(256, 4)
void k_gemm64(const u16* __restrict__ A, const u16* __restrict__ Wt,
              const float* __restrict__ bias, void* __restrict__ outp,
              const float* __restrict__ resid, int Kd)
{
  __shared__ u16 Ald[2][4096];
  __shared__ u16 Bld[2][4096];
  const int tid = threadIdx.x, lane = tid & 63, wv = tid >> 6;
  const int lr = lane & 15, g = lane >> 4;
  const int m0 = blockIdx.x * 64, n0 = blockIdx.y * 64;
  const int wm = (wv >> 1) * 32, wn = (wv & 1) * 32;
  const int srow = tid >> 3;
  const int sc  = (tid & 7) ^ (srow & 7);
  const u16* arow0p = A + (size_t)(m0+srow)*Kd + sc*8;
  const u16* arow1p = A + (size_t)(m0+srow+32)*Kd + sc*8;
  const u16* brow0p = Wt + (size_t)(n0+srow)*Kd + sc*8;
  const u16* brow1p = Wt + (size_t)(n0+srow+32)*Kd + sc*8;

  f32x4 acc[2][2];
  #pragma unroll
  for(int i=0;i<2;i++)
    #pragma unroll
    for(int j=0;j<2;j++) acc[i][j] = (f32x4){0.f,0.f,0.f,0.f};

  const int nIter = Kd >> 6;
  int cur = 0;
  auto stage = [&](int kt, int buf){
    const int k0 = kt << 6;
    gload16(arow0p + k0, &Ald[buf][tid*8]);
    gload16(arow1p + k0, &Ald[buf][2048 + tid*8]);
    gload16(brow0p + k0, &Bld[buf][tid*8]);
    gload16(brow1p + k0, &Bld[buf][2048 + tid*8]);
  };

  stage(0, 0);
  for(int kt=0; kt<nIter; ++kt){
    __syncthreads();
    if(kt+1 < nIter) stage(kt+1, cur^1);
    short8 af[2][2], bg[2][2];
    #pragma unroll
    for(int mi=0;mi<2;mi++)
      #pragma unroll
      for(int kk=0;kk<2;kk++){
        const int R = wm + mi*16 + lr;
        const int Rn = wn + mi*16 + lr;
        const int c = kk*4 + g;
        af[mi][kk] = *(const short8*)&Ald[cur][R*64 + ((c ^ (R&7))<<3)];
        bg[mi][kk] = *(const short8*)&Bld[cur][Rn*64 + ((c ^ (Rn&7))<<3)];
      }
    #pragma unroll
    for(int mi=0;mi<2;mi++)
      #pragma unroll
      for(int nj=0;nj<2;nj++)
        #pragma unroll
        for(int kk=0;kk<2;kk++)
          acc[mi][nj] = mfma16(af[mi][kk], bg[nj][kk], acc[mi][nj]);
    cur ^= 1;
  }

  #pragma unroll
  for(int mi=0;mi<2;mi++){
    #pragma unroll
    for(int nj=0;nj<2;nj++){
      #pragma unroll
      for(int r=0;r<4;r++){
        const int mrow = m0 + wm + mi*16 + g*4 + r;
        const int ncol = n0 + wn + nj*16 + lr;
        float val = acc[mi][nj][r];
        if constexpr (EPI==0 || EPI==3 || EPI==4)
          val += bias[ncol];
        if constexpr (EPI==0){
          ((float*)outp)[(size_t)mrow*512 + ncol] = val;
        } else if constexpr (EPI==2 || EPI==4){
          const size_t idx = (size_t)mrow*512 + ncol;
          ((float*)outp)[idx] = resid[idx] + val;
        } else if constexpr (EPI==3){
          const float gl = 0.5f * val * (1.f + erff(val * 0.70710678118654752f));
          ((u16*)outp)[(size_t)mrow*512 + ncol] = f2bf(gl);
        }
      }
    }
  }
}

// ---------------- wide GEMM (128x64 tile) for convs ----------------
// EPI: 5 conv1->patches 6 conv2->out
template<int EPI, int CONVC>
__global__ __launch_bounds__(256, 3)
void k_gemm(const u16* __restrict__ A, const u16* __restrict__ Wt,
            const float* __restrict__ bias, void* __restrict__ outp,
            const float* __restrict__ resid, int M, int N, int Kd)
{
  __shared__ u16 Ald[2][8192];                        // [128][64] (4 chunks of 32 rows)
  __shared__ u16 Bld[2][4096];                        // [64][64]
  const int tid = threadIdx.x, lane = tid & 63, wv = tid >> 6;
  const int lr = lane & 15, g = lane >> 4;
  const int m0 = blockIdx.x * 128, n0 = blockIdx.y * 64;
  const int wm = wv * 32;
  const int srow = tid >> 3;
  const int sc  = (tid & 7) ^ (srow & 7);
  int b0=0, y0=0;
  if constexpr (CONVC != 0){ b0 = m0>>12; y0 = (m0>>6)&63; }
  const u16* ar[4];
  if constexpr (CONVC == 0){
    #pragma unroll
    for(int j=0;j<4;j++) ar[j] = A + (size_t)(m0+srow+32*j)*Kd + sc*8;
  }
  const u16* br0 = Wt + (size_t)(n0+srow)*Kd + sc*8;
  const u16* br1 = Wt + (size_t)(n0+srow+32)*Kd + sc*8;

  f32x4 acc[2][4];
  #pragma unroll
  for(int i=0;i<2;i++)
    #pragma unroll
    for(int j=0;j<4;j++) acc[i][j] = (f32x4){0.f,0.f,0.f,0.f};

  const int nIter = Kd >> 6;
  int cur = 0;

  auto stage = [&](int kt, int buf){
    const int k0 = kt << 6;
    if constexpr (CONVC != 0){
      const int tap = k0 / CONVC;
      const int ic0 = k0 - tap*CONVC;
      const int ky = tap/3, kx = tap - 3*(tap/3);
      #pragma unroll
      for(int j=0;j<4;j++){
        const int xr = srow + 32*(j&1);
        const int yr = y0 + (j>>1) + ky;
        const u16* ga = A + ((size_t)((b0*66 + yr)*66 + xr + kx))*CONVC + ic0 + sc*8;
        gload16(ga, &Ald[buf][j*2048 + tid*8]);
      }
    } else {
      #pragma unroll
      for(int j=0;j<4;j++) gload16(ar[j] + k0, &Ald[buf][j*2048 + tid*8]);
    }
    gload16(br0 + k0, &Bld[buf][tid*8]);
    gload16(br1 + k0, &Bld[buf][2048 + tid*8]);
  };

  stage(0, 0);
  for(int kt=0; kt<nIter; ++kt){
    __syncthreads();
    if(kt+1 < nIter) stage(kt+1, cur^1);
    short8 af[2][2], bg[4][2];
    #pragma unroll
    for(int mi=0;mi<2;mi++)
      #pragma unroll
      for(int kk=0;kk<2;kk++){
        const int R = wm + mi*16 + lr;
        const int c = kk*4 + g;
        af[mi][kk] = *(const short8*)&Ald[cur][R*64 + ((c ^ (R&7))<<3)];
      }
    #pragma unroll
    for(int nj=0;nj<4;nj++)
      #pragma unroll
      for(int kk=0;kk<2;kk++){
        const int Rn = nj*16 + lr;
        const int c = kk*4 + g;
        bg[nj][kk] = *(const short8*)&Bld[cur][Rn*64 + ((c ^ (Rn&7))<<3)];
      }
    #pragma unroll
    for(int mi=0;mi<2;mi++)
      #pragma unroll
      for(int nj=0;nj<4;nj++)
        #pragma unroll
        for(int kk=0;kk<2;kk++)
          acc[mi][nj] = mfma16(af[mi][kk], bg[nj][kk], acc[mi][nj]);
    cur ^= 1;
  }

  #pragma unroll
  for(int mi=0;mi<2;mi++){
    #pragma unroll
    for(int nj=0;nj<4;nj++){
      #pragma unroll
      for(int r=0;r<4;r++){
        const int mrow = m0 + wm + mi*16 + g*4 + r;
        const int ncol = n0 + nj*16 + lr;
        float val = acc[mi][nj][r] + bias[ncol];
        if constexpr (EPI==5){
          const int b = mrow>>12; const int rr = mrow&4095; const int y = rr>>6; const int xx = rr&63;
          const size_t pidx = ((size_t)(b*1024 + (y>>1)*32 + (xx>>1)))*512 + (y&1)*256 + (xx&1)*128 + ncol;
          ((float*)outp)[pidx] = val;
        } else if constexpr (EPI==6){
          const int b = mrow>>12; const int rr = mrow&4095; const int y = rr>>6; const int xx = rr&63;
          ((float*)outp)[(((size_t)(b*320 + ncol))*64 + y)*64 + xx] = val;
        }
      }
    }
  }
}

// ---------------- wide GEMM for qkv: 128x64 tile, BK=64; q/k scatter; v -> vt directly ----------------
__global__ __launch_bounds__(256, 3)
void k_gemmW(const u16* __restrict__ A, const u16* __restrict__ Wt,
             void* __restrict__ outp, u16* __restrict__ vt, int Kd)
{
  __shared__ u16 Ald[2][8192];                       // [128][64]; reused as Vt bounce tile
  __shared__ u16 Bld[2][4096];                       // [64][64]
  const int tid = threadIdx.x, lane = tid & 63, wv = tid >> 6;
  const int lr = lane & 15, g = lane >> 4;
  const int m0 = blockIdx.x * 128, n0 = blockIdx.y * 64;
  const int wm = wv * 32;
  const int srow = tid >> 3;
  const int sc  = (tid & 7) ^ (srow & 7);
  const u16* ar[4];
  #pragma unroll
  for(int j=0;j<4;j++) ar[j] = A + (size_t)(m0+srow+32*j)*Kd + sc*8;
  const u16* br0 = Wt + (size_t)(n0+srow)*Kd + sc*8;
  const u16* br1 = Wt + (size_t)(n0+srow+32)*Kd + sc*8;

  f32x4 acc[2][4];
  #pragma unroll
  for(int i=0;i<2;i++)
    #pragma unroll
    for(int j=0;j<4;j++) acc[i][j] = (f32x4){0.f,0.f,0.f,0.f};

  const int nIter = Kd >> 6;
  int cur = 0;
  auto stage = [&](int kt, int buf){
    const int k0 = kt << 6;
    #pragma unroll
    for(int j=0;j<4;j++) gload16(ar[j] + k0, &Ald[buf][j*2048 + tid*8]);
    gload16(br0 + k0, &Bld[buf][tid*8]);
    gload16(br1 + k0, &Bld[buf][2048 + tid*8]);
  };

  stage(0, 0);
  for(int kt=0; kt<nIter; ++kt){
    __syncthreads();
    if(kt+1 < nIter) stage(kt+1, cur^1);
    short8 af[2][2], bg[4][2];
    #pragma unroll
    for(int mi=0;mi<2;mi++)
      #pragma unroll
      for(int kk=0;kk<2;kk++){
        const int R = wm + mi*16 + lr;
        const int c = kk*4 + g;
        af[mi][kk] = *(const short8*)&Ald[cur][R*64 + ((c ^ (R&7))<<3)];
      }
    #pragma unroll
    for(int nj=0;nj<4;nj++)
      #pragma unroll
      for(int kk=0;kk<2;kk++){
        const int Rn = nj*16 + lr;
        const int c = kk*4 + g;
        bg[nj][kk] = *(const short8*)&Bld[cur][Rn*64 + ((c ^ (Rn&7))<<3)];
      }
    #pragma unroll
    for(int mi=0;mi<2;mi++)
      #pragma unroll
      for(int nj=0;nj<4;nj++)
        #pragma unroll
        for(int kk=0;kk<2;kk++)
          acc[mi][nj] = mfma16(af[mi][kk], bg[nj][kk], acc[mi][nj]);
    cur ^= 1;
  }

  if(n0 < 1024){
    // q/k scatter epilogue
    #pragma unroll
    for(int mi=0;mi<2;mi++){
      #pragma unroll
      for(int nj=0;nj<4;nj++){
        #pragma unroll
        for(int r=0;r<4;r++){
          const int mrow = m0 + wm + mi*16 + g*4 + r;
          const int ncol = n0 + nj*16 + lr;
          const int sec = ncol >> 9, rem = ncol & 511;
          const int head = rem >> 6, d = rem & 63;
          const int b = mrow >> 10, t = mrow & 1023;
          ((u16*)outp)[(size_t)sec*4194304 + ((size_t)((b*8+head)*1024 + t))*64 + d] = f2bf(acc[mi][nj][r]);
        }
      }
    }
  } else {
    // v block: write vt[bh][d][t] directly via LDS bounce (raw v never materialized)
    const int head = (n0 - 1024) >> 6;
    const int b = m0 >> 10;
    const int t0 = m0 & 1023;
    const int bh = b*8 + head;
    __syncthreads();                                  // all waves done reading Ald
    u16* Vt = (u16*)Ald;                              // [64 d][136] (stride 272B, 16B-aligned)
    #pragma unroll
    for(int mi=0;mi<2;mi++)
      #pragma unroll
      for(int nj=0;nj<4;nj++)
        #pragma unroll
        for(int r=0;r<4;r++){
          const int lt = wm + mi*16 + g*4 + r;
          const int d  = nj*16 + lr;
          Vt[d*136 + lt] = f2bf(acc[mi][nj][r]);
        }
    __syncthreads();
    const int d = tid >> 2, qd = tid & 3;             // 64 d-rows x 4 chunks of 32 t
    u16* dst = vt + (size_t)bh*65536 + (size_t)d*1024 + t0 + qd*32;
    const u16* srcl = &Vt[d*136 + qd*32];
    #pragma unroll
    for(int e4=0;e4<4;e4++)
      *(short8*)(dst + e4*8) = *(const short8*)(srcl + e4*8);
  }
}

// ---------------- attention pass A: global min AND max, 128-q tile, 128-j staged (8 barriers) ----------------
__global__ __launch_bounds__(256, 4)
void k_attn_minmax(const u16* __restrict__ q, const u16* __restrict__ k, u32* __restrict__ keys, int layer){
  const int id = blockIdx.x;                   // 512 blocks
  const int qt = (id>>3)&7;
  const int bh = ((id&7)<<3) | (id>>6);
  __shared__ u16 Kld[2][8192];                 // [2 buf][2 sub][64 rows][64]
  __shared__ float redn[4], redx[4];
  const int tid = threadIdx.x, lane = tid & 63, wv = tid >> 6;
  const int lr = lane & 15, g = lane >> 4;
  const u16* qp0 = q + ((size_t)bh*1024 + qt*128 + wv*16 + lr)*64;
  const u16* qp1 = qp0 + 64*64;
  const short8 qa00 = *(const short8*)(qp0 + g*8);
  const short8 qa01 = *(const short8*)(qp0 + 32 + g*8);
  const short8 qa10 = *(const short8*)(qp1 + g*8);
  const short8 qa11 = *(const short8*)(qp1 + 32 + g*8);
  const u16* kbase = k + (size_t)bh*65536;
  const int srow = tid>>3, scs = lane&7;
  const int scg = scs ^ (srow&7);
  float mn = 3.0e38f, mx = -3.0e38f;
  auto stageK = [&](int jt, int buf){
    const int j0 = jt << 7;
    #pragma unroll
    for(int j=0;j<4;j++)
      gload16(kbase + (size_t)(j0 + srow + 32*j)*64 + scg*8, &Kld[buf][j*2048 + tid*8]);
  };
  stageK(0, 0);
  int cur = 0;
  for(int jt=0; jt<8; ++jt){
    __syncthreads();
    if(jt < 7) stageK(jt+1, cur^1);
    #pragma unroll
    for(int s=0;s<2;s++){
      const u16* Kp = &Kld[cur][s*4096];
      #pragma unroll
      for(int c=0;c<4;c++){
        const int rr = c*16 + lr;
        const short8 kb0 = *(const short8*)&Kp[rr*64 + ((g ^ (rr&7))<<3)];
        const short8 kb1 = *(const short8*)&Kp[rr*64 + (((g+4) ^ (rr&7))<<3)];
        f32x4 sa = (f32x4){0.f,0.f,0.f,0.f};
        f32x4 sb = (f32x4){0.f,0.f,0.f,0.f};
        __builtin_amdgcn_s_setprio(1);
        sa = mfma16(qa00, kb0, sa);
        sa = mfma16(qa01, kb1, sa);
        sb = mfma16(qa10, kb0, sb);
        sb = mfma16(qa11, kb1, sb);
        __builtin_amdgcn_s_setprio(0);
        mn = fminf(mn, fminf(fminf(sa[0],sa[1]), fminf(sa[2],sa[3])));
        mx = fmaxf(mx, fmaxf(fmaxf(sa[0],sa[1]), fmaxf(sa[2],sa[3])));
        mn = fminf(mn, fminf(fminf(sb[0],sb[1]), fminf(sb[2],sb[3])));
        mx = fmaxf(mx, fmaxf(fmaxf(sb[0],sb[1]), fmaxf(sb[2],sb[3])));
      }
    }
    cur ^= 1;
  }
  mn *= 0.125f; mx *= 0.125f;
  #pragma unroll
  for(int off=32; off; off>>=1){
    mn = fminf(mn, __shfl_down(mn, off));
    mx = fmaxf(mx, __shfl_down(mx, off));
  }
  if(lane==0){ redn[wv] = mn; redx[wv] = mx; }
  __syncthreads();
  if(tid==0){
    atomicMin(keys + layer,     fkey(fminf(fminf(redn[0],redn[1]), fminf(redn[2],redn[3]))));
    atomicMax(keys + 8 + layer, fkey(fmaxf(fmaxf(redx[0],redx[1]), fmaxf(redx[2],redx[3]))));
  }
}

// ---------------- attention pass B: 128-q tile, 128-j staged (8 barriers), swapped QK^T, packed P ----------------
__global__ __launch_bounds__(256, 2)
void k_attn(const u16* __restrict__ q, const u16* __restrict__ k, const u16* __restrict__ vt,
            const u64* __restrict__ rmbits, const u32* __restrict__ keys,
            u16* __restrict__ o, int layer){
  const int id = blockIdx.x;                   // 512 blocks
  const int qt = (id>>3)&7;
  const int bh = ((id&7)<<3) | (id>>6);
  const int b = bh>>3, h = bh&7;
  __shared__ u16 Kld[2][8192];                 // [buf][sub 2][64 rows][64]
  __shared__ u16 Vtld[2][8192];
  __shared__ u32 Pld[4][1024];                 // per-wave [32 qrow][32 u32]
  const int tid = threadIdx.x, lane = tid & 63, wv = tid >> 6;
  const int lr = lane & 15, g = lane >> 4;
  const int L7 = lr & 7;
  const u16* qp0 = q + ((size_t)bh*1024 + qt*128 + wv*16 + lr)*64;
  const u16* qp1 = qp0 + 64*64;
  const short8 qa00 = *(const short8*)(qp0 + g*8);
  const short8 qa01 = *(const short8*)(qp0 + 32 + g*8);
  const short8 qa10 = *(const short8*)(qp1 + g*8);
  const short8 qa11 = *(const short8*)(qp1 + 32 + g*8);
  const float L2E = 1.44269504088896f;
  const float SC = 0.125f * L2E;
  float mnv = funkey(keys[layer]);
  float mxv = funkey(keys[8+layer]);
  if(!(mnv >= -1e38f && mnv <= 1e38f)) mnv = 0.f;
  if(!(mxv >= -1e38f && mxv <= 1e38f)) mxv = 0.f;
  const float ME   = mxv * L2E;
  const float minM = fmaxf(mnv*L2E - ME, -120.f);
  const float emin = exp2f(minM);              // precomputed masked-fill value
  const u32* cbp = (const u32*)(rmbits + (size_t)(layer*8 + b)*16);
  const int rowi0 = qt*128 + wv*16 + lr;
  const int rowi1 = rowi0 + 64;
  const u32 rf0 = ((cbp[rowi0>>5] >> (rowi0&31)) & 1u) ? 0xFu : 0u;
  const u32 rf1 = ((cbp[rowi1>>5] >> (rowi1&31)) & 1u) ? 0xFu : 0u;
  u32* Pw = &Pld[wv][0];
  u32 wslot[4][2];
  #pragma unroll
  for(int c=0;c<4;c++){
    const int blk = c*2 + (g>>1);
    wslot[c][0] = lr*32 + (((blk ^ L7))<<2) + (g&1)*2;
    wslot[c][1] = wslot[c][0] + 1;
  }
  const u32 ra0 = lr*32 + ((g ^ L7)<<2);
  const u32 ra1 = lr*32 + (((4+g) ^ L7)<<2);

  float ls0 = 1e-30f, ls1 = 1e-30f;
  f32x4 acc0[4], acc1[4];
  #pragma unroll
  for(int d=0;d<4;d++){ acc0[d] = (f32x4){0.f,0.f,0.f,0.f}; acc1[d] = (f32x4){0.f,0.f,0.f,0.f}; }
  const u16* kbase = k + (size_t)bh*65536;
  const u16* vtbase = vt + (size_t)bh*65536;
  const int srow = tid>>3, scs = lane&7;
  const int scg = scs ^ (srow&7);
  auto stageKV = [&](int jt, int buf){
    const int j0 = jt << 7;
    #pragma unroll
    for(int j=0;j<4;j++)
      gload16(kbase + (size_t)(j0 + srow + 32*j)*64 + scg*8, &Kld[buf][j*2048 + tid*8]);
    #pragma unroll
    for(int s=0;s<2;s++)
      #pragma unroll
      for(int jj=0;jj<2;jj++)
        gload16(vtbase + (size_t)(srow + 32*jj)*1024 + j0 + s*64 + scg*8,
                &Vtld[buf][s*4096 + jj*2048 + tid*8]);
  };
  stageKV(0, 0);
  int cur = 0;
  for(int jt=0; jt<8; ++jt){
    __syncthreads();
    if(jt < 7) stageKV(jt+1, cur^1);
    #pragma unroll
    for(int s=0;s<2;s++){
      const int jb = jt*2 + s;
      const u32 cb_lo = cbp[jb*2], cb_hi = cbp[jb*2+1];
      const u16* Kp = &Kld[cur][s*4096];
      const u16* Vp = &Vtld[cur][s*4096];
      #pragma unroll
      for(int c=0;c<4;c++){
        const int rr = c*16 + lr;
        const short8 kb0 = *(const short8*)&Kp[rr*64 + ((g ^ (rr&7))<<3)];
        const short8 kb1 = *(const short8*)&Kp[rr*64 + (((g+4) ^ (rr&7))<<3)];
        f32x4 sa = (f32x4){0.f,0.f,0.f,0.f};
        f32x4 sb = (f32x4){0.f,0.f,0.f,0.f};
        __builtin_amdgcn_s_setprio(1);
        sa = mfma16(kb0, qa00, sa);
        sa = mfma16(kb1, qa01, sa);
        sb = mfma16(kb0, qa10, sb);
        sb = mfma16(kb1, qa11, sb);
        __builtin_amdgcn_s_setprio(0);
        const u32 base = (((c<2) ? cb_lo : cb_hi) >> ((c&1)*16 + g*4));
        const u32 cw0 = base | rf0;
        const u32 cw1 = base | rf1;
        float e0[4], e1[4];
        #pragma unroll
        for(int r=0;r<4;r++){
          // sv <= 0 always (ME is the global max); exp2 of finite negative is safe.
          const float x0 = exp2f(fmaf(sa[r], SC, -ME));
          const float x1 = exp2f(fmaf(sb[r], SC, -ME));
          e0[r] = ((cw0 >> r) & 1u) ? x0 : emin;
          e1[r] = ((cw1 >> r) & 1u) ? x1 : emin;
          ls0 += e0[r]; ls1 += e1[r];
        }
        Pw[wslot[c][0]]       = cvtpk(e0[0], e0[1]);
        Pw[wslot[c][1]]       = cvtpk(e0[2], e0[3]);
        Pw[512 + wslot[c][0]] = cvtpk(e1[0], e1[1]);
        Pw[512 + wslot[c][1]] = cvtpk(e1[2], e1[3]);
      }
      asm volatile("s_waitcnt lgkmcnt(0)" ::: "memory");
      __builtin_amdgcn_sched_barrier(0);
      const short8 pa00 = *(const short8*)&Pw[ra0];
      const short8 pa01 = *(const short8*)&Pw[ra1];
      const short8 pa10 = *(const short8*)&Pw[512 + ra0];
      const short8 pa11 = *(const short8*)&Pw[512 + ra1];
      #pragma unroll
      for(int d=0;d<4;d++){
        const int rr = d*16 + lr;
        const short8 vb0 = *(const short8*)&Vp[rr*64 + ((g ^ (rr&7))<<3)];
        const short8 vb1 = *(const short8*)&Vp[rr*64 + (((g+4) ^ (rr&7))<<3)];
        __builtin_amdgcn_s_setprio(1);
        acc0[d] = mfma16(pa00, vb0, acc0[d]);
        acc0[d] = mfma16(pa01, vb1, acc0[d]);
        acc1[d] = mfma16(pa10, vb0, acc1[d]);
        acc1[d] = mfma16(pa11, vb1, acc1[d]);
        __builtin_amdgcn_s_setprio(0);
      }
    }
    cur ^= 1;
  }
  ls0 += __shfl_xor(ls0, 16); ls0 += __shfl_xor(ls0, 32);
  ls1 += __shfl_xor(ls1, 16); ls1 += __shfl_xor(ls1, 32);
  float inv0[4], inv1[4];
  #pragma unroll
  for(int r=0;r<4;r++){ inv0[r] = 1.f / __shfl(ls0, g*4 + r); inv1[r] = 1.f / __shfl(ls1, g*4 + r); }
  #pragma unroll
  for(int d=0;d<4;d++)
    #pragma unroll
    for(int r=0;r<4;r++){
      const int qr0 = qt*128 + wv*16 + g*4 + r;
      o[((size_t)b*1024 + qr0)*512 + h*64 + d*16 + lr]        = f2bf(acc0[d][r] * inv0[r]);
      o[((size_t)b*1024 + qr0 + 64)*512 + h*64 + d*16 + lr]   = f2bf(acc1[d][r] * inv1[r]);
    }
}

// ---------------- host ----------------
extern "C" void kernel_launch(void* const* d_in, const int* in_sizes, int n_in,
                              void* d_out, int out_size, void* d_ws, size_t ws_size,
                              hipStream_t stream)
{
  const float* img     = (const float*)d_in[0];
  const int*   mask    = (const int*)d_in[1];
  const float* conv1_w = (const float*)d_in[2];
  const float* conv1_b = (const float*)d_in[3];
  const float* ln_p_g  = (const float*)d_in[4];
  const float* ln_p_b  = (const float*)d_in[5];
  const float* proj_w  = (const float*)d_in[6];
  const float* proj_b  = (const float*)d_in[7];
  const float* ln_q_g  = (const float*)d_in[8];
  const float* ln_q_b  = (const float*)d_in[9];
  const float* attn_ln_g = (const float*)d_in[10];
  const float* attn_ln_b = (const float*)d_in[11];
  const float* wqkv    = (const float*)d_in[12];
  const float* wo      = (const float*)d_in[13];
  const float* ff_ln_g = (const float*)d_in[14];
  const float* ff_ln_b = (const float*)d_in[15];
  const float* w1      = (const float*)d_in[16];
  const float* b1      = (const float*)d_in[17];
  const float* w2      = (const float*)d_in[18];
  const float* b2      = (const float*)d_in[19];
  const float* conv2_w = (const float*)d_in[20];
  const float* conv2_b = (const float*)d_in[21];

  if(ws_size < WS_NEED) return;
  char* ws = (char*)d_ws;
  u16* projWt = (u16*)(ws + O_PROJW);
  u16* qkvWt  = (u16*)(ws + O_QKVW);
  u16* woWt   = (u16*)(ws + O_WOW);
  u16* w1Wt   = (u16*)(ws + O_W1W);
  u16* w2Wt   = (u16*)(ws + O_W2W);
  u16* c1Wt   = (u16*)(ws + O_C1W);
  u16* c2Wt   = (u16*)(ws + O_C2W);
  u16* pcl    = (u16*)(ws + O_RA);      // pcl1 / vt / pcl2
  float* tmpf = (float*)(ws + O_RA);
  u16* vtb    = (u16*)(ws + O_RA);      // v^T during layer loop
  float* patches = (float*)(ws + O_RB);
  u16* qkvb   = (u16*)(ws + O_RB);      // q|k (v folded into vt), each 8*8*1024*64
  float* xbuf = (float*)(ws + O_X);
  u16* xnbf   = (u16*)(ws + O_D);
  u16* obf    = (u16*)(ws + O_F);
  u32* minbuf = (u32*)(ws + O_MIN);
  u64* rmbits = (u64*)(ws + O_RMB);

  hipMemsetAsync(ws + O_MIN, 0xFF, 32, stream);       // min keys -> UINT_MAX
  hipMemsetAsync(ws + O_MIN + 32, 0, 32, stream);     // max keys -> 0
  hipMemsetAsync(ws + O_RA, 0, 22302720, stream);     // pcl1 zero borders

  // weight conversion
  k_transpose_bf<<<dim3(16,16,1),256,0,stream>>>(proj_w, projWt, 512, 512);
  k_transpose_bf<<<dim3(16,48,6),256,0,stream>>>(wqkv,   qkvWt,  512, 1536);
  k_transpose_bf<<<dim3(16,16,6),256,0,stream>>>(wo,     woWt,   512, 512);
  k_transpose_bf<<<dim3(16,16,6),256,0,stream>>>(w1,     w1Wt,   512, 512);
  k_transpose_bf<<<dim3(16,16,6),256,0,stream>>>(w2,     w2Wt,   512, 512);
  k_convw<<<1440,256,0,stream>>>(conv1_w, c1Wt, 128, 320);
  k_convw<<<1440,256,0,stream>>>(conv2_w, c2Wt, 320, 128);
  k_rmask<<<192,256,0,stream>>>(mask, rmbits);

  // patch embed
  k_pad_img<<<dim3(512,5),256,0,stream>>>(img, pcl);
  k_gemm<5,320><<<dim3(256,2),256,0,stream>>>(pcl, c1Wt, conv1_b, patches, nullptr, 32768, 128, 2880);
  k_ln_bf<<<2048,256,0,stream>>>(patches, ln_p_g, ln_p_b, xnbf);
  k_gemm64<0><<<dim3(128,8),256,0,stream>>>(xnbf, projWt, proj_b, tmpf, nullptr, 512);
  k_lnq_pos<<<2048,256,0,stream>>>(tmpf, ln_q_g, ln_q_b, xbuf);

  const u16* qb = qkvb;
  const u16* kb = qkvb + 4194304;
  for(int i=0;i<6;i++){
    k_ln_bf<<<2048,256,0,stream>>>(xbuf, attn_ln_g + i*512, attn_ln_b + i*512, xnbf);
    k_gemmW<<<dim3(64,24),256,0,stream>>>(xnbf, qkvWt + (size_t)i*1536*512, qkvb, vtb, 512);
    k_attn_minmax<<<512,256,0,stream>>>(qb, kb, minbuf, i);
    k_attn<<<512,256,0,stream>>>(qb, kb, vtb, rmbits, minbuf, obf, i);
    k_gemm64<2><<<dim3(128,8),256,0,stream>>>(obf, woWt + (size_t)i*512*512, nullptr, xbuf, xbuf, 512);
    k_ln_bf<<<2048,256,0,stream>>>(xbuf, ff_ln_g + i*512, ff_ln_b + i*512, xnbf);
    k_gemm64<3><<<dim3(128,8),256,0,stream>>>(xnbf, w1Wt + (size_t)i*512*512, b1 + i*512, obf, nullptr, 512);
    k_gemm64<4><<<dim3(128,8),256,0,stream>>>(obf, w2Wt + (size_t)i*512*512, b2 + i*512, xbuf, xbuf, 512);
  }

  // final conv
  hipMemsetAsync(ws + O_RA, 0, 8921088, stream);    // pcl2 zero borders
  k_pad_tok<<<16384,256,0,stream>>>(xbuf, pcl);
  k_gemm<6,128><<<dim3(256,5),256,0,stream>>>(pcl, c2Wt, conv2_b, d_out, nullptr, 32768, 320, 1152);
}

// Round 16
// 920.308 us; speedup vs baseline: 1.2297x; 1.0028x over previous
//
#include <hip/hip_runtime.h>
#include <hip/hip_bf16.h>
#include <math.h>

typedef __attribute__((ext_vector_type(8))) short short8;
typedef __attribute__((ext_vector_type(4))) float f32x4;
typedef unsigned short u16;
typedef unsigned int u32;
typedef unsigned long long u64;

#define DEV __device__ __forceinline__

DEV float bf2f(u16 u){ u32 x = ((u32)u)<<16; return __builtin_bit_cast(float, x); }
DEV u16 f2bf(float f){ u32 x = __builtin_bit_cast(u32, f); return (u16)((x + 0x7FFFu + ((x>>16)&1u))>>16); }
DEV f32x4 mfma16(short8 a, short8 b, f32x4 c){ return __builtin_amdgcn_mfma_f32_16x16x32_bf16(a,b,c,0,0,0); }
DEV void gload16(const void* g, void* l){
  __builtin_amdgcn_global_load_lds((const __attribute__((address_space(1))) void*)g,
                                   (__attribute__((address_space(3))) void*)l, 16, 0, 0);
}
DEV u32 fkey(float f){ u32 b = __builtin_bit_cast(u32, f); return (b & 0x80000000u) ? ~b : (b ^ 0x80000000u); }
DEV float funkey(u32 k){ u32 b = (k & 0x80000000u) ? (k ^ 0x80000000u) : ~k; return __builtin_bit_cast(float, b); }
DEV u32 cvtpk(float lo, float hi){ u32 d; asm("v_cvt_pk_bf16_f32 %0, %1, %2" : "=v"(d) : "v"(lo), "v"(hi)); return d; }

// ---------------- workspace layout (bytes) ----------------
static constexpr size_t O_PROJW = 0;                         // 512*512*2
static constexpr size_t O_QKVW  = O_PROJW + 524288;          // 6*1536*512*2
static constexpr size_t O_WOW   = O_QKVW + 9437184;          // 6*512*512*2
static constexpr size_t O_W1W   = O_WOW + 3145728;
static constexpr size_t O_W2W   = O_W1W + 3145728;
static constexpr size_t O_C1W   = O_W2W + 3145728;           // 128*2880*2
static constexpr size_t O_C2W   = O_C1W + 737280;            // 320*1152*2
static constexpr size_t O_RA    = O_C2W + 737280;            // pcl1 22.3MB / tmp f32 / vt 8.4MB / pcl2
static constexpr size_t O_RB    = O_RA + 22302720;           // patches f32 16.8MB then qkv bf16 25.2MB
static constexpr size_t O_X     = O_RB + 25165824;           // x f32 16.8MB
static constexpr size_t O_D     = O_X + 16777216;            // xn bf16 8.4MB
static constexpr size_t O_F     = O_D + 8388608;             // o/g bf16 8.4MB
static constexpr size_t O_RM    = O_F + 8388608;             // 48*1024 u8
static constexpr size_t O_MIN   = O_RM + 49152;              // min keys [0..5], max keys [8..13]
static constexpr size_t O_RMB   = O_MIN + 256;               // 48*16 u64 bit-packed masks
static constexpr size_t WS_NEED = O_RMB + 8192;

// ---------------- weight conversion ----------------
// src [z][K][N] f32 -> dst [z][N][K] bf16
__global__ __launch_bounds__(256) void k_transpose_bf(const float* __restrict__ src, u16* __restrict__ dst, int K, int N){
  __shared__ float tile[32][33];
  const int k0 = blockIdx.x*32, n0 = blockIdx.y*32;
  src += (size_t)blockIdx.z*K*N; dst += (size_t)blockIdx.z*K*N;
  const int c = threadIdx.x & 31, r4 = threadIdx.x >> 5;
  for(int r=r4; r<32; r+=8) tile[r][c] = src[(size_t)(k0+r)*N + n0+c];
  __syncthreads();
  for(int r=r4; r<32; r+=8) dst[(size_t)(n0+r)*K + k0+c] = f2bf(tile[c][r]);
}

// conv weights [OC][IC][3][3] f32 -> Wt [OC][tap*IC+ic] bf16
__global__ __launch_bounds__(256) void k_convw(const float* __restrict__ src, u16* __restrict__ dst, int OC, int IC){
  int idx = blockIdx.x*256 + threadIdx.x;
  int total = OC*IC*9;
  if(idx >= total) return;
  int oc = idx/(IC*9); int rem = idx - oc*IC*9; int tap = rem/IC; int ic = rem - tap*IC;
  dst[idx] = f2bf(src[(size_t)(oc*IC+ic)*9 + tap]);
}

// img [8][320][64][64] f32 -> pcl1 [8][66][66][320] bf16 (interior; borders pre-zeroed)
__global__ __launch_bounds__(256) void k_pad_img(const float* __restrict__ img, u16* __restrict__ pcl){
  const int by = blockIdx.x; const int b = by>>6, y = by&63; const int c0 = blockIdx.y*64;
  __shared__ float t[64][65];
  const int tx = threadIdx.x & 63, tz = threadIdx.x >> 6;
  for(int ci=tz; ci<64; ci+=4) t[ci][tx] = img[(((size_t)b*320 + c0+ci)*64 + y)*64 + tx];
  __syncthreads();
  for(int x=tz; x<64; x+=4) pcl[(((size_t)b*66 + y+1)*66 + (x+1))*320 + c0 + tx] = f2bf(t[tx][x]);
}

// x tokens f32 -> pcl2 [8][66][66][128] bf16 (interior)
__global__ __launch_bounds__(256) void k_pad_tok(const float* __restrict__ x, u16* __restrict__ pcl){
  int idx = blockIdx.x*256 + threadIdx.x;           // 8*64*64*128
  const int c = idx & 127; int r = idx >> 7; const int xx = r & 63; r >>= 6; const int yy = r & 63; const int b = r >> 6;
  const int n = (yy>>1)*32 + (xx>>1); const int f = (yy&1)*256 + (xx&1)*128 + c;
  pcl[(((size_t)b*66 + yy+1)*66 + xx+1)*128 + c] = f2bf(x[((size_t)b*1024 + n)*512 + f]);
}

// mask [48][64][64] int -> rmbits [48][16] u64 (2x2 any)
__global__ __launch_bounds__(256) void k_rmask(const int* __restrict__ mask, u64* __restrict__ rmbits){
  int idx = blockIdx.x*256 + threadIdx.x;
  const int m = idx >> 10, n = idx & 1023; const int h = n>>5, w = n&31;
  const int* mp = mask + ((size_t)m*64 + h*2)*64 + w*2;
  const int v = (mp[0]==1) | (mp[1]==1) | (mp[64]==1) | (mp[65]==1);
  const u64 bm = __ballot(v);
  if((threadIdx.x & 63) == 0) rmbits[idx>>6] = bm;
}

// ---------------- layernorm (wave per token) ----------------
__global__ __launch_bounds__(256) void k_ln_bf(const float* __restrict__ in, const float* __restrict__ gw,
                                               const float* __restrict__ bw, u16* __restrict__ out){
  const int tok = blockIdx.x*4 + (threadIdx.x>>6);
  const int lane = threadIdx.x & 63;
  const float* rp = in + (size_t)tok*512 + lane*8;
  const float4 a = *(const float4*)rp;
  const float4 b = *(const float4*)(rp+4);
  float s  = a.x+a.y+a.z+a.w + b.x+b.y+b.z+b.w;
  float sq = a.x*a.x+a.y*a.y+a.z*a.z+a.w*a.w + b.x*b.x+b.y*b.y+b.z*b.z+b.w*b.w;
  #pragma unroll
  for(int off=1; off<64; off<<=1){ s += __shfl_xor(s,off); sq += __shfl_xor(sq,off); }
  const float mu = s*(1.f/512.f);
  const float rs = rsqrtf(fmaxf(sq*(1.f/512.f) - mu*mu, 0.f) + 1e-5f);
  const float4 g0 = *(const float4*)(gw + lane*8);
  const float4 g1 = *(const float4*)(gw + lane*8 + 4);
  const float4 b0 = *(const float4*)(bw + lane*8);
  const float4 b1 = *(const float4*)(bw + lane*8 + 4);
  short8 o8;
  o8[0]=f2bf((a.x-mu)*rs*g0.x+b0.x); o8[1]=f2bf((a.y-mu)*rs*g0.y+b0.y);
  o8[2]=f2bf((a.z-mu)*rs*g0.z+b0.z); o8[3]=f2bf((a.w-mu)*rs*g0.w+b0.w);
  o8[4]=f2bf((b.x-mu)*rs*g1.x+b1.x); o8[5]=f2bf((b.y-mu)*rs*g1.y+b1.y);
  o8[6]=f2bf((b.z-mu)*rs*g1.z+b1.z); o8[7]=f2bf((b.w-mu)*rs*g1.w+b1.w);
  *(short8*)(out + (size_t)tok*512 + lane*8) = o8;
}

// LN + sincos 2d posemb -> f32 x (wave per token)
__global__ __launch_bounds__(256) void k_lnq_pos(const float* __restrict__ in, const float* __restrict__ gw,
                                                 const float* __restrict__ bw, float* __restrict__ out){
  const int tok = blockIdx.x*4 + (threadIdx.x>>6);
  const int lane = threadIdx.x & 63;
  const float* rp = in + (size_t)tok*512 + lane*8;
  const float4 a = *(const float4*)rp;
  const float4 b = *(const float4*)(rp+4);
  float s  = a.x+a.y+a.z+a.w + b.x+b.y+b.z+b.w;
  float sq = a.x*a.x+a.y*a.y+a.z*a.z+a.w*a.w + b.x*b.x+b.y*b.y+b.z*b.z+b.w*b.w;
  #pragma unroll
  for(int off=1; off<64; off<<=1){ s += __shfl_xor(s,off); sq += __shfl_xor(sq,off); }
  const float mu = s*(1.f/512.f);
  const float rs = rsqrtf(fmaxf(sq*(1.f/512.f) - mu*mu, 0.f) + 1e-5f);
  const int n = tok & 1023; const int yy = n>>5, xx = n&31;
  const int f0 = lane*8; const int sec = f0>>7;
  const float coord = (sec<2) ? (float)xx : (float)yy;
  const float vv[8] = {a.x,a.y,a.z,a.w,b.x,b.y,b.z,b.w};
  float ov[8];
  #pragma unroll
  for(int j=0;j<8;j++){
    const int f = f0+j; const int qq = f & 127;
    const float om = __expf(-(float)qq * (9.2103403719761836f/127.f));
    const float arg = coord * om;
    const float pe = (sec&1) ? __cosf(arg) : __sinf(arg);
    ov[j] = (vv[j]-mu)*rs*gw[f] + bw[f] + pe;
  }
  float* op = out + (size_t)tok*512 + f0;
  *(float4*)op = (float4){ov[0],ov[1],ov[2],ov[3]};
  *(float4*)(op+4) = (float4){ov[4],ov[5],ov[6],ov[7]};
}

// ---------------- GEMM 64x64 tile (4 blocks/CU) for N=512 layers ----------------
// EPI: 0 proj(f32+bias) 2 resid(f32) 3 gelu(bf16+bias) 4 resid+bias
template<int EPI>
__global__ __launch_bounds__(256, 4)
void k_gemm64(const u16* __restrict__ A, const u16* __restrict__ Wt,
              const float* __restrict__ bias, void* __restrict__ outp,
              const float* __restrict__ resid, int Kd)
{
  __shared__ u16 Ald[2][4096];
  __shared__ u16 Bld[2][4096];
  const int tid = threadIdx.x, lane = tid & 63, wv = tid >> 6;
  const int lr = lane & 15, g = lane >> 4;
  const int m0 = blockIdx.x * 64, n0 = blockIdx.y * 64;
  const int wm = (wv >> 1) * 32, wn = (wv & 1) * 32;
  const int srow = tid >> 3;
  const int sc  = (tid & 7) ^ (srow & 7);
  const u16* arow0p = A + (size_t)(m0+srow)*Kd + sc*8;
  const u16* arow1p = A + (size_t)(m0+srow+32)*Kd + sc*8;
  const u16* brow0p = Wt + (size_t)(n0+srow)*Kd + sc*8;
  const u16* brow1p = Wt + (size_t)(n0+srow+32)*Kd + sc*8;

  f32x4 acc[2][2];
  #pragma unroll
  for(int i=0;i<2;i++)
    #pragma unroll
    for(int j=0;j<2;j++) acc[i][j] = (f32x4){0.f,0.f,0.f,0.f};

  const int nIter = Kd >> 6;
  int cur = 0;
  auto stage = [&](int kt, int buf){
    const int k0 = kt << 6;
    gload16(arow0p + k0, &Ald[buf][tid*8]);
    gload16(arow1p + k0, &Ald[buf][2048 + tid*8]);
    gload16(brow0p + k0, &Bld[buf][tid*8]);
    gload16(brow1p + k0, &Bld[buf][2048 + tid*8]);
  };

  stage(0, 0);
  for(int kt=0; kt<nIter; ++kt){
    __syncthreads();
    if(kt+1 < nIter) stage(kt+1, cur^1);
    short8 af[2][2], bg[2][2];
    #pragma unroll
    for(int mi=0;mi<2;mi++)
      #pragma unroll
      for(int kk=0;kk<2;kk++){
        const int R = wm + mi*16 + lr;
        const int Rn = wn + mi*16 + lr;
        const int c = kk*4 + g;
        af[mi][kk] = *(const short8*)&Ald[cur][R*64 + ((c ^ (R&7))<<3)];
        bg[mi][kk] = *(const short8*)&Bld[cur][Rn*64 + ((c ^ (Rn&7))<<3)];
      }
    #pragma unroll
    for(int mi=0;mi<2;mi++)
      #pragma unroll
      for(int nj=0;nj<2;nj++)
        #pragma unroll
        for(int kk=0;kk<2;kk++)
          acc[mi][nj] = mfma16(af[mi][kk], bg[nj][kk], acc[mi][nj]);
    cur ^= 1;
  }

  #pragma unroll
  for(int mi=0;mi<2;mi++){
    #pragma unroll
    for(int nj=0;nj<2;nj++){
      #pragma unroll
      for(int r=0;r<4;r++){
        const int mrow = m0 + wm + mi*16 + g*4 + r;
        const int ncol = n0 + wn + nj*16 + lr;
        float val = acc[mi][nj][r];
        if constexpr (EPI==0 || EPI==3 || EPI==4)
          val += bias[ncol];
        if constexpr (EPI==0){
          ((float*)outp)[(size_t)mrow*512 + ncol] = val;
        } else if constexpr (EPI==2 || EPI==4){
          const size_t idx = (size_t)mrow*512 + ncol;
          ((float*)outp)[idx] = resid[idx] + val;
        } else if constexpr (EPI==3){
          const float gl = 0.5f * val * (1.f + erff(val * 0.70710678118654752f));
          ((u16*)outp)[(size_t)mrow*512 + ncol] = f2bf(gl);
        }
      }
    }
  }
}

// ---------------- conv1 GEMM: 64x64 tile, 4 blocks/CU, tap addressing, patches epilogue ----------------
__global__ __launch_bounds__(256, 4)
void k_gemmC(const u16* __restrict__ A, const u16* __restrict__ Wt,
             const float* __restrict__ bias, float* __restrict__ outp, int Kd)
{
  __shared__ u16 Ald[2][4096];
  __shared__ u16 Bld[2][4096];
  const int tid = threadIdx.x, lane = tid & 63, wv = tid >> 6;
  const int lr = lane & 15, g = lane >> 4;
  const int m0 = blockIdx.x * 64, n0 = blockIdx.y * 64;
  const int wm = (wv >> 1) * 32, wn = (wv & 1) * 32;
  const int srow = tid >> 3;
  const int sc  = (tid & 7) ^ (srow & 7);
  const int b0 = m0 >> 12, y0 = (m0 >> 6) & 63;
  const u16* brow0p = Wt + (size_t)(n0+srow)*Kd + sc*8;
  const u16* brow1p = Wt + (size_t)(n0+srow+32)*Kd + sc*8;

  f32x4 acc[2][2];
  #pragma unroll
  for(int i=0;i<2;i++)
    #pragma unroll
    for(int j=0;j<2;j++) acc[i][j] = (f32x4){0.f,0.f,0.f,0.f};

  const int nIter = Kd >> 6;
  int cur = 0;
  auto stage = [&](int kt, int buf){
    const int k0 = kt << 6;
    const int tap = k0 / 320;
    const int ic0 = k0 - tap*320;
    const int ky = tap/3, kx = tap - 3*(tap/3);
    const size_t rb0 = ((size_t)((b0*66 + y0+ky)*66 + kx))*320 + ic0 + sc*8;
    gload16(A + rb0 + (size_t)(srow)*320,    &Ald[buf][tid*8]);
    gload16(A + rb0 + (size_t)(srow+32)*320, &Ald[buf][2048 + tid*8]);
    gload16(brow0p + k0, &Bld[buf][tid*8]);
    gload16(brow1p + k0, &Bld[buf][2048 + tid*8]);
  };

  stage(0, 0);
  for(int kt=0; kt<nIter; ++kt){
    __syncthreads();
    if(kt+1 < nIter) stage(kt+1, cur^1);
    short8 af[2][2], bg[2][2];
    #pragma unroll
    for(int mi=0;mi<2;mi++)
      #pragma unroll
      for(int kk=0;kk<2;kk++){
        const int R = wm + mi*16 + lr;
        const int Rn = wn + mi*16 + lr;
        const int c = kk*4 + g;
        af[mi][kk] = *(const short8*)&Ald[cur][R*64 + ((c ^ (R&7))<<3)];
        bg[mi][kk] = *(const short8*)&Bld[cur][Rn*64 + ((c ^ (Rn&7))<<3)];
      }
    #pragma unroll
    for(int mi=0;mi<2;mi++)
      #pragma unroll
      for(int nj=0;nj<2;nj++)
        #pragma unroll
        for(int kk=0;kk<2;kk++)
          acc[mi][nj] = mfma16(af[mi][kk], bg[nj][kk], acc[mi][nj]);
    cur ^= 1;
  }

  #pragma unroll
  for(int mi=0;mi<2;mi++){
    #pragma unroll
    for(int nj=0;nj<2;nj++){
      #pragma unroll
      for(int r=0;r<4;r++){
        const int mrow = m0 + wm + mi*16 + g*4 + r;
        const int ncol = n0 + wn + nj*16 + lr;
        const float val = acc[mi][nj][r] + bias[ncol];
        const int b = mrow>>12; const int rr = mrow&4095; const int y = rr>>6; const int xx = rr&63;
        const size_t pidx = ((size_t)(b*1024 + (y>>1)*32 + (xx>>1)))*512 + (y&1)*256 + (xx&1)*128 + ncol;
        outp[pidx] = val;
      }
    }
  }
}

// ---------------- wide GEMM (128x64 tile) for conv2 ----------------
// EPI: 6 conv2->out
template<int EPI, int CONVC>
__global__ __launch_bounds__(256, 3)
void k_gemm(const u16* __restrict__ A, const u16* __restrict__ Wt,
            const float* __restrict__ bias, void* __restrict__ outp,
            const float* __restrict__ resid, int M, int N, int Kd)
{
  __shared__ u16 Ald[2][8192];                        // [128][64] (4 chunks of 32 rows)
  __shared__ u16 Bld[2][4096];                        // [64][64]
  const int tid = threadIdx.x, lane = tid & 63, wv = tid >> 6;
  const int lr = lane & 15, g = lane >> 4;
  const int m0 = blockIdx.x * 128, n0 = blockIdx.y * 64;
  const int wm = wv * 32;
  const int srow = tid >> 3;
  const int sc  = (tid & 7) ^ (srow & 7);
  int b0=0, y0=0;
  if constexpr (CONVC != 0){ b0 = m0>>12; y0 = (m0>>6)&63; }
  const u16* ar[4];
  if constexpr (CONVC == 0){
    #pragma unroll
    for(int j=0;j<4;j++) ar[j] = A + (size_t)(m0+srow+32*j)*Kd + sc*8;
  }
  const u16* br0 = Wt + (size_t)(n0+srow)*Kd + sc*8;
  const u16* br1 = Wt + (size_t)(n0+srow+32)*Kd + sc*8;

  f32x4 acc[2][4];
  #pragma unroll
  for(int i=0;i<2;i++)
    #pragma unroll
    for(int j=0;j<4;j++) acc[i][j] = (f32x4){0.f,0.f,0.f,0.f};

  const int nIter = Kd >> 6;
  int cur = 0;

  auto stage = [&](int kt, int buf){
    const int k0 = kt << 6;
    if constexpr (CONVC != 0){
      const int tap = k0 / CONVC;
      const int ic0 = k0 - tap*CONVC;
      const int ky = tap/3, kx = tap - 3*(tap/3);
      #pragma unroll
      for(int j=0;j<4;j++){
        const int xr = srow + 32*(j&1);
        const int yr = y0 + (j>>1) + ky;
        const u16* ga = A + ((size_t)((b0*66 + yr)*66 + xr + kx))*CONVC + ic0 + sc*8;
        gload16(ga, &Ald[buf][j*2048 + tid*8]);
      }
    } else {
      #pragma unroll
      for(int j=0;j<4;j++) gload16(ar[j] + k0, &Ald[buf][j*2048 + tid*8]);
    }
    gload16(br0 + k0, &Bld[buf][tid*8]);
    gload16(br1 + k0, &Bld[buf][2048 + tid*8]);
  };

  stage(0, 0);
  for(int kt=0; kt<nIter; ++kt){
    __syncthreads();
    if(kt+1 < nIter) stage(kt+1, cur^1);
    short8 af[2][2], bg[4][2];
    #pragma unroll
    for(int mi=0;mi<2;mi++)
      #pragma unroll
      for(int kk=0;kk<2;kk++){
        const int R = wm + mi*16 + lr;
        const int c = kk*4 + g;
        af[mi][kk] = *(const short8*)&Ald[cur][R*64 + ((c ^ (R&7))<<3)];
      }
    #pragma unroll
    for(int nj=0;nj<4;nj++)
      #pragma unroll
      for(int kk=0;kk<2;kk++){
        const int Rn = nj*16 + lr;
        const int c = kk*4 + g;
        bg[nj][kk] = *(const short8*)&Bld[cur][Rn*64 + ((c ^ (Rn&7))<<3)];
      }
    #pragma unroll
    for(int mi=0;mi<2;mi++)
      #pragma unroll
      for(int nj=0;nj<4;nj++)
        #pragma unroll
        for(int kk=0;kk<2;kk++)
          acc[mi][nj] = mfma16(af[mi][kk], bg[nj][kk], acc[mi][nj]);
    cur ^= 1;
  }

  #pragma unroll
  for(int mi=0;mi<2;mi++){
    #pragma unroll
    for(int nj=0;nj<4;nj++){
      #pragma unroll
      for(int r=0;r<4;r++){
        const int mrow = m0 + wm + mi*16 + g*4 + r;
        const int ncol = n0 + nj*16 + lr;
        float val = acc[mi][nj][r] + bias[ncol];
        if constexpr (EPI==5){
          const int b = mrow>>12; const int rr = mrow&4095; const int y = rr>>6; const int xx = rr&63;
          const size_t pidx = ((size_t)(b*1024 + (y>>1)*32 + (xx>>1)))*512 + (y&1)*256 + (xx&1)*128 + ncol;
          ((float*)outp)[pidx] = val;
        } else if constexpr (EPI==6){
          const int b = mrow>>12; const int rr = mrow&4095; const int y = rr>>6; const int xx = rr&63;
          ((float*)outp)[(((size_t)(b*320 + ncol))*64 + y)*64 + xx] = val;
        }
      }
    }
  }
}

// ---------------- wide GEMM for qkv: 128x64 tile, BK=64; q/k scatter; v -> vt directly ----------------
__global__ __launch_bounds__(256, 3)
void k_gemmW(const u16* __restrict__ A, const u16* __restrict__ Wt,
             void* __restrict__ outp, u16* __restrict__ vt, int Kd)
{
  __shared__ u16 Ald[2][8192];                       // [128][64]; reused as Vt bounce tile
  __shared__ u16 Bld[2][4096];                       // [64][64]
  const int tid = threadIdx.x, lane = tid & 63, wv = tid >> 6;
  const int lr = lane & 15, g = lane >> 4;
  const int m0 = blockIdx.x * 128, n0 = blockIdx.y * 64;
  const int wm = wv * 32;
  const int srow = tid >> 3;
  const int sc  = (tid & 7) ^ (srow & 7);
  const u16* ar[4];
  #pragma unroll
  for(int j=0;j<4;j++) ar[j] = A + (size_t)(m0+srow+32*j)*Kd + sc*8;
  const u16* br0 = Wt + (size_t)(n0+srow)*Kd + sc*8;
  const u16* br1 = Wt + (size_t)(n0+srow+32)*Kd + sc*8;

  f32x4 acc[2][4];
  #pragma unroll
  for(int i=0;i<2;i++)
    #pragma unroll
    for(int j=0;j<4;j++) acc[i][j] = (f32x4){0.f,0.f,0.f,0.f};

  const int nIter = Kd >> 6;
  int cur = 0;
  auto stage = [&](int kt, int buf){
    const int k0 = kt << 6;
    #pragma unroll
    for(int j=0;j<4;j++) gload16(ar[j] + k0, &Ald[buf][j*2048 + tid*8]);
    gload16(br0 + k0, &Bld[buf][tid*8]);
    gload16(br1 + k0, &Bld[buf][2048 + tid*8]);
  };

  stage(0, 0);
  for(int kt=0; kt<nIter; ++kt){
    __syncthreads();
    if(kt+1 < nIter) stage(kt+1, cur^1);
    short8 af[2][2], bg[4][2];
    #pragma unroll
    for(int mi=0;mi<2;mi++)
      #pragma unroll
      for(int kk=0;kk<2;kk++){
        const int R = wm + mi*16 + lr;
        const int c = kk*4 + g;
        af[mi][kk] = *(const short8*)&Ald[cur][R*64 + ((c ^ (R&7))<<3)];
      }
    #pragma unroll
    for(int nj=0;nj<4;nj++)
      #pragma unroll
      for(int kk=0;kk<2;kk++){
        const int Rn = nj*16 + lr;
        const int c = kk*4 + g;
        bg[nj][kk] = *(const short8*)&Bld[cur][Rn*64 + ((c ^ (Rn&7))<<3)];
      }
    #pragma unroll
    for(int mi=0;mi<2;mi++)
      #pragma unroll
      for(int nj=0;nj<4;nj++)
        #pragma unroll
        for(int kk=0;kk<2;kk++)
          acc[mi][nj] = mfma16(af[mi][kk], bg[nj][kk], acc[mi][nj]);
    cur ^= 1;
  }

  if(n0 < 1024){
    // q/k scatter epilogue
    #pragma unroll
    for(int mi=0;mi<2;mi++){
      #pragma unroll
      for(int nj=0;nj<4;nj++){
        #pragma unroll
        for(int r=0;r<4;r++){
          const int mrow = m0 + wm + mi*16 + g*4 + r;
          const int ncol = n0 + nj*16 + lr;
          const int sec = ncol >> 9, rem = ncol & 511;
          const int head = rem >> 6, d = rem & 63;
          const int b = mrow >> 10, t = mrow & 1023;
          ((u16*)outp)[(size_t)sec*4194304 + ((size_t)((b*8+head)*1024 + t))*64 + d] = f2bf(acc[mi][nj][r]);
        }
      }
    }
  } else {
    // v block: write vt[bh][d][t] directly via LDS bounce (raw v never materialized)
    const int head = (n0 - 1024) >> 6;
    const int b = m0 >> 10;
    const int t0 = m0 & 1023;
    const int bh = b*8 + head;
    __syncthreads();                                  // all waves done reading Ald
    u16* Vt = (u16*)Ald;                              // [64 d][136] (stride 272B, 16B-aligned)
    #pragma unroll
    for(int mi=0;mi<2;mi++)
      #pragma unroll
      for(int nj=0;nj<4;nj++)
        #pragma unroll
        for(int r=0;r<4;r++){
          const int lt = wm + mi*16 + g*4 + r;
          const int d  = nj*16 + lr;
          Vt[d*136 + lt] = f2bf(acc[mi][nj][r]);
        }
    __syncthreads();
    const int d = tid >> 2, qd = tid & 3;             // 64 d-rows x 4 chunks of 32 t
    u16* dst = vt + (size_t)bh*65536 + (size_t)d*1024 + t0 + qd*32;
    const u16* srcl = &Vt[d*136 + qd*32];
    #pragma unroll
    for(int e4=0;e4<4;e4++)
      *(short8*)(dst + e4*8) = *(const short8*)(srcl + e4*8);
  }
}

// ---------------- attention pass A: global min AND max, 128-q tile, 128-j staged (8 barriers) ----------------
__global__ __launch_bounds__(256, 4)
void k_attn_minmax(const u16* __restrict__ q, const u16* __restrict__ k, u32* __restrict__ keys, int layer){
  const int id = blockIdx.x;                   // 512 blocks
  const int qt = (id>>3)&7;
  const int bh = ((id&7)<<3) | (id>>6);
  __shared__ u16 Kld[2][8192];                 // [2 buf][2 sub][64 rows][64]
  __shared__ float redn[4], redx[4];
  const int tid = threadIdx.x, lane = tid & 63, wv = tid >> 6;
  const int lr = lane & 15, g = lane >> 4;
  const u16* qp0 = q + ((size_t)bh*1024 + qt*128 + wv*16 + lr)*64;
  const u16* qp1 = qp0 + 64*64;
  const short8 qa00 = *(const short8*)(qp0 + g*8);
  const short8 qa01 = *(const short8*)(qp0 + 32 + g*8);
  const short8 qa10 = *(const short8*)(qp1 + g*8);
  const short8 qa11 = *(const short8*)(qp1 + 32 + g*8);
  const u16* kbase = k + (size_t)bh*65536;
  const int srow = tid>>3, scs = lane&7;
  const int scg = scs ^ (srow&7);
  float mn = 3.0e38f, mx = -3.0e38f;
  auto stageK = [&](int jt, int buf){
    const int j0 = jt << 7;
    #pragma unroll
    for(int j=0;j<4;j++)
      gload16(kbase + (size_t)(j0 + srow + 32*j)*64 + scg*8, &Kld[buf][j*2048 + tid*8]);
  };
  stageK(0, 0);
  int cur = 0;
  for(int jt=0; jt<8; ++jt){
    __syncthreads();
    if(jt < 7) stageK(jt+1, cur^1);
    #pragma unroll
    for(int s=0;s<2;s++){
      const u16* Kp = &Kld[cur][s*4096];
      #pragma unroll
      for(int c=0;c<4;c++){
        const int rr = c*16 + lr;
        const short8 kb0 = *(const short8*)&Kp[rr*64 + ((g ^ (rr&7))<<3)];
        const short8 kb1 = *(const short8*)&Kp[rr*64 + (((g+4) ^ (rr&7))<<3)];
        f32x4 sa = (f32x4){0.f,0.f,0.f,0.f};
        f32x4 sb = (f32x4){0.f,0.f,0.f,0.f};
        __builtin_amdgcn_s_setprio(1);
        sa = mfma16(qa00, kb0, sa);
        sa = mfma16(qa01, kb1, sa);
        sb = mfma16(qa10, kb0, sb);
        sb = mfma16(qa11, kb1, sb);
        __builtin_amdgcn_s_setprio(0);
        mn = fminf(mn, fminf(fminf(sa[0],sa[1]), fminf(sa[2],sa[3])));
        mx = fmaxf(mx, fmaxf(fmaxf(sa[0],sa[1]), fmaxf(sa[2],sa[3])));
        mn = fminf(mn, fminf(fminf(sb[0],sb[1]), fminf(sb[2],sb[3])));
        mx = fmaxf(mx, fmaxf(fmaxf(sb[0],sb[1]), fmaxf(sb[2],sb[3])));
      }
    }
    cur ^= 1;
  }
  mn *= 0.125f; mx *= 0.125f;
  #pragma unroll
  for(int off=32; off; off>>=1){
    mn = fminf(mn, __shfl_down(mn, off));
    mx = fmaxf(mx, __shfl_down(mx, off));
  }
  if(lane==0){ redn[wv] = mn; redx[wv] = mx; }
  __syncthreads();
  if(tid==0){
    atomicMin(keys + layer,     fkey(fminf(fminf(redn[0],redn[1]), fminf(redn[2],redn[3]))));
    atomicMax(keys + 8 + layer, fkey(fmaxf(fmaxf(redx[0],redx[1]), fmaxf(redx[2],redx[3]))));
  }
}

// ---------------- attention pass B: 128-q tile, 128-j staged (8 barriers), swapped QK^T, packed P ----------------
__global__ __launch_bounds__(256, 2)
void k_attn(const u16* __restrict__ q, const u16* __restrict__ k, const u16* __restrict__ vt,
            const u64* __restrict__ rmbits, const u32* __restrict__ keys,
            u16* __restrict__ o, int layer){
  const int id = blockIdx.x;                   // 512 blocks
  const int qt = (id>>3)&7;
  const int bh = ((id&7)<<3) | (id>>6);
  const int b = bh>>3, h = bh&7;
  __shared__ u16 Kld[2][8192];                 // [buf][sub 2][64 rows][64]
  __shared__ u16 Vtld[2][8192];
  __shared__ u32 Pld[4][1024];                 // per-wave [32 qrow][32 u32]
  const int tid = threadIdx.x, lane = tid & 63, wv = tid >> 6;
  const int lr = lane & 15, g = lane >> 4;
  const int L7 = lr & 7;
  const u16* qp0 = q + ((size_t)bh*1024 + qt*128 + wv*16 + lr)*64;
  const u16* qp1 = qp0 + 64*64;
  const short8 qa00 = *(const short8*)(qp0 + g*8);
  const short8 qa01 = *(const short8*)(qp0 + 32 + g*8);
  const short8 qa10 = *(const short8*)(qp1 + g*8);
  const short8 qa11 = *(const short8*)(qp1 + 32 + g*8);
  const float L2E = 1.44269504088896f;
  const float SC = 0.125f * L2E;
  float mnv = funkey(keys[layer]);
  float mxv = funkey(keys[8+layer]);
  if(!(mnv >= -1e38f && mnv <= 1e38f)) mnv = 0.f;
  if(!(mxv >= -1e38f && mxv <= 1e38f)) mxv = 0.f;
  const float ME   = mxv * L2E;
  const float minM = fmaxf(mnv*L2E - ME, -120.f);
  const float emin = exp2f(minM);              // precomputed masked-fill value
  const u32* cbp = (const u32*)(rmbits + (size_t)(layer*8 + b)*16);
  const int rowi0 = qt*128 + wv*16 + lr;
  const int rowi1 = rowi0 + 64;
  const u32 rf0 = ((cbp[rowi0>>5] >> (rowi0&31)) & 1u) ? 0xFu : 0u;
  const u32 rf1 = ((cbp[rowi1>>5] >> (rowi1&31)) & 1u) ? 0xFu : 0u;
  u32* Pw = &Pld[wv][0];
  u32 wslot[4][2];
  #pragma unroll
  for(int c=0;c<4;c++){
    const int blk = c*2 + (g>>1);
    wslot[c][0] = lr*32 + (((blk ^ L7))<<2) + (g&1)*2;
    wslot[c][1] = wslot[c][0] + 1;
  }
  const u32 ra0 = lr*32 + ((g ^ L7)<<2);
  const u32 ra1 = lr*32 + (((4+g) ^ L7)<<2);

  float ls0 = 1e-30f, ls1 = 1e-30f;
  f32x4 acc0[4], acc1[4];
  #pragma unroll
  for(int d=0;d<4;d++){ acc0[d] = (f32x4){0.f,0.f,0.f,0.f}; acc1[d] = (f32x4){0.f,0.f,0.f,0.f}; }
  const u16* kbase = k + (size_t)bh*65536;
  const u16* vtbase = vt + (size_t)bh*65536;
  const int srow = tid>>3, scs = lane&7;
  const int scg = scs ^ (srow&7);
  auto stageKV = [&](int jt, int buf){
    const int j0 = jt << 7;
    #pragma unroll
    for(int j=0;j<4;j++)
      gload16(kbase + (size_t)(j0 + srow + 32*j)*64 + scg*8, &Kld[buf][j*2048 + tid*8]);
    #pragma unroll
    for(int s=0;s<2;s++)
      #pragma unroll
      for(int jj=0;jj<2;jj++)
        gload16(vtbase + (size_t)(srow + 32*jj)*1024 + j0 + s*64 + scg*8,
                &Vtld[buf][s*4096 + jj*2048 + tid*8]);
  };
  stageKV(0, 0);
  int cur = 0;
  for(int jt=0; jt<8; ++jt){
    __syncthreads();
    if(jt < 7) stageKV(jt+1, cur^1);
    #pragma unroll
    for(int s=0;s<2;s++){
      const int jb = jt*2 + s;
      const u32 cb_lo = cbp[jb*2], cb_hi = cbp[jb*2+1];
      const u16* Kp = &Kld[cur][s*4096];
      const u16* Vp = &Vtld[cur][s*4096];
      #pragma unroll
      for(int c=0;c<4;c++){
        const int rr = c*16 + lr;
        const short8 kb0 = *(const short8*)&Kp[rr*64 + ((g ^ (rr&7))<<3)];
        const short8 kb1 = *(const short8*)&Kp[rr*64 + (((g+4) ^ (rr&7))<<3)];
        f32x4 sa = (f32x4){0.f,0.f,0.f,0.f};
        f32x4 sb = (f32x4){0.f,0.f,0.f,0.f};
        __builtin_amdgcn_s_setprio(1);
        sa = mfma16(kb0, qa00, sa);
        sa = mfma16(kb1, qa01, sa);
        sb = mfma16(kb0, qa10, sb);
        sb = mfma16(kb1, qa11, sb);
        __builtin_amdgcn_s_setprio(0);
        const u32 base = (((c<2) ? cb_lo : cb_hi) >> ((c&1)*16 + g*4));
        const u32 cw0 = base | rf0;
        const u32 cw1 = base | rf1;
        float e0[4], e1[4];
        #pragma unroll
        for(int r=0;r<4;r++){
          // sv <= 0 always (ME is the global max); exp2 of finite negative is safe.
          const float x0 = exp2f(fmaf(sa[r], SC, -ME));
          const float x1 = exp2f(fmaf(sb[r], SC, -ME));
          e0[r] = ((cw0 >> r) & 1u) ? x0 : emin;
          e1[r] = ((cw1 >> r) & 1u) ? x1 : emin;
          ls0 += e0[r]; ls1 += e1[r];
        }
        Pw[wslot[c][0]]       = cvtpk(e0[0], e0[1]);
        Pw[wslot[c][1]]       = cvtpk(e0[2], e0[3]);
        Pw[512 + wslot[c][0]] = cvtpk(e1[0], e1[1]);
        Pw[512 + wslot[c][1]] = cvtpk(e1[2], e1[3]);
      }
      asm volatile("s_waitcnt lgkmcnt(0)" ::: "memory");
      __builtin_amdgcn_sched_barrier(0);
      const short8 pa00 = *(const short8*)&Pw[ra0];
      const short8 pa01 = *(const short8*)&Pw[ra1];
      const short8 pa10 = *(const short8*)&Pw[512 + ra0];
      const short8 pa11 = *(const short8*)&Pw[512 + ra1];
      #pragma unroll
      for(int d=0;d<4;d++){
        const int rr = d*16 + lr;
        const short8 vb0 = *(const short8*)&Vp[rr*64 + ((g ^ (rr&7))<<3)];
        const short8 vb1 = *(const short8*)&Vp[rr*64 + (((g+4) ^ (rr&7))<<3)];
        __builtin_amdgcn_s_setprio(1);
        acc0[d] = mfma16(pa00, vb0, acc0[d]);
        acc0[d] = mfma16(pa01, vb1, acc0[d]);
        acc1[d] = mfma16(pa10, vb0, acc1[d]);
        acc1[d] = mfma16(pa11, vb1, acc1[d]);
        __builtin_amdgcn_s_setprio(0);
      }
    }
    cur ^= 1;
  }
  ls0 += __shfl_xor(ls0, 16); ls0 += __shfl_xor(ls0, 32);
  ls1 += __shfl_xor(ls1, 16); ls1 += __shfl_xor(ls1, 32);
  float inv0[4], inv1[4];
  #pragma unroll
  for(int r=0;r<4;r++){ inv0[r] = 1.f / __shfl(ls0, g*4 + r); inv1[r] = 1.f / __shfl(ls1, g*4 + r); }
  #pragma unroll
  for(int d=0;d<4;d++)
    #pragma unroll
    for(int r=0;r<4;r++){
      const int qr0 = qt*128 + wv*16 + g*4 + r;
      o[((size_t)b*1024 + qr0)*512 + h*64 + d*16 + lr]        = f2bf(acc0[d][r] * inv0[r]);
      o[((size_t)b*1024 + qr0 + 64)*512 + h*64 + d*16 + lr]   = f2bf(acc1[d][r] * inv1[r]);
    }
}

// ---------------- host ----------------
extern "C" void kernel_launch(void* const* d_in, const int* in_sizes, int n_in,
                              void* d_out, int out_size, void* d_ws, size_t ws_size,
                              hipStream_t stream)
{
  const float* img     = (const float*)d_in[0];
  const int*   mask    = (const int*)d_in[1];
  const float* conv1_w = (const float*)d_in[2];
  const float* conv1_b = (const float*)d_in[3];
  const float* ln_p_g  = (const float*)d_in[4];
  const float* ln_p_b  = (const float*)d_in[5];
  const float* proj_w  = (const float*)d_in[6];
  const float* proj_b  = (const float*)d_in[7];
  const float* ln_q_g  = (const float*)d_in[8];
  const float* ln_q_b  = (const float*)d_in[9];
  const float* attn_ln_g = (const float*)d_in[10];
  const float* attn_ln_b = (const float*)d_in[11];
  const float* wqkv    = (const float*)d_in[12];
  const float* wo      = (const float*)d_in[13];
  const float* ff_ln_g = (const float*)d_in[14];
  const float* ff_ln_b = (const float*)d_in[15];
  const float* w1      = (const float*)d_in[16];
  const float* b1      = (const float*)d_in[17];
  const float* w2      = (const float*)d_in[18];
  const float* b2      = (const float*)d_in[19];
  const float* conv2_w = (const float*)d_in[20];
  const float* conv2_b = (const float*)d_in[21];

  if(ws_size < WS_NEED) return;
  char* ws = (char*)d_ws;
  u16* projWt = (u16*)(ws + O_PROJW);
  u16* qkvWt  = (u16*)(ws + O_QKVW);
  u16* woWt   = (u16*)(ws + O_WOW);
  u16* w1Wt   = (u16*)(ws + O_W1W);
  u16* w2Wt   = (u16*)(ws + O_W2W);
  u16* c1Wt   = (u16*)(ws + O_C1W);
  u16* c2Wt   = (u16*)(ws + O_C2W);
  u16* pcl    = (u16*)(ws + O_RA);      // pcl1 / vt / pcl2
  float* tmpf = (float*)(ws + O_RA);
  u16* vtb    = (u16*)(ws + O_RA);      // v^T during layer loop
  float* patches = (float*)(ws + O_RB);
  u16* qkvb   = (u16*)(ws + O_RB);      // q|k (v folded into vt), each 8*8*1024*64
  float* xbuf = (float*)(ws + O_X);
  u16* xnbf   = (u16*)(ws + O_D);
  u16* obf    = (u16*)(ws + O_F);
  u32* minbuf = (u32*)(ws + O_MIN);
  u64* rmbits = (u64*)(ws + O_RMB);

  hipMemsetAsync(ws + O_MIN, 0xFF, 32, stream);       // min keys -> UINT_MAX
  hipMemsetAsync(ws + O_MIN + 32, 0, 32, stream);     // max keys -> 0
  hipMemsetAsync(ws + O_RA, 0, 22302720, stream);     // pcl1 zero borders

  // weight conversion
  k_transpose_bf<<<dim3(16,16,1),256,0,stream>>>(proj_w, projWt, 512, 512);
  k_transpose_bf<<<dim3(16,48,6),256,0,stream>>>(wqkv,   qkvWt,  512, 1536);
  k_transpose_bf<<<dim3(16,16,6),256,0,stream>>>(wo,     woWt,   512, 512);
  k_transpose_bf<<<dim3(16,16,6),256,0,stream>>>(w1,     w1Wt,   512, 512);
  k_transpose_bf<<<dim3(16,16,6),256,0,stream>>>(w2,     w2Wt,   512, 512);
  k_convw<<<1440,256,0,stream>>>(conv1_w, c1Wt, 128, 320);
  k_convw<<<1440,256,0,stream>>>(conv2_w, c2Wt, 320, 128);
  k_rmask<<<192,256,0,stream>>>(mask, rmbits);

  // patch embed
  k_pad_img<<<dim3(512,5),256,0,stream>>>(img, pcl);
  k_gemmC<<<dim3(512,2),256,0,stream>>>(pcl, c1Wt, conv1_b, patches, 2880);
  k_ln_bf<<<2048,256,0,stream>>>(patches, ln_p_g, ln_p_b, xnbf);
  k_gemm64<0><<<dim3(128,8),256,0,stream>>>(xnbf, projWt, proj_b, tmpf, nullptr, 512);
  k_lnq_pos<<<2048,256,0,stream>>>(tmpf, ln_q_g, ln_q_b, xbuf);

  const u16* qb = qkvb;
  const u16* kb = qkvb + 4194304;
  for(int i=0;i<6;i++){
    k_ln_bf<<<2048,256,0,stream>>>(xbuf, attn_ln_g + i*512, attn_ln_b + i*512, xnbf);
    k_gemmW<<<dim3(64,24),256,0,stream>>>(xnbf, qkvWt + (size_t)i*1536*512, qkvb, vtb, 512);
    k_attn_minmax<<<512,256,0,stream>>>(qb, kb, minbuf, i);
    k_attn<<<512,256,0,stream>>>(qb, kb, vtb, rmbits, minbuf, obf, i);
    k_gemm64<2><<<dim3(128,8),256,0,stream>>>(obf, woWt + (size_t)i*512*512, nullptr, xbuf, xbuf, 512);
    k_ln_bf<<<2048,256,0,stream>>>(xbuf, ff_ln_g + i*512, ff_ln_b + i*512, xnbf);
    k_gemm64<3><<<dim3(128,8),256,0,stream>>>(xnbf, w1Wt + (size_t)i*512*512, b1 + i*512, obf, nullptr, 512);
    k_gemm64<4><<<dim3(128,8),256,0,stream>>>(obf, w2Wt + (size_t)i*512*512, b2 + i*512, xbuf, xbuf, 512);
  }

  // final conv
  hipMemsetAsync(ws + O_RA, 0, 8921088, stream);    // pcl2 zero borders
  k_pad_tok<<<16384,256,0,stream>>>(xbuf, pcl);
  k_gemm<6,128><<<dim3(256,5),256,0,stream>>>(pcl, c2Wt, conv2_b, d_out, nullptr, 32768, 320, 1152);
}

// Round 17
// 917.019 us; speedup vs baseline: 1.2341x; 1.0036x over previous
//
#include <hip/hip_runtime.h>
#include <hip/hip_bf16.h>
#include <math.h>

typedef __attribute__((ext_vector_type(8))) short short8;
typedef __attribute__((ext_vector_type(4))) float f32x4;
typedef unsigned short u16;
typedef unsigned int u32;
typedef unsigned long long u64;

#define DEV __device__ __forceinline__

DEV float bf2f(u16 u){ u32 x = ((u32)u)<<16; return __builtin_bit_cast(float, x); }
DEV u16 f2bf(float f){ u32 x = __builtin_bit_cast(u32, f); return (u16)((x + 0x7FFFu + ((x>>16)&1u))>>16); }
DEV f32x4 mfma16(short8 a, short8 b, f32x4 c){ return __builtin_amdgcn_mfma_f32_16x16x32_bf16(a,b,c,0,0,0); }
DEV void gload16(const void* g, void* l){
  __builtin_amdgcn_global_load_lds((const __attribute__((address_space(1))) void*)g,
                                   (__attribute__((address_space(3))) void*)l, 16, 0, 0);
}
DEV u32 fkey(float f){ u32 b = __builtin_bit_cast(u32, f); return (b & 0x80000000u) ? ~b : (b ^ 0x80000000u); }
DEV float funkey(u32 k){ u32 b = (k & 0x80000000u) ? (k ^ 0x80000000u) : ~k; return __builtin_bit_cast(float, b); }
DEV u32 cvtpk(float lo, float hi){ u32 d; asm("v_cvt_pk_bf16_f32 %0, %1, %2" : "=v"(d) : "v"(lo), "v"(hi)); return d; }

// ---------------- workspace layout (bytes) ----------------
static constexpr size_t O_PROJW = 0;                         // 512*512*2
static constexpr size_t O_QKVW  = O_PROJW + 524288;          // 6*1536*512*2
static constexpr size_t O_WOW   = O_QKVW + 9437184;          // 6*512*512*2
static constexpr size_t O_W1W   = O_WOW + 3145728;
static constexpr size_t O_W2W   = O_W1W + 3145728;
static constexpr size_t O_C1W   = O_W2W + 3145728;           // 128*2880*2
static constexpr size_t O_C2W   = O_C1W + 737280;            // 320*1152*2
static constexpr size_t O_RA    = O_C2W + 737280;            // pcl1 22.3MB / tmp f32 / vt 8.4MB / pcl2
static constexpr size_t O_RB    = O_RA + 22302720;           // patches f32 16.8MB then qkv bf16 25.2MB
static constexpr size_t O_X     = O_RB + 25165824;           // x f32 16.8MB
static constexpr size_t O_D     = O_X + 16777216;            // xn bf16 8.4MB
static constexpr size_t O_F     = O_D + 8388608;             // o/g bf16 8.4MB
static constexpr size_t O_RM    = O_F + 8388608;             // 48*1024 u8
static constexpr size_t O_MIN   = O_RM + 49152;              // min keys [0..5], max keys [8..13]
static constexpr size_t O_RMB   = O_MIN + 256;               // 48*16 u64 bit-packed masks
static constexpr size_t WS_NEED = O_RMB + 8192;

// ---------------- weight conversion ----------------
// src [z][K][N] f32 -> dst [z][N][K] bf16
__global__ __launch_bounds__(256) void k_transpose_bf(const float* __restrict__ src, u16* __restrict__ dst, int K, int N){
  __shared__ float tile[32][33];
  const int k0 = blockIdx.x*32, n0 = blockIdx.y*32;
  src += (size_t)blockIdx.z*K*N; dst += (size_t)blockIdx.z*K*N;
  const int c = threadIdx.x & 31, r4 = threadIdx.x >> 5;
  for(int r=r4; r<32; r+=8) tile[r][c] = src[(size_t)(k0+r)*N + n0+c];
  __syncthreads();
  for(int r=r4; r<32; r+=8) dst[(size_t)(n0+r)*K + k0+c] = f2bf(tile[c][r]);
}

// conv weights [OC][IC][3][3] f32 -> Wt [OC][tap*IC+ic] bf16
__global__ __launch_bounds__(256) void k_convw(const float* __restrict__ src, u16* __restrict__ dst, int OC, int IC){
  int idx = blockIdx.x*256 + threadIdx.x;
  int total = OC*IC*9;
  if(idx >= total) return;
  int oc = idx/(IC*9); int rem = idx - oc*IC*9; int tap = rem/IC; int ic = rem - tap*IC;
  dst[idx] = f2bf(src[(size_t)(oc*IC+ic)*9 + tap]);
}

// img [8][320][64][64] f32 -> pcl1 [8][66][66][320] bf16 (interior; borders pre-zeroed)
__global__ __launch_bounds__(256) void k_pad_img(const float* __restrict__ img, u16* __restrict__ pcl){
  const int by = blockIdx.x; const int b = by>>6, y = by&63; const int c0 = blockIdx.y*64;
  __shared__ float t[64][65];
  const int tx = threadIdx.x & 63, tz = threadIdx.x >> 6;
  for(int ci=tz; ci<64; ci+=4) t[ci][tx] = img[(((size_t)b*320 + c0+ci)*64 + y)*64 + tx];
  __syncthreads();
  for(int x=tz; x<64; x+=4) pcl[(((size_t)b*66 + y+1)*66 + (x+1))*320 + c0 + tx] = f2bf(t[tx][x]);
}

// x tokens f32 -> pcl2 [8][66][66][128] bf16 (interior)
__global__ __launch_bounds__(256) void k_pad_tok(const float* __restrict__ x, u16* __restrict__ pcl){
  int idx = blockIdx.x*256 + threadIdx.x;           // 8*64*64*128
  const int c = idx & 127; int r = idx >> 7; const int xx = r & 63; r >>= 6; const int yy = r & 63; const int b = r >> 6;
  const int n = (yy>>1)*32 + (xx>>1); const int f = (yy&1)*256 + (xx&1)*128 + c;
  pcl[(((size_t)b*66 + yy+1)*66 + xx+1)*128 + c] = f2bf(x[((size_t)b*1024 + n)*512 + f]);
}

// mask [48][64][64] int -> rmbits [48][16] u64 (2x2 any)
__global__ __launch_bounds__(256) void k_rmask(const int* __restrict__ mask, u64* __restrict__ rmbits){
  int idx = blockIdx.x*256 + threadIdx.x;
  const int m = idx >> 10, n = idx & 1023; const int h = n>>5, w = n&31;
  const int* mp = mask + ((size_t)m*64 + h*2)*64 + w*2;
  const int v = (mp[0]==1) | (mp[1]==1) | (mp[64]==1) | (mp[65]==1);
  const u64 bm = __ballot(v);
  if((threadIdx.x & 63) == 0) rmbits[idx>>6] = bm;
}

// ---------------- layernorm (wave per token) ----------------
__global__ __launch_bounds__(256) void k_ln_bf(const float* __restrict__ in, const float* __restrict__ gw,
                                               const float* __restrict__ bw, u16* __restrict__ out){
  const int tok = blockIdx.x*4 + (threadIdx.x>>6);
  const int lane = threadIdx.x & 63;
  const float* rp = in + (size_t)tok*512 + lane*8;
  const float4 a = *(const float4*)rp;
  const float4 b = *(const float4*)(rp+4);
  float s  = a.x+a.y+a.z+a.w + b.x+b.y+b.z+b.w;
  float sq = a.x*a.x+a.y*a.y+a.z*a.z+a.w*a.w + b.x*b.x+b.y*b.y+b.z*b.z+b.w*b.w;
  #pragma unroll
  for(int off=1; off<64; off<<=1){ s += __shfl_xor(s,off); sq += __shfl_xor(sq,off); }
  const float mu = s*(1.f/512.f);
  const float rs = rsqrtf(fmaxf(sq*(1.f/512.f) - mu*mu, 0.f) + 1e-5f);
  const float4 g0 = *(const float4*)(gw + lane*8);
  const float4 g1 = *(const float4*)(gw + lane*8 + 4);
  const float4 b0 = *(const float4*)(bw + lane*8);
  const float4 b1 = *(const float4*)(bw + lane*8 + 4);
  short8 o8;
  o8[0]=f2bf((a.x-mu)*rs*g0.x+b0.x); o8[1]=f2bf((a.y-mu)*rs*g0.y+b0.y);
  o8[2]=f2bf((a.z-mu)*rs*g0.z+b0.z); o8[3]=f2bf((a.w-mu)*rs*g0.w+b0.w);
  o8[4]=f2bf((b.x-mu)*rs*g1.x+b1.x); o8[5]=f2bf((b.y-mu)*rs*g1.y+b1.y);
  o8[6]=f2bf((b.z-mu)*rs*g1.z+b1.z); o8[7]=f2bf((b.w-mu)*rs*g1.w+b1.w);
  *(short8*)(out + (size_t)tok*512 + lane*8) = o8;
}

// LN + sincos 2d posemb -> f32 x (wave per token)
__global__ __launch_bounds__(256) void k_lnq_pos(const float* __restrict__ in, const float* __restrict__ gw,
                                                 const float* __restrict__ bw, float* __restrict__ out){
  const int tok = blockIdx.x*4 + (threadIdx.x>>6);
  const int lane = threadIdx.x & 63;
  const float* rp = in + (size_t)tok*512 + lane*8;
  const float4 a = *(const float4*)rp;
  const float4 b = *(const float4*)(rp+4);
  float s  = a.x+a.y+a.z+a.w + b.x+b.y+b.z+b.w;
  float sq = a.x*a.x+a.y*a.y+a.z*a.z+a.w*a.w + b.x*b.x+b.y*b.y+b.z*b.z+b.w*b.w;
  #pragma unroll
  for(int off=1; off<64; off<<=1){ s += __shfl_xor(s,off); sq += __shfl_xor(sq,off); }
  const float mu = s*(1.f/512.f);
  const float rs = rsqrtf(fmaxf(sq*(1.f/512.f) - mu*mu, 0.f) + 1e-5f);
  const int n = tok & 1023; const int yy = n>>5, xx = n&31;
  const int f0 = lane*8; const int sec = f0>>7;
  const float coord = (sec<2) ? (float)xx : (float)yy;
  const float vv[8] = {a.x,a.y,a.z,a.w,b.x,b.y,b.z,b.w};
  float ov[8];
  #pragma unroll
  for(int j=0;j<8;j++){
    const int f = f0+j; const int qq = f & 127;
    const float om = __expf(-(float)qq * (9.2103403719761836f/127.f));
    const float arg = coord * om;
    const float pe = (sec&1) ? __cosf(arg) : __sinf(arg);
    ov[j] = (vv[j]-mu)*rs*gw[f] + bw[f] + pe;
  }
  float* op = out + (size_t)tok*512 + f0;
  *(float4*)op = (float4){ov[0],ov[1],ov[2],ov[3]};
  *(float4*)(op+4) = (float4){ov[4],ov[5],ov[6],ov[7]};
}

// ---------------- GEMM 64x64 tile (4 blocks/CU) for N=512 layers ----------------
// EPI: 0 proj(f32+bias) 2 resid(f32) 3 gelu(bf16+bias) 4 resid+bias
template<int EPI>
__global__ __launch_bounds__(256, 4)
void k_gemm64(const u16* __restrict__ A, const u16* __restrict__ Wt,
              const float* __restrict__ bias, void* __restrict__ outp,
              const float* __restrict__ resid, int Kd)
{
  __shared__ u16 Ald[2][4096];
  __shared__ u16 Bld[2][4096];
  const int tid = threadIdx.x, lane = tid & 63, wv = tid >> 6;
  const int lr = lane & 15, g = lane >> 4;
  const int m0 = blockIdx.x * 64, n0 = blockIdx.y * 64;
  const int wm = (wv >> 1) * 32, wn = (wv & 1) * 32;
  const int srow = tid >> 3;
  const int sc  = (tid & 7) ^ (srow & 7);
  const u16* arow0p = A + (size_t)(m0+srow)*Kd + sc*8;
  const u16* arow1p = A + (size_t)(m0+srow+32)*Kd + sc*8;
  const u16* brow0p = Wt + (size_t)(n0+srow)*Kd + sc*8;
  const u16* brow1p = Wt + (size_t)(n0+srow+32)*Kd + sc*8;

  f32x4 acc[2][2];
  #pragma unroll
  for(int i=0;i<2;i++)
    #pragma unroll
    for(int j=0;j<2;j++) acc[i][j] = (f32x4){0.f,0.f,0.f,0.f};

  const int nIter = Kd >> 6;
  int cur = 0;
  auto stage = [&](int kt, int buf){
    const int k0 = kt << 6;
    gload16(arow0p + k0, &Ald[buf][tid*8]);
    gload16(arow1p + k0, &Ald[buf][2048 + tid*8]);
    gload16(brow0p + k0, &Bld[buf][tid*8]);
    gload16(brow1p + k0, &Bld[buf][2048 + tid*8]);
  };

  stage(0, 0);
  for(int kt=0; kt<nIter; ++kt){
    __syncthreads();
    if(kt+1 < nIter) stage(kt+1, cur^1);
    short8 af[2][2], bg[2][2];
    #pragma unroll
    for(int mi=0;mi<2;mi++)
      #pragma unroll
      for(int kk=0;kk<2;kk++){
        const int R = wm + mi*16 + lr;
        const int Rn = wn + mi*16 + lr;
        const int c = kk*4 + g;
        af[mi][kk] = *(const short8*)&Ald[cur][R*64 + ((c ^ (R&7))<<3)];
        bg[mi][kk] = *(const short8*)&Bld[cur][Rn*64 + ((c ^ (Rn&7))<<3)];
      }
    #pragma unroll
    for(int mi=0;mi<2;mi++)
      #pragma unroll
      for(int nj=0;nj<2;nj++)
        #pragma unroll
        for(int kk=0;kk<2;kk++)
          acc[mi][nj] = mfma16(af[mi][kk], bg[nj][kk], acc[mi][nj]);
    cur ^= 1;
  }

  #pragma unroll
  for(int mi=0;mi<2;mi++){
    #pragma unroll
    for(int nj=0;nj<2;nj++){
      #pragma unroll
      for(int r=0;r<4;r++){
        const int mrow = m0 + wm + mi*16 + g*4 + r;
        const int ncol = n0 + wn + nj*16 + lr;
        float val = acc[mi][nj][r];
        if constexpr (EPI==0 || EPI==3 || EPI==4)
          val += bias[ncol];
        if constexpr (EPI==0){
          ((float*)outp)[(size_t)mrow*512 + ncol] = val;
        } else if constexpr (EPI==2 || EPI==4){
          const size_t idx = (size_t)mrow*512 + ncol;
          ((float*)outp)[idx] = resid[idx] + val;
        } else if constexpr (EPI==3){
          const float gl = 0.5f * val * (1.f + erff(val * 0.70710678118654752f));
          ((u16*)outp)[(size_t)mrow*512 + ncol] = f2bf(gl);
        }
      }
    }
  }
}

// ---------------- conv1 GEMM: 64x64 tile, 4 blocks/CU, tap addressing, patches epilogue ----------------
__global__ __launch_bounds__(256, 4)
void k_gemmC(const u16* __restrict__ A, const u16* __restrict__ Wt,
             const float* __restrict__ bias, float* __restrict__ outp, int Kd)
{
  __shared__ u16 Ald[2][4096];
  __shared__ u16 Bld[2][4096];
  const int tid = threadIdx.x, lane = tid & 63, wv = tid >> 6;
  const int lr = lane & 15, g = lane >> 4;
  const int m0 = blockIdx.x * 64, n0 = blockIdx.y * 64;
  const int wm = (wv >> 1) * 32, wn = (wv & 1) * 32;
  const int srow = tid >> 3;
  const int sc  = (tid & 7) ^ (srow & 7);
  const int b0 = m0 >> 12, y0 = (m0 >> 6) & 63;
  const u16* brow0p = Wt + (size_t)(n0+srow)*Kd + sc*8;
  const u16* brow1p = Wt + (size_t)(n0+srow+32)*Kd + sc*8;

  f32x4 acc[2][2];
  #pragma unroll
  for(int i=0;i<2;i++)
    #pragma unroll
    for(int j=0;j<2;j++) acc[i][j] = (f32x4){0.f,0.f,0.f,0.f};

  const int nIter = Kd >> 6;
  int cur = 0;
  auto stage = [&](int kt, int buf){
    const int k0 = kt << 6;
    const int tap = k0 / 320;
    const int ic0 = k0 - tap*320;
    const int ky = tap/3, kx = tap - 3*(tap/3);
    const size_t rb0 = ((size_t)((b0*66 + y0+ky)*66 + kx))*320 + ic0 + sc*8;
    gload16(A + rb0 + (size_t)(srow)*320,    &Ald[buf][tid*8]);
    gload16(A + rb0 + (size_t)(srow+32)*320, &Ald[buf][2048 + tid*8]);
    gload16(brow0p + k0, &Bld[buf][tid*8]);
    gload16(brow1p + k0, &Bld[buf][2048 + tid*8]);
  };

  stage(0, 0);
  for(int kt=0; kt<nIter; ++kt){
    __syncthreads();
    if(kt+1 < nIter) stage(kt+1, cur^1);
    short8 af[2][2], bg[2][2];
    #pragma unroll
    for(int mi=0;mi<2;mi++)
      #pragma unroll
      for(int kk=0;kk<2;kk++){
        const int R = wm + mi*16 + lr;
        const int Rn = wn + mi*16 + lr;
        const int c = kk*4 + g;
        af[mi][kk] = *(const short8*)&Ald[cur][R*64 + ((c ^ (R&7))<<3)];
        bg[mi][kk] = *(const short8*)&Bld[cur][Rn*64 + ((c ^ (Rn&7))<<3)];
      }
    #pragma unroll
    for(int mi=0;mi<2;mi++)
      #pragma unroll
      for(int nj=0;nj<2;nj++)
        #pragma unroll
        for(int kk=0;kk<2;kk++)
          acc[mi][nj] = mfma16(af[mi][kk], bg[nj][kk], acc[mi][nj]);
    cur ^= 1;
  }

  #pragma unroll
  for(int mi=0;mi<2;mi++){
    #pragma unroll
    for(int nj=0;nj<2;nj++){
      #pragma unroll
      for(int r=0;r<4;r++){
        const int mrow = m0 + wm + mi*16 + g*4 + r;
        const int ncol = n0 + wn + nj*16 + lr;
        const float val = acc[mi][nj][r] + bias[ncol];
        const int b = mrow>>12; const int rr = mrow&4095; const int y = rr>>6; const int xx = rr&63;
        const size_t pidx = ((size_t)(b*1024 + (y>>1)*32 + (xx>>1)))*512 + (y&1)*256 + (xx&1)*128 + ncol;
        outp[pidx] = val;
      }
    }
  }
}

// ---------------- wide GEMM (128x64 tile) for conv2 ----------------
// EPI: 6 conv2->out
template<int EPI, int CONVC>
__global__ __launch_bounds__(256, 3)
void k_gemm(const u16* __restrict__ A, const u16* __restrict__ Wt,
            const float* __restrict__ bias, void* __restrict__ outp,
            const float* __restrict__ resid, int M, int N, int Kd)
{
  __shared__ u16 Ald[2][8192];                        // [128][64] (4 chunks of 32 rows)
  __shared__ u16 Bld[2][4096];                        // [64][64]
  const int tid = threadIdx.x, lane = tid & 63, wv = tid >> 6;
  const int lr = lane & 15, g = lane >> 4;
  const int m0 = blockIdx.x * 128, n0 = blockIdx.y * 64;
  const int wm = wv * 32;
  const int srow = tid >> 3;
  const int sc  = (tid & 7) ^ (srow & 7);
  int b0=0, y0=0;
  if constexpr (CONVC != 0){ b0 = m0>>12; y0 = (m0>>6)&63; }
  const u16* ar[4];
  if constexpr (CONVC == 0){
    #pragma unroll
    for(int j=0;j<4;j++) ar[j] = A + (size_t)(m0+srow+32*j)*Kd + sc*8;
  }
  const u16* br0 = Wt + (size_t)(n0+srow)*Kd + sc*8;
  const u16* br1 = Wt + (size_t)(n0+srow+32)*Kd + sc*8;

  f32x4 acc[2][4];
  #pragma unroll
  for(int i=0;i<2;i++)
    #pragma unroll
    for(int j=0;j<4;j++) acc[i][j] = (f32x4){0.f,0.f,0.f,0.f};

  const int nIter = Kd >> 6;
  int cur = 0;

  auto stage = [&](int kt, int buf){
    const int k0 = kt << 6;
    if constexpr (CONVC != 0){
      const int tap = k0 / CONVC;
      const int ic0 = k0 - tap*CONVC;
      const int ky = tap/3, kx = tap - 3*(tap/3);
      #pragma unroll
      for(int j=0;j<4;j++){
        const int xr = srow + 32*(j&1);
        const int yr = y0 + (j>>1) + ky;
        const u16* ga = A + ((size_t)((b0*66 + yr)*66 + xr + kx))*CONVC + ic0 + sc*8;
        gload16(ga, &Ald[buf][j*2048 + tid*8]);
      }
    } else {
      #pragma unroll
      for(int j=0;j<4;j++) gload16(ar[j] + k0, &Ald[buf][j*2048 + tid*8]);
    }
    gload16(br0 + k0, &Bld[buf][tid*8]);
    gload16(br1 + k0, &Bld[buf][2048 + tid*8]);
  };

  stage(0, 0);
  for(int kt=0; kt<nIter; ++kt){
    __syncthreads();
    if(kt+1 < nIter) stage(kt+1, cur^1);
    short8 af[2][2], bg[4][2];
    #pragma unroll
    for(int mi=0;mi<2;mi++)
      #pragma unroll
      for(int kk=0;kk<2;kk++){
        const int R = wm + mi*16 + lr;
        const int c = kk*4 + g;
        af[mi][kk] = *(const short8*)&Ald[cur][R*64 + ((c ^ (R&7))<<3)];
      }
    #pragma unroll
    for(int nj=0;nj<4;nj++)
      #pragma unroll
      for(int kk=0;kk<2;kk++){
        const int Rn = nj*16 + lr;
        const int c = kk*4 + g;
        bg[nj][kk] = *(const short8*)&Bld[cur][Rn*64 + ((c ^ (Rn&7))<<3)];
      }
    #pragma unroll
    for(int mi=0;mi<2;mi++)
      #pragma unroll
      for(int nj=0;nj<4;nj++)
        #pragma unroll
        for(int kk=0;kk<2;kk++)
          acc[mi][nj] = mfma16(af[mi][kk], bg[nj][kk], acc[mi][nj]);
    cur ^= 1;
  }

  #pragma unroll
  for(int mi=0;mi<2;mi++){
    #pragma unroll
    for(int nj=0;nj<4;nj++){
      #pragma unroll
      for(int r=0;r<4;r++){
        const int mrow = m0 + wm + mi*16 + g*4 + r;
        const int ncol = n0 + nj*16 + lr;
        float val = acc[mi][nj][r] + bias[ncol];
        if constexpr (EPI==5){
          const int b = mrow>>12; const int rr = mrow&4095; const int y = rr>>6; const int xx = rr&63;
          const size_t pidx = ((size_t)(b*1024 + (y>>1)*32 + (xx>>1)))*512 + (y&1)*256 + (xx&1)*128 + ncol;
          ((float*)outp)[pidx] = val;
        } else if constexpr (EPI==6){
          const int b = mrow>>12; const int rr = mrow&4095; const int y = rr>>6; const int xx = rr&63;
          ((float*)outp)[(((size_t)(b*320 + ncol))*64 + y)*64 + xx] = val;
        }
      }
    }
  }
}

// ---------------- wide GEMM for qkv: 128x64 tile, BK=64; q/k scatter; v -> vt directly ----------------
__global__ __launch_bounds__(256, 3)
void k_gemmW(const u16* __restrict__ A, const u16* __restrict__ Wt,
             void* __restrict__ outp, u16* __restrict__ vt, int Kd)
{
  __shared__ u16 Ald[2][8192];                       // [128][64]; reused as Vt bounce tile
  __shared__ u16 Bld[2][4096];                       // [64][64]
  const int tid = threadIdx.x, lane = tid & 63, wv = tid >> 6;
  const int lr = lane & 15, g = lane >> 4;
  const int m0 = blockIdx.x * 128, n0 = blockIdx.y * 64;
  const int wm = wv * 32;
  const int srow = tid >> 3;
  const int sc  = (tid & 7) ^ (srow & 7);
  const u16* ar[4];
  #pragma unroll
  for(int j=0;j<4;j++) ar[j] = A + (size_t)(m0+srow+32*j)*Kd + sc*8;
  const u16* br0 = Wt + (size_t)(n0+srow)*Kd + sc*8;
  const u16* br1 = Wt + (size_t)(n0+srow+32)*Kd + sc*8;

  f32x4 acc[2][4];
  #pragma unroll
  for(int i=0;i<2;i++)
    #pragma unroll
    for(int j=0;j<4;j++) acc[i][j] = (f32x4){0.f,0.f,0.f,0.f};

  const int nIter = Kd >> 6;
  int cur = 0;
  auto stage = [&](int kt, int buf){
    const int k0 = kt << 6;
    #pragma unroll
    for(int j=0;j<4;j++) gload16(ar[j] + k0, &Ald[buf][j*2048 + tid*8]);
    gload16(br0 + k0, &Bld[buf][tid*8]);
    gload16(br1 + k0, &Bld[buf][2048 + tid*8]);
  };

  stage(0, 0);
  for(int kt=0; kt<nIter; ++kt){
    __syncthreads();
    if(kt+1 < nIter) stage(kt+1, cur^1);
    short8 af[2][2], bg[4][2];
    #pragma unroll
    for(int mi=0;mi<2;mi++)
      #pragma unroll
      for(int kk=0;kk<2;kk++){
        const int R = wm + mi*16 + lr;
        const int c = kk*4 + g;
        af[mi][kk] = *(const short8*)&Ald[cur][R*64 + ((c ^ (R&7))<<3)];
      }
    #pragma unroll
    for(int nj=0;nj<4;nj++)
      #pragma unroll
      for(int kk=0;kk<2;kk++){
        const int Rn = nj*16 + lr;
        const int c = kk*4 + g;
        bg[nj][kk] = *(const short8*)&Bld[cur][Rn*64 + ((c ^ (Rn&7))<<3)];
      }
    #pragma unroll
    for(int mi=0;mi<2;mi++)
      #pragma unroll
      for(int nj=0;nj<4;nj++)
        #pragma unroll
        for(int kk=0;kk<2;kk++)
          acc[mi][nj] = mfma16(af[mi][kk], bg[nj][kk], acc[mi][nj]);
    cur ^= 1;
  }

  if(n0 < 1024){
    // q/k scatter epilogue
    #pragma unroll
    for(int mi=0;mi<2;mi++){
      #pragma unroll
      for(int nj=0;nj<4;nj++){
        #pragma unroll
        for(int r=0;r<4;r++){
          const int mrow = m0 + wm + mi*16 + g*4 + r;
          const int ncol = n0 + nj*16 + lr;
          const int sec = ncol >> 9, rem = ncol & 511;
          const int head = rem >> 6, d = rem & 63;
          const int b = mrow >> 10, t = mrow & 1023;
          ((u16*)outp)[(size_t)sec*4194304 + ((size_t)((b*8+head)*1024 + t))*64 + d] = f2bf(acc[mi][nj][r]);
        }
      }
    }
  } else {
    // v block: write vt[bh][d][t] directly via LDS bounce (raw v never materialized)
    const int head = (n0 - 1024) >> 6;
    const int b = m0 >> 10;
    const int t0 = m0 & 1023;
    const int bh = b*8 + head;
    __syncthreads();                                  // all waves done reading Ald
    u16* Vt = (u16*)Ald;                              // [64 d][136] (stride 272B, 16B-aligned)
    #pragma unroll
    for(int mi=0;mi<2;mi++)
      #pragma unroll
      for(int nj=0;nj<4;nj++)
        #pragma unroll
        for(int r=0;r<4;r++){
          const int lt = wm + mi*16 + g*4 + r;
          const int d  = nj*16 + lr;
          Vt[d*136 + lt] = f2bf(acc[mi][nj][r]);
        }
    __syncthreads();
    const int d = tid >> 2, qd = tid & 3;             // 64 d-rows x 4 chunks of 32 t
    u16* dst = vt + (size_t)bh*65536 + (size_t)d*1024 + t0 + qd*32;
    const u16* srcl = &Vt[d*136 + qd*32];
    #pragma unroll
    for(int e4=0;e4<4;e4++)
      *(short8*)(dst + e4*8) = *(const short8*)(srcl + e4*8);
  }
}

// ---------------- attention pass A: global min AND max, 128-q tile, 128-j staged (8 barriers) ----------------
__global__ __launch_bounds__(256, 4)
void k_attn_minmax(const u16* __restrict__ q, const u16* __restrict__ k, u32* __restrict__ keys, int layer){
  const int id = blockIdx.x;                   // 512 blocks
  const int qt = (id>>3)&7;
  const int bh = ((id&7)<<3) | (id>>6);
  __shared__ u16 Kld[2][8192];                 // [2 buf][2 sub][64 rows][64]
  __shared__ float redn[4], redx[4];
  const int tid = threadIdx.x, lane = tid & 63, wv = tid >> 6;
  const int lr = lane & 15, g = lane >> 4;
  const u16* qp0 = q + ((size_t)bh*1024 + qt*128 + wv*16 + lr)*64;
  const u16* qp1 = qp0 + 64*64;
  const short8 qa00 = *(const short8*)(qp0 + g*8);
  const short8 qa01 = *(const short8*)(qp0 + 32 + g*8);
  const short8 qa10 = *(const short8*)(qp1 + g*8);
  const short8 qa11 = *(const short8*)(qp1 + 32 + g*8);
  const u16* kbase = k + (size_t)bh*65536;
  const int srow = tid>>3, scs = lane&7;
  const int scg = scs ^ (srow&7);
  float mn = 3.0e38f, mx = -3.0e38f;
  auto stageK = [&](int jt, int buf){
    const int j0 = jt << 7;
    #pragma unroll
    for(int j=0;j<4;j++)
      gload16(kbase + (size_t)(j0 + srow + 32*j)*64 + scg*8, &Kld[buf][j*2048 + tid*8]);
  };
  stageK(0, 0);
  int cur = 0;
  for(int jt=0; jt<8; ++jt){
    __syncthreads();
    if(jt < 7) stageK(jt+1, cur^1);
    #pragma unroll
    for(int s=0;s<2;s++){
      const u16* Kp = &Kld[cur][s*4096];
      #pragma unroll
      for(int c=0;c<4;c++){
        const int rr = c*16 + lr;
        const short8 kb0 = *(const short8*)&Kp[rr*64 + ((g ^ (rr&7))<<3)];
        const short8 kb1 = *(const short8*)&Kp[rr*64 + (((g+4) ^ (rr&7))<<3)];
        f32x4 sa = (f32x4){0.f,0.f,0.f,0.f};
        f32x4 sb = (f32x4){0.f,0.f,0.f,0.f};
        __builtin_amdgcn_s_setprio(1);
        sa = mfma16(qa00, kb0, sa);
        sa = mfma16(qa01, kb1, sa);
        sb = mfma16(qa10, kb0, sb);
        sb = mfma16(qa11, kb1, sb);
        __builtin_amdgcn_s_setprio(0);
        mn = fminf(mn, fminf(fminf(sa[0],sa[1]), fminf(sa[2],sa[3])));
        mx = fmaxf(mx, fmaxf(fmaxf(sa[0],sa[1]), fmaxf(sa[2],sa[3])));
        mn = fminf(mn, fminf(fminf(sb[0],sb[1]), fminf(sb[2],sb[3])));
        mx = fmaxf(mx, fmaxf(fmaxf(sb[0],sb[1]), fmaxf(sb[2],sb[3])));
      }
    }
    cur ^= 1;
  }
  mn *= 0.125f; mx *= 0.125f;
  #pragma unroll
  for(int off=32; off; off>>=1){
    mn = fminf(mn, __shfl_down(mn, off));
    mx = fmaxf(mx, __shfl_down(mx, off));
  }
  if(lane==0){ redn[wv] = mn; redx[wv] = mx; }
  __syncthreads();
  if(tid==0){
    atomicMin(keys + layer,     fkey(fminf(fminf(redn[0],redn[1]), fminf(redn[2],redn[3]))));
    atomicMax(keys + 8 + layer, fkey(fmaxf(fmaxf(redx[0],redx[1]), fmaxf(redx[2],redx[3]))));
  }
}

// ---------------- attention pass B: 128-q tile, 128-j staged, MFMA row-sum, packed P ----------------
__global__ __launch_bounds__(256, 2)
void k_attn(const u16* __restrict__ q, const u16* __restrict__ k, const u16* __restrict__ vt,
            const u64* __restrict__ rmbits, const u32* __restrict__ keys,
            u16* __restrict__ o, int layer){
  const int id = blockIdx.x;                   // 512 blocks
  const int qt = (id>>3)&7;
  const int bh = ((id&7)<<3) | (id>>6);
  const int b = bh>>3, h = bh&7;
  __shared__ u16 Kld[2][8192];                 // [buf][sub 2][64 rows][64]
  __shared__ u16 Vtld[2][8192];
  __shared__ u32 Pld[4][1024];                 // per-wave [32 qrow][32 u32]
  const int tid = threadIdx.x, lane = tid & 63, wv = tid >> 6;
  const int lr = lane & 15, g = lane >> 4;
  const int L7 = lr & 7;
  const u16* qp0 = q + ((size_t)bh*1024 + qt*128 + wv*16 + lr)*64;
  const u16* qp1 = qp0 + 64*64;
  const short8 qa00 = *(const short8*)(qp0 + g*8);
  const short8 qa01 = *(const short8*)(qp0 + 32 + g*8);
  const short8 qa10 = *(const short8*)(qp1 + g*8);
  const short8 qa11 = *(const short8*)(qp1 + 32 + g*8);
  const float L2E = 1.44269504088896f;
  const float SC = 0.125f * L2E;
  float mnv = funkey(keys[layer]);
  float mxv = funkey(keys[8+layer]);
  if(!(mnv >= -1e38f && mnv <= 1e38f)) mnv = 0.f;
  if(!(mxv >= -1e38f && mxv <= 1e38f)) mxv = 0.f;
  const float ME   = mxv * L2E;
  const float minM = fmaxf(mnv*L2E - ME, -120.f);
  const float emin = exp2f(minM);              // precomputed masked-fill value
  const u32* cbp = (const u32*)(rmbits + (size_t)(layer*8 + b)*16);
  const int rowi0 = qt*128 + wv*16 + lr;
  const int rowi1 = rowi0 + 64;
  const u32 rf0 = ((cbp[rowi0>>5] >> (rowi0&31)) & 1u) ? 0xFu : 0u;
  const u32 rf1 = ((cbp[rowi1>>5] >> (rowi1&31)) & 1u) ? 0xFu : 0u;
  u32* Pw = &Pld[wv][0];
  u32 wslot[4][2];
  #pragma unroll
  for(int c=0;c<4;c++){
    const int blk = c*2 + (g>>1);
    wslot[c][0] = lr*32 + (((blk ^ L7))<<2) + (g&1)*2;
    wslot[c][1] = wslot[c][0] + 1;
  }
  const u32 ra0 = lr*32 + ((g ^ L7)<<2);
  const u32 ra1 = lr*32 + (((4+g) ^ L7)<<2);

  short8 vones;
  #pragma unroll
  for(int i=0;i<8;i++) vones[i] = (short)0x3F80;     // bf16 1.0
  f32x4 ls0 = (f32x4){0.f,0.f,0.f,0.f};
  f32x4 ls1 = (f32x4){0.f,0.f,0.f,0.f};
  f32x4 acc0[4], acc1[4];
  #pragma unroll
  for(int d=0;d<4;d++){ acc0[d] = (f32x4){0.f,0.f,0.f,0.f}; acc1[d] = (f32x4){0.f,0.f,0.f,0.f}; }
  const u16* kbase = k + (size_t)bh*65536;
  const u16* vtbase = vt + (size_t)bh*65536;
  const int srow = tid>>3, scs = lane&7;
  const int scg = scs ^ (srow&7);
  auto stageKV = [&](int jt, int buf){
    const int j0 = jt << 7;
    #pragma unroll
    for(int j=0;j<4;j++)
      gload16(kbase + (size_t)(j0 + srow + 32*j)*64 + scg*8, &Kld[buf][j*2048 + tid*8]);
    #pragma unroll
    for(int s=0;s<2;s++)
      #pragma unroll
      for(int jj=0;jj<2;jj++)
        gload16(vtbase + (size_t)(srow + 32*jj)*1024 + j0 + s*64 + scg*8,
                &Vtld[buf][s*4096 + jj*2048 + tid*8]);
  };
  stageKV(0, 0);
  int cur = 0;
  for(int jt=0; jt<8; ++jt){
    __syncthreads();
    if(jt < 7) stageKV(jt+1, cur^1);
    #pragma unroll
    for(int s=0;s<2;s++){
      const int jb = jt*2 + s;
      const u32 cb_lo = cbp[jb*2], cb_hi = cbp[jb*2+1];
      const u16* Kp = &Kld[cur][s*4096];
      const u16* Vp = &Vtld[cur][s*4096];
      #pragma unroll
      for(int c=0;c<4;c++){
        const int rr = c*16 + lr;
        const short8 kb0 = *(const short8*)&Kp[rr*64 + ((g ^ (rr&7))<<3)];
        const short8 kb1 = *(const short8*)&Kp[rr*64 + (((g+4) ^ (rr&7))<<3)];
        f32x4 sa = (f32x4){0.f,0.f,0.f,0.f};
        f32x4 sb = (f32x4){0.f,0.f,0.f,0.f};
        __builtin_amdgcn_s_setprio(1);
        sa = mfma16(kb0, qa00, sa);
        sa = mfma16(kb1, qa01, sa);
        sb = mfma16(kb0, qa10, sb);
        sb = mfma16(kb1, qa11, sb);
        __builtin_amdgcn_s_setprio(0);
        const u32 base = (((c<2) ? cb_lo : cb_hi) >> ((c&1)*16 + g*4));
        const u32 cw0 = base | rf0;
        const u32 cw1 = base | rf1;
        float e0[4], e1[4];
        #pragma unroll
        for(int r=0;r<4;r++){
          // sv <= 0 always (ME is the global max); exp2 of finite negative is safe.
          const float x0 = exp2f(fmaf(sa[r], SC, -ME));
          const float x1 = exp2f(fmaf(sb[r], SC, -ME));
          e0[r] = ((cw0 >> r) & 1u) ? x0 : emin;
          e1[r] = ((cw1 >> r) & 1u) ? x1 : emin;
        }
        Pw[wslot[c][0]]       = cvtpk(e0[0], e0[1]);
        Pw[wslot[c][1]]       = cvtpk(e0[2], e0[3]);
        Pw[512 + wslot[c][0]] = cvtpk(e1[0], e1[1]);
        Pw[512 + wslot[c][1]] = cvtpk(e1[2], e1[3]);
      }
      asm volatile("s_waitcnt lgkmcnt(0)" ::: "memory");
      __builtin_amdgcn_sched_barrier(0);
      const short8 pa00 = *(const short8*)&Pw[ra0];
      const short8 pa01 = *(const short8*)&Pw[ra1];
      const short8 pa10 = *(const short8*)&Pw[512 + ra0];
      const short8 pa11 = *(const short8*)&Pw[512 + ra1];
      // row-sum via MFMA with ones-B (moves lsum off the VALU pipe)
      __builtin_amdgcn_s_setprio(1);
      ls0 = mfma16(pa00, vones, ls0);
      ls0 = mfma16(pa01, vones, ls0);
      ls1 = mfma16(pa10, vones, ls1);
      ls1 = mfma16(pa11, vones, ls1);
      __builtin_amdgcn_s_setprio(0);
      #pragma unroll
      for(int d=0;d<4;d++){
        const int rr = d*16 + lr;
        const short8 vb0 = *(const short8*)&Vp[rr*64 + ((g ^ (rr&7))<<3)];
        const short8 vb1 = *(const short8*)&Vp[rr*64 + (((g+4) ^ (rr&7))<<3)];
        __builtin_amdgcn_s_setprio(1);
        acc0[d] = mfma16(pa00, vb0, acc0[d]);
        acc0[d] = mfma16(pa01, vb1, acc0[d]);
        acc1[d] = mfma16(pa10, vb0, acc1[d]);
        acc1[d] = mfma16(pa11, vb1, acc1[d]);
        __builtin_amdgcn_s_setprio(0);
      }
    }
    cur ^= 1;
  }
  float inv0[4], inv1[4];
  #pragma unroll
  for(int r=0;r<4;r++){
    inv0[r] = 1.f / (ls0[r] + 1e-30f);
    inv1[r] = 1.f / (ls1[r] + 1e-30f);
  }
  #pragma unroll
  for(int d=0;d<4;d++)
    #pragma unroll
    for(int r=0;r<4;r++){
      const int qr0 = qt*128 + wv*16 + g*4 + r;
      o[((size_t)b*1024 + qr0)*512 + h*64 + d*16 + lr]        = f2bf(acc0[d][r] * inv0[r]);
      o[((size_t)b*1024 + qr0 + 64)*512 + h*64 + d*16 + lr]   = f2bf(acc1[d][r] * inv1[r]);
    }
}

// ---------------- host ----------------
extern "C" void kernel_launch(void* const* d_in, const int* in_sizes, int n_in,
                              void* d_out, int out_size, void* d_ws, size_t ws_size,
                              hipStream_t stream)
{
  const float* img     = (const float*)d_in[0];
  const int*   mask    = (const int*)d_in[1];
  const float* conv1_w = (const float*)d_in[2];
  const float* conv1_b = (const float*)d_in[3];
  const float* ln_p_g  = (const float*)d_in[4];
  const float* ln_p_b  = (const float*)d_in[5];
  const float* proj_w  = (const float*)d_in[6];
  const float* proj_b  = (const float*)d_in[7];
  const float* ln_q_g  = (const float*)d_in[8];
  const float* ln_q_b  = (const float*)d_in[9];
  const float* attn_ln_g = (const float*)d_in[10];
  const float* attn_ln_b = (const float*)d_in[11];
  const float* wqkv    = (const float*)d_in[12];
  const float* wo      = (const float*)d_in[13];
  const float* ff_ln_g = (const float*)d_in[14];
  const float* ff_ln_b = (const float*)d_in[15];
  const float* w1      = (const float*)d_in[16];
  const float* b1      = (const float*)d_in[17];
  const float* w2      = (const float*)d_in[18];
  const float* b2      = (const float*)d_in[19];
  const float* conv2_w = (const float*)d_in[20];
  const float* conv2_b = (const float*)d_in[21];

  if(ws_size < WS_NEED) return;
  char* ws = (char*)d_ws;
  u16* projWt = (u16*)(ws + O_PROJW);
  u16* qkvWt  = (u16*)(ws + O_QKVW);
  u16* woWt   = (u16*)(ws + O_WOW);
  u16* w1Wt   = (u16*)(ws + O_W1W);
  u16* w2Wt   = (u16*)(ws + O_W2W);
  u16* c1Wt   = (u16*)(ws + O_C1W);
  u16* c2Wt   = (u16*)(ws + O_C2W);
  u16* pcl    = (u16*)(ws + O_RA);      // pcl1 / vt / pcl2
  float* tmpf = (float*)(ws + O_RA);
  u16* vtb    = (u16*)(ws + O_RA);      // v^T during layer loop
  float* patches = (float*)(ws + O_RB);
  u16* qkvb   = (u16*)(ws + O_RB);      // q|k (v folded into vt), each 8*8*1024*64
  float* xbuf = (float*)(ws + O_X);
  u16* xnbf   = (u16*)(ws + O_D);
  u16* obf    = (u16*)(ws + O_F);
  u32* minbuf = (u32*)(ws + O_MIN);
  u64* rmbits = (u64*)(ws + O_RMB);

  hipMemsetAsync(ws + O_MIN, 0xFF, 32, stream);       // min keys -> UINT_MAX
  hipMemsetAsync(ws + O_MIN + 32, 0, 32, stream);     // max keys -> 0
  hipMemsetAsync(ws + O_RA, 0, 22302720, stream);     // pcl1 zero borders

  // weight conversion
  k_transpose_bf<<<dim3(16,16,1),256,0,stream>>>(proj_w, projWt, 512, 512);
  k_transpose_bf<<<dim3(16,48,6),256,0,stream>>>(wqkv,   qkvWt,  512, 1536);
  k_transpose_bf<<<dim3(16,16,6),256,0,stream>>>(wo,     woWt,   512, 512);
  k_transpose_bf<<<dim3(16,16,6),256,0,stream>>>(w1,     w1Wt,   512, 512);
  k_transpose_bf<<<dim3(16,16,6),256,0,stream>>>(w2,     w2Wt,   512, 512);
  k_convw<<<1440,256,0,stream>>>(conv1_w, c1Wt, 128, 320);
  k_convw<<<1440,256,0,stream>>>(conv2_w, c2Wt, 320, 128);
  k_rmask<<<192,256,0,stream>>>(mask, rmbits);

  // patch embed
  k_pad_img<<<dim3(512,5),256,0,stream>>>(img, pcl);
  k_gemmC<<<dim3(512,2),256,0,stream>>>(pcl, c1Wt, conv1_b, patches, 2880);
  k_ln_bf<<<2048,256,0,stream>>>(patches, ln_p_g, ln_p_b, xnbf);
  k_gemm64<0><<<dim3(128,8),256,0,stream>>>(xnbf, projWt, proj_b, tmpf, nullptr, 512);
  k_lnq_pos<<<2048,256,0,stream>>>(tmpf, ln_q_g, ln_q_b, xbuf);

  const u16* qb = qkvb;
  const u16* kb = qkvb + 4194304;
  for(int i=0;i<6;i++){
    k_ln_bf<<<2048,256,0,stream>>>(xbuf, attn_ln_g + i*512, attn_ln_b + i*512, xnbf);
    k_gemmW<<<dim3(64,24),256,0,stream>>>(xnbf, qkvWt + (size_t)i*1536*512, qkvb, vtb, 512);
    k_attn_minmax<<<512,256,0,stream>>>(qb, kb, minbuf, i);
    k_attn<<<512,256,0,stream>>>(qb, kb, vtb, rmbits, minbuf, obf, i);
    k_gemm64<2><<<dim3(128,8),256,0,stream>>>(obf, woWt + (size_t)i*512*512, nullptr, xbuf, xbuf, 512);
    k_ln_bf<<<2048,256,0,stream>>>(xbuf, ff_ln_g + i*512, ff_ln_b + i*512, xnbf);
    k_gemm64<3><<<dim3(128,8),256,0,stream>>>(xnbf, w1Wt + (size_t)i*512*512, b1 + i*512, obf, nullptr, 512);
    k_gemm64<4><<<dim3(128,8),256,0,stream>>>(obf, w2Wt + (size_t)i*512*512, b2 + i*512, xbuf, xbuf, 512);
  }

  // final conv
  hipMemsetAsync(ws + O_RA, 0, 8921088, stream);    // pcl2 zero borders
  k_pad_tok<<<16384,256,0,stream>>>(xbuf, pcl);
  k_gemm<6,128><<<dim3(256,5),256,0,stream>>>(pcl, c2Wt, conv2_b, d_out, nullptr, 32768, 320, 1152);
}

// Round 19
// 914.848 us; speedup vs baseline: 1.2371x; 1.0024x over previous
//
#include <hip/hip_runtime.h>
#include <hip/hip_bf16.h>
#include <math.h>

typedef __attribute__((ext_vector_type(8))) short short8;
typedef __attribute__((ext_vector_type(4))) float f32x4;
typedef unsigned short u16;
typedef unsigned int u32;
typedef unsigned long long u64;

#define DEV __device__ __forceinline__

DEV float bf2f(u16 u){ u32 x = ((u32)u)<<16; return __builtin_bit_cast(float, x); }
DEV u16 f2bf(float f){ u32 x = __builtin_bit_cast(u32, f); return (u16)((x + 0x7FFFu + ((x>>16)&1u))>>16); }
DEV f32x4 mfma16(short8 a, short8 b, f32x4 c){ return __builtin_amdgcn_mfma_f32_16x16x32_bf16(a,b,c,0,0,0); }
DEV void gload16(const void* g, void* l){
  __builtin_amdgcn_global_load_lds((const __attribute__((address_space(1))) void*)g,
                                   (__attribute__((address_space(3))) void*)l, 16, 0, 0);
}
DEV u32 fkey(float f){ u32 b = __builtin_bit_cast(u32, f); return (b & 0x80000000u) ? ~b : (b ^ 0x80000000u); }
DEV float funkey(u32 k){ u32 b = (k & 0x80000000u) ? (k ^ 0x80000000u) : ~k; return __builtin_bit_cast(float, b); }
DEV u32 cvtpk(float lo, float hi){ u32 d; asm("v_cvt_pk_bf16_f32 %0, %1, %2" : "=v"(d) : "v"(lo), "v"(hi)); return d; }

// ---------------- workspace layout (bytes) ----------------
static constexpr size_t O_PROJW = 0;                         // 512*512*2
static constexpr size_t O_QKVW  = O_PROJW + 524288;          // 6*1536*512*2
static constexpr size_t O_WOW   = O_QKVW + 9437184;          // 6*512*512*2
static constexpr size_t O_W1W   = O_WOW + 3145728;
static constexpr size_t O_W2W   = O_W1W + 3145728;
static constexpr size_t O_C1W   = O_W2W + 3145728;           // 128*2880*2
static constexpr size_t O_C2W   = O_C1W + 737280;            // 320*1152*2
static constexpr size_t O_RA    = O_C2W + 737280;            // pcl1 22.3MB / tmp f32 / vt 8.4MB / pcl2
static constexpr size_t O_RB    = O_RA + 22302720;           // patches f32 16.8MB then qkv bf16 25.2MB
static constexpr size_t O_X     = O_RB + 25165824;           // x f32 16.8MB
static constexpr size_t O_D     = O_X + 16777216;            // xn bf16 8.4MB
static constexpr size_t O_F     = O_D + 8388608;             // o/g bf16 8.4MB
static constexpr size_t O_RM    = O_F + 8388608;             // 48*1024 u8
static constexpr size_t O_MIN   = O_RM + 49152;              // min keys [0..5], max keys [8..13]
static constexpr size_t O_RMB   = O_MIN + 256;               // 48*16 u64 bit-packed masks
static constexpr size_t WS_NEED = O_RMB + 8192;

// ---------------- weight conversion ----------------
// src [z][K][N] f32 -> dst [z][N][K] bf16
__global__ __launch_bounds__(256) void k_transpose_bf(const float* __restrict__ src, u16* __restrict__ dst, int K, int N){
  __shared__ float tile[32][33];
  const int k0 = blockIdx.x*32, n0 = blockIdx.y*32;
  src += (size_t)blockIdx.z*K*N; dst += (size_t)blockIdx.z*K*N;
  const int c = threadIdx.x & 31, r4 = threadIdx.x >> 5;
  for(int r=r4; r<32; r+=8) tile[r][c] = src[(size_t)(k0+r)*N + n0+c];
  __syncthreads();
  for(int r=r4; r<32; r+=8) dst[(size_t)(n0+r)*K + k0+c] = f2bf(tile[c][r]);
}

// conv weights [OC][IC][3][3] f32 -> Wt [OC][tap*IC+ic] bf16
__global__ __launch_bounds__(256) void k_convw(const float* __restrict__ src, u16* __restrict__ dst, int OC, int IC){
  int idx = blockIdx.x*256 + threadIdx.x;
  int total = OC*IC*9;
  if(idx >= total) return;
  int oc = idx/(IC*9); int rem = idx - oc*IC*9; int tap = rem/IC; int ic = rem - tap*IC;
  dst[idx] = f2bf(src[(size_t)(oc*IC+ic)*9 + tap]);
}

// img [8][320][64][64] f32 -> pcl1 [8][66][66][320] bf16 (interior; borders pre-zeroed)
__global__ __launch_bounds__(256) void k_pad_img(const float* __restrict__ img, u16* __restrict__ pcl){
  const int by = blockIdx.x; const int b = by>>6, y = by&63; const int c0 = blockIdx.y*64;
  __shared__ float t[64][65];
  const int tx = threadIdx.x & 63, tz = threadIdx.x >> 6;
  for(int ci=tz; ci<64; ci+=4) t[ci][tx] = img[(((size_t)b*320 + c0+ci)*64 + y)*64 + tx];
  __syncthreads();
  for(int x=tz; x<64; x+=4) pcl[(((size_t)b*66 + y+1)*66 + (x+1))*320 + c0 + tx] = f2bf(t[tx][x]);
}

// x tokens f32 -> pcl2 [8][66][66][128] bf16 (interior)
__global__ __launch_bounds__(256) void k_pad_tok(const float* __restrict__ x, u16* __restrict__ pcl){
  int idx = blockIdx.x*256 + threadIdx.x;           // 8*64*64*128
  const int c = idx & 127; int r = idx >> 7; const int xx = r & 63; r >>= 6; const int yy = r & 63; const int b = r >> 6;
  const int n = (yy>>1)*32 + (xx>>1); const int f = (yy&1)*256 + (xx&1)*128 + c;
  pcl[(((size_t)b*66 + yy+1)*66 + xx+1)*128 + c] = f2bf(x[((size_t)b*1024 + n)*512 + f]);
}

// mask [48][64][64] int -> rmbits [48][16] u64 (2x2 any)
__global__ __launch_bounds__(256) void k_rmask(const int* __restrict__ mask, u64* __restrict__ rmbits){
  int idx = blockIdx.x*256 + threadIdx.x;
  const int m = idx >> 10, n = idx & 1023; const int h = n>>5, w = n&31;
  const int* mp = mask + ((size_t)m*64 + h*2)*64 + w*2;
  const int v = (mp[0]==1) | (mp[1]==1) | (mp[64]==1) | (mp[65]==1);
  const u64 bm = __ballot(v);
  if((threadIdx.x & 63) == 0) rmbits[idx>>6] = bm;
}

// ---------------- layernorm (wave per token) ----------------
__global__ __launch_bounds__(256) void k_ln_bf(const float* __restrict__ in, const float* __restrict__ gw,
                                               const float* __restrict__ bw, u16* __restrict__ out){
  const int tok = blockIdx.x*4 + (threadIdx.x>>6);
  const int lane = threadIdx.x & 63;
  const float* rp = in + (size_t)tok*512 + lane*8;
  const float4 a = *(const float4*)rp;
  const float4 b = *(const float4*)(rp+4);
  float s  = a.x+a.y+a.z+a.w + b.x+b.y+b.z+b.w;
  float sq = a.x*a.x+a.y*a.y+a.z*a.z+a.w*a.w + b.x*b.x+b.y*b.y+b.z*b.z+b.w*b.w;
  #pragma unroll
  for(int off=1; off<64; off<<=1){ s += __shfl_xor(s,off); sq += __shfl_xor(sq,off); }
  const float mu = s*(1.f/512.f);
  const float rs = rsqrtf(fmaxf(sq*(1.f/512.f) - mu*mu, 0.f) + 1e-5f);
  const float4 g0 = *(const float4*)(gw + lane*8);
  const float4 g1 = *(const float4*)(gw + lane*8 + 4);
  const float4 b0 = *(const float4*)(bw + lane*8);
  const float4 b1 = *(const float4*)(bw + lane*8 + 4);
  short8 o8;
  o8[0]=f2bf((a.x-mu)*rs*g0.x+b0.x); o8[1]=f2bf((a.y-mu)*rs*g0.y+b0.y);
  o8[2]=f2bf((a.z-mu)*rs*g0.z+b0.z); o8[3]=f2bf((a.w-mu)*rs*g0.w+b0.w);
  o8[4]=f2bf((b.x-mu)*rs*g1.x+b1.x); o8[5]=f2bf((b.y-mu)*rs*g1.y+b1.y);
  o8[6]=f2bf((b.z-mu)*rs*g1.z+b1.z); o8[7]=f2bf((b.w-mu)*rs*g1.w+b1.w);
  *(short8*)(out + (size_t)tok*512 + lane*8) = o8;
}

// LN + sincos 2d posemb -> f32 x (wave per token)
__global__ __launch_bounds__(256) void k_lnq_pos(const float* __restrict__ in, const float* __restrict__ gw,
                                                 const float* __restrict__ bw, float* __restrict__ out){
  const int tok = blockIdx.x*4 + (threadIdx.x>>6);
  const int lane = threadIdx.x & 63;
  const float* rp = in + (size_t)tok*512 + lane*8;
  const float4 a = *(const float4*)rp;
  const float4 b = *(const float4*)(rp+4);
  float s  = a.x+a.y+a.z+a.w + b.x+b.y+b.z+b.w;
  float sq = a.x*a.x+a.y*a.y+a.z*a.z+a.w*a.w + b.x*b.x+b.y*b.y+b.z*b.z+b.w*b.w;
  #pragma unroll
  for(int off=1; off<64; off<<=1){ s += __shfl_xor(s,off); sq += __shfl_xor(sq,off); }
  const float mu = s*(1.f/512.f);
  const float rs = rsqrtf(fmaxf(sq*(1.f/512.f) - mu*mu, 0.f) + 1e-5f);
  const int n = tok & 1023; const int yy = n>>5, xx = n&31;
  const int f0 = lane*8; const int sec = f0>>7;
  const float coord = (sec<2) ? (float)xx : (float)yy;
  const float vv[8] = {a.x,a.y,a.z,a.w,b.x,b.y,b.z,b.w};
  float ov[8];
  #pragma unroll
  for(int j=0;j<8;j++){
    const int f = f0+j; const int qq = f & 127;
    const float om = __expf(-(float)qq * (9.2103403719761836f/127.f));
    const float arg = coord * om;
    const float pe = (sec&1) ? __cosf(arg) : __sinf(arg);
    ov[j] = (vv[j]-mu)*rs*gw[f] + bw[f] + pe;
  }
  float* op = out + (size_t)tok*512 + f0;
  *(float4*)op = (float4){ov[0],ov[1],ov[2],ov[3]};
  *(float4*)(op+4) = (float4){ov[4],ov[5],ov[6],ov[7]};
}

// ---------------- GEMM 64x64 tile (4 blocks/CU) for N=512 layers ----------------
// EPI: 0 proj(f32+bias) 2 resid(f32) 3 gelu(bf16+bias) 4 resid+bias
template<int EPI>
__global__ __launch_bounds__(256, 4)
void k_gemm64(const u16* __restrict__ A, const u16* __restrict__ Wt,
              const float* __restrict__ bias, void* __restrict__ outp,
              const float* __restrict__ resid, int Kd)
{
  __shared__ u16 Ald[2][4096];
  __shared__ u16 Bld[2][4096];
  const int tid = threadIdx.x, lane = tid & 63, wv = tid >> 6;
  const int lr = lane & 15, g = lane >> 4;
  const int m0 = blockIdx.x * 64, n0 = blockIdx.y * 64;
  const int wm = (wv >> 1) * 32, wn = (wv & 1) * 32;
  const int srow = tid >> 3;
  const int sc  = (tid & 7) ^ (srow & 7);
  const u16* arow0p = A + (size_t)(m0+srow)*Kd + sc*8;
  const u16* arow1p = A + (size_t)(m0+srow+32)*Kd + sc*8;
  const u16* brow0p = Wt + (size_t)(n0+srow)*Kd + sc*8;
  const u16* brow1p = Wt + (size_t)(n0+srow+32)*Kd + sc*8;

  f32x4 acc[2][2];
  #pragma unroll
  for(int i=0;i<2;i++)
    #pragma unroll
    for(int j=0;j<2;j++) acc[i][j] = (f32x4){0.f,0.f,0.f,0.f};

  const int nIter = Kd >> 6;
  int cur = 0;
  auto stage = [&](int kt, int buf){
    const int k0 = kt << 6;
    gload16(arow0p + k0, &Ald[buf][tid*8]);
    gload16(arow1p + k0, &Ald[buf][2048 + tid*8]);
    gload16(brow0p + k0, &Bld[buf][tid*8]);
    gload16(brow1p + k0, &Bld[buf][2048 + tid*8]);
  };

  stage(0, 0);
  for(int kt=0; kt<nIter; ++kt){
    __syncthreads();
    if(kt+1 < nIter) stage(kt+1, cur^1);
    short8 af[2][2], bg[2][2];
    #pragma unroll
    for(int mi=0;mi<2;mi++)
      #pragma unroll
      for(int kk=0;kk<2;kk++){
        const int R = wm + mi*16 + lr;
        const int Rn = wn + mi*16 + lr;
        const int c = kk*4 + g;
        af[mi][kk] = *(const short8*)&Ald[cur][R*64 + ((c ^ (R&7))<<3)];
        bg[mi][kk] = *(const short8*)&Bld[cur][Rn*64 + ((c ^ (Rn&7))<<3)];
      }
    #pragma unroll
    for(int mi=0;mi<2;mi++)
      #pragma unroll
      for(int nj=0;nj<2;nj++)
        #pragma unroll
        for(int kk=0;kk<2;kk++)
          acc[mi][nj] = mfma16(af[mi][kk], bg[nj][kk], acc[mi][nj]);
    cur ^= 1;
  }

  #pragma unroll
  for(int mi=0;mi<2;mi++){
    #pragma unroll
    for(int nj=0;nj<2;nj++){
      #pragma unroll
      for(int r=0;r<4;r++){
        const int mrow = m0 + wm + mi*16 + g*4 + r;
        const int ncol = n0 + wn + nj*16 + lr;
        float val = acc[mi][nj][r];
        if constexpr (EPI==0 || EPI==3 || EPI==4)
          val += bias[ncol];
        if constexpr (EPI==0){
          ((float*)outp)[(size_t)mrow*512 + ncol] = val;
        } else if constexpr (EPI==2 || EPI==4){
          const size_t idx = (size_t)mrow*512 + ncol;
          ((float*)outp)[idx] = resid[idx] + val;
        } else if constexpr (EPI==3){
          const float gl = 0.5f * val * (1.f + erff(val * 0.70710678118654752f));
          ((u16*)outp)[(size_t)mrow*512 + ncol] = f2bf(gl);
        }
      }
    }
  }
}

// ---------------- conv1 GEMM: 64x64 tile, 4 blocks/CU, tap addressing, patches epilogue ----------------
__global__ __launch_bounds__(256, 4)
void k_gemmC(const u16* __restrict__ A, const u16* __restrict__ Wt,
             const float* __restrict__ bias, float* __restrict__ outp, int Kd)
{
  __shared__ u16 Ald[2][4096];
  __shared__ u16 Bld[2][4096];
  const int tid = threadIdx.x, lane = tid & 63, wv = tid >> 6;
  const int lr = lane & 15, g = lane >> 4;
  const int m0 = blockIdx.x * 64, n0 = blockIdx.y * 64;
  const int wm = (wv >> 1) * 32, wn = (wv & 1) * 32;
  const int srow = tid >> 3;
  const int sc  = (tid & 7) ^ (srow & 7);
  const int b0 = m0 >> 12, y0 = (m0 >> 6) & 63;
  const u16* brow0p = Wt + (size_t)(n0+srow)*Kd + sc*8;
  const u16* brow1p = Wt + (size_t)(n0+srow+32)*Kd + sc*8;

  f32x4 acc[2][2];
  #pragma unroll
  for(int i=0;i<2;i++)
    #pragma unroll
    for(int j=0;j<2;j++) acc[i][j] = (f32x4){0.f,0.f,0.f,0.f};

  const int nIter = Kd >> 6;
  int cur = 0;
  auto stage = [&](int kt, int buf){
    const int k0 = kt << 6;
    const int tap = k0 / 320;
    const int ic0 = k0 - tap*320;
    const int ky = tap/3, kx = tap - 3*(tap/3);
    const size_t rb0 = ((size_t)((b0*66 + y0+ky)*66 + kx))*320 + ic0 + sc*8;
    gload16(A + rb0 + (size_t)(srow)*320,    &Ald[buf][tid*8]);
    gload16(A + rb0 + (size_t)(srow+32)*320, &Ald[buf][2048 + tid*8]);
    gload16(brow0p + k0, &Bld[buf][tid*8]);
    gload16(brow1p + k0, &Bld[buf][2048 + tid*8]);
  };

  stage(0, 0);
  for(int kt=0; kt<nIter; ++kt){
    __syncthreads();
    if(kt+1 < nIter) stage(kt+1, cur^1);
    short8 af[2][2], bg[2][2];
    #pragma unroll
    for(int mi=0;mi<2;mi++)
      #pragma unroll
      for(int kk=0;kk<2;kk++){
        const int R = wm + mi*16 + lr;
        const int Rn = wn + mi*16 + lr;
        const int c = kk*4 + g;
        af[mi][kk] = *(const short8*)&Ald[cur][R*64 + ((c ^ (R&7))<<3)];
        bg[mi][kk] = *(const short8*)&Bld[cur][Rn*64 + ((c ^ (Rn&7))<<3)];
      }
    #pragma unroll
    for(int mi=0;mi<2;mi++)
      #pragma unroll
      for(int nj=0;nj<2;nj++)
        #pragma unroll
        for(int kk=0;kk<2;kk++)
          acc[mi][nj] = mfma16(af[mi][kk], bg[nj][kk], acc[mi][nj]);
    cur ^= 1;
  }

  #pragma unroll
  for(int mi=0;mi<2;mi++){
    #pragma unroll
    for(int nj=0;nj<2;nj++){
      #pragma unroll
      for(int r=0;r<4;r++){
        const int mrow = m0 + wm + mi*16 + g*4 + r;
        const int ncol = n0 + wn + nj*16 + lr;
        const float val = acc[mi][nj][r] + bias[ncol];
        const int b = mrow>>12; const int rr = mrow&4095; const int y = rr>>6; const int xx = rr&63;
        const size_t pidx = ((size_t)(b*1024 + (y>>1)*32 + (xx>>1)))*512 + (y&1)*256 + (xx&1)*128 + ncol;
        outp[pidx] = val;
      }
    }
  }
}

// ---------------- wide GEMM (128x64 tile) for conv2 ----------------
// EPI: 6 conv2->out
template<int EPI, int CONVC>
__global__ __launch_bounds__(256, 3)
void k_gemm(const u16* __restrict__ A, const u16* __restrict__ Wt,
            const float* __restrict__ bias, void* __restrict__ outp,
            const float* __restrict__ resid, int M, int N, int Kd)
{
  __shared__ u16 Ald[2][8192];                        // [128][64] (4 chunks of 32 rows)
  __shared__ u16 Bld[2][4096];                        // [64][64]
  const int tid = threadIdx.x, lane = tid & 63, wv = tid >> 6;
  const int lr = lane & 15, g = lane >> 4;
  const int m0 = blockIdx.x * 128, n0 = blockIdx.y * 64;
  const int wm = wv * 32;
  const int srow = tid >> 3;
  const int sc  = (tid & 7) ^ (srow & 7);
  int b0=0, y0=0;
  if constexpr (CONVC != 0){ b0 = m0>>12; y0 = (m0>>6)&63; }
  const u16* ar[4];
  if constexpr (CONVC == 0){
    #pragma unroll
    for(int j=0;j<4;j++) ar[j] = A + (size_t)(m0+srow+32*j)*Kd + sc*8;
  }
  const u16* br0 = Wt + (size_t)(n0+srow)*Kd + sc*8;
  const u16* br1 = Wt + (size_t)(n0+srow+32)*Kd + sc*8;

  f32x4 acc[2][4];
  #pragma unroll
  for(int i=0;i<2;i++)
    #pragma unroll
    for(int j=0;j<4;j++) acc[i][j] = (f32x4){0.f,0.f,0.f,0.f};

  const int nIter = Kd >> 6;
  int cur = 0;

  auto stage = [&](int kt, int buf){
    const int k0 = kt << 6;
    if constexpr (CONVC != 0){
      const int tap = k0 / CONVC;
      const int ic0 = k0 - tap*CONVC;
      const int ky = tap/3, kx = tap - 3*(tap/3);
      #pragma unroll
      for(int j=0;j<4;j++){
        const int xr = srow + 32*(j&1);
        const int yr = y0 + (j>>1) + ky;
        const u16* ga = A + ((size_t)((b0*66 + yr)*66 + xr + kx))*CONVC + ic0 + sc*8;
        gload16(ga, &Ald[buf][j*2048 + tid*8]);
      }
    } else {
      #pragma unroll
      for(int j=0;j<4;j++) gload16(ar[j] + k0, &Ald[buf][j*2048 + tid*8]);
    }
    gload16(br0 + k0, &Bld[buf][tid*8]);
    gload16(br1 + k0, &Bld[buf][2048 + tid*8]);
  };

  stage(0, 0);
  for(int kt=0; kt<nIter; ++kt){
    __syncthreads();
    if(kt+1 < nIter) stage(kt+1, cur^1);
    short8 af[2][2], bg[4][2];
    #pragma unroll
    for(int mi=0;mi<2;mi++)
      #pragma unroll
      for(int kk=0;kk<2;kk++){
        const int R = wm + mi*16 + lr;
        const int c = kk*4 + g;
        af[mi][kk] = *(const short8*)&Ald[cur][R*64 + ((c ^ (R&7))<<3)];
      }
    #pragma unroll
    for(int nj=0;nj<4;nj++)
      #pragma unroll
      for(int kk=0;kk<2;kk++){
        const int Rn = nj*16 + lr;
        const int c = kk*4 + g;
        bg[nj][kk] = *(const short8*)&Bld[cur][Rn*64 + ((c ^ (Rn&7))<<3)];
      }
    #pragma unroll
    for(int mi=0;mi<2;mi++)
      #pragma unroll
      for(int nj=0;nj<4;nj++)
        #pragma unroll
        for(int kk=0;kk<2;kk++)
          acc[mi][nj] = mfma16(af[mi][kk], bg[nj][kk], acc[mi][nj]);
    cur ^= 1;
  }

  #pragma unroll
  for(int mi=0;mi<2;mi++){
    #pragma unroll
    for(int nj=0;nj<4;nj++){
      #pragma unroll
      for(int r=0;r<4;r++){
        const int mrow = m0 + wm + mi*16 + g*4 + r;
        const int ncol = n0 + nj*16 + lr;
        float val = acc[mi][nj][r] + bias[ncol];
        if constexpr (EPI==5){
          const int b = mrow>>12; const int rr = mrow&4095; const int y = rr>>6; const int xx = rr&63;
          const size_t pidx = ((size_t)(b*1024 + (y>>1)*32 + (xx>>1)))*512 + (y&1)*256 + (xx&1)*128 + ncol;
          ((float*)outp)[pidx] = val;
        } else if constexpr (EPI==6){
          const int b = mrow>>12; const int rr = mrow&4095; const int y = rr>>6; const int xx = rr&63;
          ((float*)outp)[(((size_t)(b*320 + ncol))*64 + y)*64 + xx] = val;
        }
      }
    }
  }
}

// ---------------- wide GEMM for qkv: 128x64 tile, BK=64; q/k scatter; v -> vt directly ----------------
__global__ __launch_bounds__(256, 3)
void k_gemmW(const u16* __restrict__ A, const u16* __restrict__ Wt,
             void* __restrict__ outp, u16* __restrict__ vt, int Kd)
{
  __shared__ u16 Ald[2][8192];                       // [128][64]; reused as Vt bounce tile
  __shared__ u16 Bld[2][4096];                       // [64][64]
  const int tid = threadIdx.x, lane = tid & 63, wv = tid >> 6;
  const int lr = lane & 15, g = lane >> 4;
  const int m0 = blockIdx.x * 128, n0 = blockIdx.y * 64;
  const int wm = wv * 32;
  const int srow = tid >> 3;
  const int sc  = (tid & 7) ^ (srow & 7);
  const u16* ar[4];
  #pragma unroll
  for(int j=0;j<4;j++) ar[j] = A + (size_t)(m0+srow+32*j)*Kd + sc*8;
  const u16* br0 = Wt + (size_t)(n0+srow)*Kd + sc*8;
  const u16* br1 = Wt + (size_t)(n0+srow+32)*Kd + sc*8;

  f32x4 acc[2][4];
  #pragma unroll
  for(int i=0;i<2;i++)
    #pragma unroll
    for(int j=0;j<4;j++) acc[i][j] = (f32x4){0.f,0.f,0.f,0.f};

  const int nIter = Kd >> 6;
  int cur = 0;
  auto stage = [&](int kt, int buf){
    const int k0 = kt << 6;
    #pragma unroll
    for(int j=0;j<4;j++) gload16(ar[j] + k0, &Ald[buf][j*2048 + tid*8]);
    gload16(br0 + k0, &Bld[buf][tid*8]);
    gload16(br1 + k0, &Bld[buf][2048 + tid*8]);
  };

  stage(0, 0);
  for(int kt=0; kt<nIter; ++kt){
    __syncthreads();
    if(kt+1 < nIter) stage(kt+1, cur^1);
    short8 af[2][2], bg[4][2];
    #pragma unroll
    for(int mi=0;mi<2;mi++)
      #pragma unroll
      for(int kk=0;kk<2;kk++){
        const int R = wm + mi*16 + lr;
        const int c = kk*4 + g;
        af[mi][kk] = *(const short8*)&Ald[cur][R*64 + ((c ^ (R&7))<<3)];
      }
    #pragma unroll
    for(int nj=0;nj<4;nj++)
      #pragma unroll
      for(int kk=0;kk<2;kk++){
        const int Rn = nj*16 + lr;
        const int c = kk*4 + g;
        bg[nj][kk] = *(const short8*)&Bld[cur][Rn*64 + ((c ^ (Rn&7))<<3)];
      }
    #pragma unroll
    for(int mi=0;mi<2;mi++)
      #pragma unroll
      for(int nj=0;nj<4;nj++)
        #pragma unroll
        for(int kk=0;kk<2;kk++)
          acc[mi][nj] = mfma16(af[mi][kk], bg[nj][kk], acc[mi][nj]);
    cur ^= 1;
  }

  if(n0 < 1024){
    // q/k scatter epilogue
    #pragma unroll
    for(int mi=0;mi<2;mi++){
      #pragma unroll
      for(int nj=0;nj<4;nj++){
        #pragma unroll
        for(int r=0;r<4;r++){
          const int mrow = m0 + wm + mi*16 + g*4 + r;
          const int ncol = n0 + nj*16 + lr;
          const int sec = ncol >> 9, rem = ncol & 511;
          const int head = rem >> 6, d = rem & 63;
          const int b = mrow >> 10, t = mrow & 1023;
          ((u16*)outp)[(size_t)sec*4194304 + ((size_t)((b*8+head)*1024 + t))*64 + d] = f2bf(acc[mi][nj][r]);
        }
      }
    }
  } else {
    // v block: write vt[bh][d][t] directly via LDS bounce (raw v never materialized)
    const int head = (n0 - 1024) >> 6;
    const int b = m0 >> 10;
    const int t0 = m0 & 1023;
    const int bh = b*8 + head;
    __syncthreads();                                  // all waves done reading Ald
    u16* Vt = (u16*)Ald;                              // [64 d][136] (stride 272B, 16B-aligned)
    #pragma unroll
    for(int mi=0;mi<2;mi++)
      #pragma unroll
      for(int nj=0;nj<4;nj++)
        #pragma unroll
        for(int r=0;r<4;r++){
          const int lt = wm + mi*16 + g*4 + r;
          const int d  = nj*16 + lr;
          Vt[d*136 + lt] = f2bf(acc[mi][nj][r]);
        }
    __syncthreads();
    const int d = tid >> 2, qd = tid & 3;             // 64 d-rows x 4 chunks of 32 t
    u16* dst = vt + (size_t)bh*65536 + (size_t)d*1024 + t0 + qd*32;
    const u16* srcl = &Vt[d*136 + qd*32];
    #pragma unroll
    for(int e4=0;e4<4;e4++)
      *(short8*)(dst + e4*8) = *(const short8*)(srcl + e4*8);
  }
}

// ---------------- attention pass A: global min AND max, 128-q tile, 128-j staged (8 barriers) ----------------
__global__ __launch_bounds__(256, 4)
void k_attn_minmax(const u16* __restrict__ q, const u16* __restrict__ k, u32* __restrict__ keys, int layer){
  const int id = blockIdx.x;                   // 512 blocks
  const int qt = (id>>3)&7;
  const int bh = ((id&7)<<3) | (id>>6);
  __shared__ u16 Kld[2][8192];                 // [2 buf][2 sub][64 rows][64]
  __shared__ float redn[4], redx[4];
  const int tid = threadIdx.x, lane = tid & 63, wv = tid >> 6;
  const int lr = lane & 15, g = lane >> 4;
  const u16* qp0 = q + ((size_t)bh*1024 + qt*128 + wv*16 + lr)*64;
  const u16* qp1 = qp0 + 64*64;
  const short8 qa00 = *(const short8*)(qp0 + g*8);
  const short8 qa01 = *(const short8*)(qp0 + 32 + g*8);
  const short8 qa10 = *(const short8*)(qp1 + g*8);
  const short8 qa11 = *(const short8*)(qp1 + 32 + g*8);
  const u16* kbase = k + (size_t)bh*65536;
  const int srow = tid>>3, scs = lane&7;
  const int scg = scs ^ (srow&7);
  float mn = 3.0e38f, mx = -3.0e38f;
  auto stageK = [&](int jt, int buf){
    const int j0 = jt << 7;
    #pragma unroll
    for(int j=0;j<4;j++)
      gload16(kbase + (size_t)(j0 + srow + 32*j)*64 + scg*8, &Kld[buf][j*2048 + tid*8]);
  };
  stageK(0, 0);
  int cur = 0;
  for(int jt=0; jt<8; ++jt){
    __syncthreads();
    if(jt < 7) stageK(jt+1, cur^1);
    #pragma unroll
    for(int s=0;s<2;s++){
      const u16* Kp = &Kld[cur][s*4096];
      #pragma unroll
      for(int c=0;c<4;c++){
        const int rr = c*16 + lr;
        const short8 kb0 = *(const short8*)&Kp[rr*64 + ((g ^ (rr&7))<<3)];
        const short8 kb1 = *(const short8*)&Kp[rr*64 + (((g+4) ^ (rr&7))<<3)];
        f32x4 sa = (f32x4){0.f,0.f,0.f,0.f};
        f32x4 sb = (f32x4){0.f,0.f,0.f,0.f};
        __builtin_amdgcn_s_setprio(1);
        sa = mfma16(qa00, kb0, sa);
        sa = mfma16(qa01, kb1, sa);
        sb = mfma16(qa10, kb0, sb);
        sb = mfma16(qa11, kb1, sb);
        __builtin_amdgcn_s_setprio(0);
        mn = fminf(mn, fminf(fminf(sa[0],sa[1]), fminf(sa[2],sa[3])));
        mx = fmaxf(mx, fmaxf(fmaxf(sa[0],sa[1]), fmaxf(sa[2],sa[3])));
        mn = fminf(mn, fminf(fminf(sb[0],sb[1]), fminf(sb[2],sb[3])));
        mx = fmaxf(mx, fmaxf(fmaxf(sb[0],sb[1]), fmaxf(sb[2],sb[3])));
      }
    }
    cur ^= 1;
  }
  mn *= 0.125f; mx *= 0.125f;
  #pragma unroll
  for(int off=32; off; off>>=1){
    mn = fminf(mn, __shfl_down(mn, off));
    mx = fmaxf(mx, __shfl_down(mx, off));
  }
  if(lane==0){ redn[wv] = mn; redx[wv] = mx; }
  __syncthreads();
  if(tid==0){
    atomicMin(keys + layer,     fkey(fminf(fminf(redn[0],redn[1]), fminf(redn[2],redn[3]))));
    atomicMax(keys + 8 + layer, fkey(fmaxf(fmaxf(redx[0],redx[1]), fmaxf(redx[2],redx[3]))));
  }
}

// ---------------- attention pass B: 128-q tile, 128-j staged, MFMA row-sum, packed P ----------------
__global__ __launch_bounds__(256, 2)
void k_attn(const u16* __restrict__ q, const u16* __restrict__ k, const u16* __restrict__ vt,
            const u64* __restrict__ rmbits, const u32* __restrict__ keys,
            u16* __restrict__ o, int layer){
  const int id = blockIdx.x;                   // 512 blocks
  const int qt = (id>>3)&7;
  const int bh = ((id&7)<<3) | (id>>6);
  const int b = bh>>3, h = bh&7;
  __shared__ u16 Kld[2][8192];                 // [buf][sub 2][64 rows][64]
  __shared__ u16 Vtld[2][8192];
  __shared__ u32 Pld[4][1024];                 // per-wave [32 qrow][32 u32]
  const int tid = threadIdx.x, lane = tid & 63, wv = tid >> 6;
  const int lr = lane & 15, g = lane >> 4;
  const int L7 = lr & 7;
  const u16* qp0 = q + ((size_t)bh*1024 + qt*128 + wv*16 + lr)*64;
  const u16* qp1 = qp0 + 64*64;
  const short8 qa00 = *(const short8*)(qp0 + g*8);
  const short8 qa01 = *(const short8*)(qp0 + 32 + g*8);
  const short8 qa10 = *(const short8*)(qp1 + g*8);
  const short8 qa11 = *(const short8*)(qp1 + 32 + g*8);
  const float L2E = 1.44269504088896f;
  const float SC = 0.125f * L2E;
  float mnv = funkey(keys[layer]);
  float mxv = funkey(keys[8+layer]);
  if(!(mnv >= -1e38f && mnv <= 1e38f)) mnv = 0.f;
  if(!(mxv >= -1e38f && mxv <= 1e38f)) mxv = 0.f;
  const float ME   = mxv * L2E;
  const float minM = fmaxf(mnv*L2E - ME, -120.f);
  const float emin = exp2f(minM);              // precomputed masked-fill value
  const u32* cbp = (const u32*)(rmbits + (size_t)(layer*8 + b)*16);
  const int rowi0 = qt*128 + wv*16 + lr;
  const int rowi1 = rowi0 + 64;
  const u32 rf0 = ((cbp[rowi0>>5] >> (rowi0&31)) & 1u) ? 0xFu : 0u;
  const u32 rf1 = ((cbp[rowi1>>5] >> (rowi1&31)) & 1u) ? 0xFu : 0u;
  u32* Pw = &Pld[wv][0];
  u32 wslot[4][2];
  #pragma unroll
  for(int c=0;c<4;c++){
    const int blk = c*2 + (g>>1);
    wslot[c][0] = lr*32 + (((blk ^ L7))<<2) + (g&1)*2;
    wslot[c][1] = wslot[c][0] + 1;
  }
  const u32 ra0 = lr*32 + ((g ^ L7)<<2);
  const u32 ra1 = lr*32 + (((4+g) ^ L7)<<2);

  short8 vones;
  #pragma unroll
  for(int i=0;i<8;i++) vones[i] = (short)0x3F80;     // bf16 1.0
  f32x4 ls0 = (f32x4){0.f,0.f,0.f,0.f};
  f32x4 ls1 = (f32x4){0.f,0.f,0.f,0.f};
  f32x4 acc0[4], acc1[4];
  #pragma unroll
  for(int d=0;d<4;d++){ acc0[d] = (f32x4){0.f,0.f,0.f,0.f}; acc1[d] = (f32x4){0.f,0.f,0.f,0.f}; }
  const u16* kbase = k + (size_t)bh*65536;
  const u16* vtbase = vt + (size_t)bh*65536;
  const int srow = tid>>3, scs = lane&7;
  const int scg = scs ^ (srow&7);
  auto stageKV = [&](int jt, int buf){
    const int j0 = jt << 7;
    #pragma unroll
    for(int j=0;j<4;j++)
      gload16(kbase + (size_t)(j0 + srow + 32*j)*64 + scg*8, &Kld[buf][j*2048 + tid*8]);
    #pragma unroll
    for(int s=0;s<2;s++)
      #pragma unroll
      for(int jj=0;jj<2;jj++)
        gload16(vtbase + (size_t)(srow + 32*jj)*1024 + j0 + s*64 + scg*8,
                &Vtld[buf][s*4096 + jj*2048 + tid*8]);
  };
  stageKV(0, 0);
  int cur = 0;
  for(int jt=0; jt<8; ++jt){
    __syncthreads();
    if(jt < 7) stageKV(jt+1, cur^1);
    #pragma unroll
    for(int s=0;s<2;s++){
      const int jb = jt*2 + s;
      const u32 cb_lo = cbp[jb*2], cb_hi = cbp[jb*2+1];
      const u16* Kp = &Kld[cur][s*4096];
      const u16* Vp = &Vtld[cur][s*4096];
      #pragma unroll
      for(int c=0;c<4;c++){
        const int rr = c*16 + lr;
        const short8 kb0 = *(const short8*)&Kp[rr*64 + ((g ^ (rr&7))<<3)];
        const short8 kb1 = *(const short8*)&Kp[rr*64 + (((g+4) ^ (rr&7))<<3)];
        f32x4 sa = (f32x4){0.f,0.f,0.f,0.f};
        f32x4 sb = (f32x4){0.f,0.f,0.f,0.f};
        __builtin_amdgcn_s_setprio(1);
        sa = mfma16(kb0, qa00, sa);
        sa = mfma16(kb1, qa01, sa);
        sb = mfma16(kb0, qa10, sb);
        sb = mfma16(kb1, qa11, sb);
        __builtin_amdgcn_s_setprio(0);
        const u32 base = (((c<2) ? cb_lo : cb_hi) >> ((c&1)*16 + g*4));
        const u32 cw0 = base | rf0;
        const u32 cw1 = base | rf1;
        float e0[4], e1[4];
        #pragma unroll
        for(int r=0;r<4;r++){
          // sv <= 0 always (ME is the global max); exp2 of finite negative is safe.
          const float x0 = exp2f(fmaf(sa[r], SC, -ME));
          const float x1 = exp2f(fmaf(sb[r], SC, -ME));
          e0[r] = ((cw0 >> r) & 1u) ? x0 : emin;
          e1[r] = ((cw1 >> r) & 1u) ? x1 : emin;
        }
        Pw[wslot[c][0]]       = cvtpk(e0[0], e0[1]);
        Pw[wslot[c][1]]       = cvtpk(e0[2], e0[3]);
        Pw[512 + wslot[c][0]] = cvtpk(e1[0], e1[1]);
        Pw[512 + wslot[c][1]] = cvtpk(e1[2], e1[3]);
      }
      asm volatile("s_waitcnt lgkmcnt(0)" ::: "memory");
      __builtin_amdgcn_sched_barrier(0);
      const short8 pa00 = *(const short8*)&Pw[ra0];
      const short8 pa01 = *(const short8*)&Pw[ra1];
      const short8 pa10 = *(const short8*)&Pw[512 + ra0];
      const short8 pa11 = *(const short8*)&Pw[512 + ra1];
      // row-sum via MFMA with ones-B (moves lsum off the VALU pipe)
      __builtin_amdgcn_s_setprio(1);
      ls0 = mfma16(pa00, vones, ls0);
      ls0 = mfma16(pa01, vones, ls0);
      ls1 = mfma16(pa10, vones, ls1);
      ls1 = mfma16(pa11, vones, ls1);
      __builtin_amdgcn_s_setprio(0);
      #pragma unroll
      for(int d=0;d<4;d++){
        const int rr = d*16 + lr;
        const short8 vb0 = *(const short8*)&Vp[rr*64 + ((g ^ (rr&7))<<3)];
        const short8 vb1 = *(const short8*)&Vp[rr*64 + (((g+4) ^ (rr&7))<<3)];
        __builtin_amdgcn_s_setprio(1);
        acc0[d] = mfma16(pa00, vb0, acc0[d]);
        acc0[d] = mfma16(pa01, vb1, acc0[d]);
        acc1[d] = mfma16(pa10, vb0, acc1[d]);
        acc1[d] = mfma16(pa11, vb1, acc1[d]);
        __builtin_amdgcn_s_setprio(0);
      }
    }
    cur ^= 1;
  }
  float inv0[4], inv1[4];
  #pragma unroll
  for(int r=0;r<4;r++){
    inv0[r] = 1.f / (ls0[r] + 1e-30f);
    inv1[r] = 1.f / (ls1[r] + 1e-30f);
  }
  #pragma unroll
  for(int d=0;d<4;d++)
    #pragma unroll
    for(int r=0;r<4;r++){
      const int qr0 = qt*128 + wv*16 + g*4 + r;
      o[((size_t)b*1024 + qr0)*512 + h*64 + d*16 + lr]        = f2bf(acc0[d][r] * inv0[r]);
      o[((size_t)b*1024 + qr0 + 64)*512 + h*64 + d*16 + lr]   = f2bf(acc1[d][r] * inv1[r]);
    }
}

// ---------------- host ----------------
extern "C" void kernel_launch(void* const* d_in, const int* in_sizes, int n_in,
                              void* d_out, int out_size, void* d_ws, size_t ws_size,
                              hipStream_t stream)
{
  const float* img     = (const float*)d_in[0];
  const int*   mask    = (const int*)d_in[1];
  const float* conv1_w = (const float*)d_in[2];
  const float* conv1_b = (const float*)d_in[3];
  const float* ln_p_g  = (const float*)d_in[4];
  const float* ln_p_b  = (const float*)d_in[5];
  const float* proj_w  = (const float*)d_in[6];
  const float* proj_b  = (const float*)d_in[7];
  const float* ln_q_g  = (const float*)d_in[8];
  const float* ln_q_b  = (const float*)d_in[9];
  const float* attn_ln_g = (const float*)d_in[10];
  const float* attn_ln_b = (const float*)d_in[11];
  const float* wqkv    = (const float*)d_in[12];
  const float* wo      = (const float*)d_in[13];
  const float* ff_ln_g = (const float*)d_in[14];
  const float* ff_ln_b = (const float*)d_in[15];
  const float* w1      = (const float*)d_in[16];
  const float* b1      = (const float*)d_in[17];
  const float* w2      = (const float*)d_in[18];
  const float* b2      = (const float*)d_in[19];
  const float* conv2_w = (const float*)d_in[20];
  const float* conv2_b = (const float*)d_in[21];

  if(ws_size < WS_NEED) return;
  char* ws = (char*)d_ws;
  u16* projWt = (u16*)(ws + O_PROJW);
  u16* qkvWt  = (u16*)(ws + O_QKVW);
  u16* woWt   = (u16*)(ws + O_WOW);
  u16* w1Wt   = (u16*)(ws + O_W1W);
  u16* w2Wt   = (u16*)(ws + O_W2W);
  u16* c1Wt   = (u16*)(ws + O_C1W);
  u16* c2Wt   = (u16*)(ws + O_C2W);
  u16* pcl    = (u16*)(ws + O_RA);      // pcl1 / vt / pcl2
  float* tmpf = (float*)(ws + O_RA);
  u16* vtb    = (u16*)(ws + O_RA);      // v^T during layer loop
  float* patches = (float*)(ws + O_RB);
  u16* qkvb   = (u16*)(ws + O_RB);      // q|k (v folded into vt), each 8*8*1024*64
  float* xbuf = (float*)(ws + O_X);
  u16* xnbf   = (u16*)(ws + O_D);
  u16* obf    = (u16*)(ws + O_F);
  u32* minbuf = (u32*)(ws + O_MIN);
  u64* rmbits = (u64*)(ws + O_RMB);

  hipMemsetAsync(ws + O_MIN, 0xFF, 32, stream);       // min keys -> UINT_MAX
  hipMemsetAsync(ws + O_MIN + 32, 0, 32, stream);     // max keys -> 0
  hipMemsetAsync(ws + O_RA, 0, 22302720, stream);     // pcl1 zero borders

  // weight conversion
  k_transpose_bf<<<dim3(16,16,1),256,0,stream>>>(proj_w, projWt, 512, 512);
  k_transpose_bf<<<dim3(16,48,6),256,0,stream>>>(wqkv,   qkvWt,  512, 1536);
  k_transpose_bf<<<dim3(16,16,6),256,0,stream>>>(wo,     woWt,   512, 512);
  k_transpose_bf<<<dim3(16,16,6),256,0,stream>>>(w1,     w1Wt,   512, 512);
  k_transpose_bf<<<dim3(16,16,6),256,0,stream>>>(w2,     w2Wt,   512, 512);
  k_convw<<<1440,256,0,stream>>>(conv1_w, c1Wt, 128, 320);
  k_convw<<<1440,256,0,stream>>>(conv2_w, c2Wt, 320, 128);
  k_rmask<<<192,256,0,stream>>>(mask, rmbits);

  // patch embed
  k_pad_img<<<dim3(512,5),256,0,stream>>>(img, pcl);
  k_gemmC<<<dim3(512,2),256,0,stream>>>(pcl, c1Wt, conv1_b, patches, 2880);
  k_ln_bf<<<2048,256,0,stream>>>(patches, ln_p_g, ln_p_b, xnbf);
  k_gemm64<0><<<dim3(128,8),256,0,stream>>>(xnbf, projWt, proj_b, tmpf, nullptr, 512);
  k_lnq_pos<<<2048,256,0,stream>>>(tmpf, ln_q_g, ln_q_b, xbuf);

  const u16* qb = qkvb;
  const u16* kb = qkvb + 4194304;
  for(int i=0;i<6;i++){
    k_ln_bf<<<2048,256,0,stream>>>(xbuf, attn_ln_g + i*512, attn_ln_b + i*512, xnbf);
    k_gemmW<<<dim3(64,24),256,0,stream>>>(xnbf, qkvWt + (size_t)i*1536*512, qkvb, vtb, 512);
    k_attn_minmax<<<512,256,0,stream>>>(qb, kb, minbuf, i);
    k_attn<<<512,256,0,stream>>>(qb, kb, vtb, rmbits, minbuf, obf, i);
    k_gemm64<2><<<dim3(128,8),256,0,stream>>>(obf, woWt + (size_t)i*512*512, nullptr, xbuf, xbuf, 512);
    k_ln_bf<<<2048,256,0,stream>>>(xbuf, ff_ln_g + i*512, ff_ln_b + i*512, xnbf);
    k_gemm64<3><<<dim3(128,8),256,0,stream>>>(xnbf, w1Wt + (size_t)i*512*512, b1 + i*512, obf, nullptr, 512);
    k_gemm64<4><<<dim3(128,8),256,0,stream>>>(obf, w2Wt + (size_t)i*512*512, b2 + i*512, xbuf, xbuf, 512);
  }

  // final conv
  hipMemsetAsync(ws + O_RA, 0, 8921088, stream);    // pcl2 zero borders
  k_pad_tok<<<16384,256,0,stream>>>(xbuf, pcl);
  k_gemm<6,128><<<dim3(256,5),256,0,stream>>>(pcl, c2Wt, conv2_b, d_out, nullptr, 32768, 320, 1152);
}